// Round 4
// baseline (197.428 us; speedup 1.0000x reference)
//
#include <hip/hip_runtime.h>

#define PI_F 3.14159265358979323846f

typedef short bf16x8 __attribute__((ext_vector_type(8)));
typedef float f32x4 __attribute__((ext_vector_type(4)));

#define MFMA16(acc, a, b) \
  acc = __builtin_amdgcn_mfma_f32_16x16x32_bf16(a, b, acc, 0, 0, 0)

// ---------------- workspace layout (float offsets) ----------------
#define WS_SPEC   0u          // 32*128*1024  [b][t][k]
#define WS_H0     4194304u    // 32*32*128    [b][o][t]
#define WS_ACC    4325376u    // 32*128*32    [b][t][o]
#define WS_V      4456448u    // 32*32*128    [b][c][t]; ALSO: prep stashes the
                              // chain-weight bf16 packs in the first 16384 floats
                              // (region only becomes v after k_sparse_dense,
                              // which runs after k_chain has consumed the packs)
#define WS_WTIN   4587520u    // 1024*32      [k][o]
#define WS_WST    4620288u    // 32*256       [m][o2]
#define WS_WDT    4628480u    // 256*32       [o2][c]
#define WS_FRAMES 4636672u    // 32*32*2048   [c][f][j]
#define WS_RES    6733824u    // (dead: res assembly fused into obpack) -> Bh/Bl packs
// total 7782400 floats = ~29.7 MB

// ---- 2048-pt complex DIT FFT, bit-reversed input, 256 thr, LDS twiddle table ----
// tw holds per-stage tables: stage s entries at [2^s - 1, 2^(s+1) - 1), entry j =
// exp(-i*pi*j/2^s). Values built with the SAME __sincosf as the old in-loop code
// -> bitwise-identical numerics. Per-stage layout keeps lane-consecutive j ->
// <=2-way LDS banks at every stage (a single 1024-entry table read at stride
// 1<<(10-s) would 32-way conflict at mid stages).
__device__ __forceinline__ void fft2048_stages(float2* buf, const float2* tw, int tid) {
  for (int stage = 0; stage < 11; ++stage) {
    int half = 1 << stage;
    for (int t = tid; t < 1024; t += 256) {
      int j  = t & (half - 1);
      int i0 = ((t >> stage) << (stage + 1)) + j;
      int i1 = i0 + half;
      float2 w2 = tw[(half - 1) + j];     // (cos, sin) of -pi*j/half
      float2 u = buf[i0];
      float2 w = buf[i1];
      float tr = w2.x * w.x - w2.y * w.y;
      float ti = w2.x * w.y + w2.y * w.x;
      buf[i0] = make_float2(u.x + tr, u.y + ti);
      buf[i1] = make_float2(u.x - tr, u.y - ti);
    }
    __syncthreads();
  }
}

// ---------------- fused FFT kernel: STFT pairs + resonance pairs + prep tail ----------------
// blk <  2048 : STFT (2 frames per block via complex pack)
// blk <  2560 : resonance frames (2 exponents per block via complex pack)
// blk >= 2560 : weight transposes + chain-weight bf16 packs (old k_prep, 128 blocks)
__global__ __launch_bounds__(256) void k_fft(const float* __restrict__ audio,
                                             const float* __restrict__ resin,
                                             const float* __restrict__ Win,
                                             const float* __restrict__ Ws,
                                             const float* __restrict__ Wd,
                                             const float* __restrict__ bwIn,
                                             float* __restrict__ spec,
                                             float* __restrict__ frames,
                                             float* __restrict__ WT,
                                             float* __restrict__ WsT,
                                             float* __restrict__ WdT,
                                             short* __restrict__ Whg,
                                             short* __restrict__ Wlg) {
  __shared__ float2 buf[2048];
  __shared__ float2 tw[2047];
  int blk = blockIdx.x;

  if (blk >= 2560) {                  // ---- prep branch (no LDS, no syncs) ----
    int i = (blk - 2560) * 256 + threadIdx.x;
    if (i < 32768) { int o = i >> 10, k = i & 1023; WT[k * 32 + o] = Win[i]; }
    if (i < 8192)  { int o2 = i >> 5, m = i & 31;   WsT[m * 256 + o2] = Ws[i]; }
    if (i < 8192)  { int c = i >> 8, o2 = i & 255;  WdT[o2 * 32 + c] = Wd[i]; }
    if (i < 16384) {
      // i = ((s*32+o)*32+m)*2 + w
      int w = i & 1, m = (i >> 1) & 31, o = (i >> 6) & 31, s = i >> 11;
      float val = bwIn[i];
      unsigned bits = __float_as_uint(val);
      float rem = val - __uint_as_float(bits & 0xffff0000u);
      int row = (s * 2 + w) * 32 + o;
      Whg[row * 32 + m] = (short)(bits >> 16);
      Wlg[row * 32 + m] = (short)(__float_as_uint(rem) >> 16);
    }
    return;
  }

  // build per-stage twiddle tables (2047 entries)
  for (int i = threadIdx.x; i < 2047; i += 256) {
    int s2   = 31 - __clz(i + 1);
    int half = 1 << s2;
    int jj   = i + 1 - half;
    float sn, cs;
    __sincosf(-PI_F * (float)jj / (float)half, &sn, &cs);
    tw[i] = make_float2(cs, sn);
  }

  if (blk < 2048) {
    int b  = blk >> 6;
    int f0 = (blk & 63) * 2;      // frames f0, f0+1
    for (int j = threadIdx.x; j < 2048; j += 256) {
      float h = 0.5f - 0.5f * __cosf(0.0030679615757712823f * (float)j); // 2pi/2048
      int i1 = f0 * 256 + j;
      int i2 = i1 + 256;
      float a1 = (i1 < 32768) ? audio[b * 32768 + i1] : 0.f;
      float a2 = (i2 < 32768) ? audio[b * 32768 + i2] : 0.f;
      buf[__brev((unsigned)j) >> 21] = make_float2(a1 * h, a2 * h);
    }
    __syncthreads();
    fft2048_stages(buf, tw, threadIdx.x);
    const float scale = 0.5f * 0.022097086912079608f;  // 0.5 / sqrt(2048)
    for (int k = threadIdx.x; k < 1024; k += 256) {
      float2 zk = buf[k];
      float2 zn = buf[(2048 - k) & 2047];
      float f1r = zk.x + zn.x, f1i = zk.y - zn.y;
      float f2r = zk.y + zn.y, f2i = zk.x - zn.x;
      spec[(b * 128 + f0) * 1024 + k]     = sqrtf(f1r * f1r + f1i * f1i) * scale;
      spec[(b * 128 + f0 + 1) * 1024 + k] = sqrtf(f2r * f2r + f2i * f2i) * scale;
    }
  } else {
    int r = blk - 2048;           // 0..511
    int c = r >> 4;
    int g = r & 15;               // frames 2g (exp 2g+1), 2g+1 (exp 2g+2)
    float e1 = (float)(2 * g + 1);
    for (int k = threadIdx.x; k < 2048; k += 256) {
      int kk = (k <= 1024) ? k : 2048 - k;   // Hermitian (real) extension
      float cv = resin[c * 1025 + kk];
      cv = fminf(fmaxf(cv, 0.f), 0.9999f);
      float m1 = __powf(cv, e1);
      float m2 = m1 * cv;
      buf[__brev((unsigned)k) >> 21] = make_float2(m1, m2);
    }
    __syncthreads();
    fft2048_stages(buf, tw, threadIdx.x);
    for (int j = threadIdx.x; j < 2048; j += 256) {
      float h  = 0.5f - 0.5f * __cosf(0.0030679615757712823f * (float)j);
      float sc = h * (1.f / 2048.f);
      float2 z = buf[j];
      frames[(c * 32 + 2 * g) * 2048 + j]     = z.x * sc;
      frames[(c * 32 + 2 * g + 1) * 2048 + j] = z.y * sc;
    }
  }
}

// ---------------- merged mid kernel: proj_in (blk<512) + overlap-add/B-pack ----------------
__global__ __launch_bounds__(256) void k_mid(const float* __restrict__ spec,
                                             const float* __restrict__ WT,
                                             const float* __restrict__ bias,
                                             float* __restrict__ h0,
                                             const float* __restrict__ frames,
                                             short* __restrict__ Bh,
                                             short* __restrict__ Bl) {
  __shared__ float specL[8][1024];
  __shared__ float red[32][8][8];   // [o][tt][p]

  if (blockIdx.x >= 512) {          // ---- fused overlap-add + B-pack ----
    int bb = blockIdx.x - 512;      // 0..511
    int c = bb >> 4, o = bb & 15;
    int r = threadIdx.x;
    bf16x8 hv, lv;
#pragma unroll
    for (int j = 0; j < 8; ++j) {
      int fo = 8 * o + j;
      int g  = fo >> 2;
      int j0 = ((fo & 3) << 8) + r;
      float val = frames[(c * 32 + g) * 2048 + j0];
      if (g > 0) val += frames[(c * 32 + g - 1) * 2048 + j0 + 1024];
      unsigned bits = __float_as_uint(val);
      float rem = val - __uint_as_float(bits & 0xffff0000u);
      hv[j] = (short)(bits >> 16);
      lv[j] = (short)(__float_as_uint(rem) >> 16);
    }
    int unit = (bb * 16 + (r >> 4)) * 16 + (r & 15);
    ((bf16x8*)Bh)[unit] = hv;
    ((bf16x8*)Bl)[unit] = lv;
    return;
  }

  // ---- proj_in: h0[b,o,t] = sum_k WT[k][o]*spec[b,t,k] + bias ----
  int b  = blockIdx.x >> 4;
  int t0 = (blockIdx.x & 15) * 8;
  for (int i = threadIdx.x; i < 8192; i += 256) {
    int tt = i >> 10, k = i & 1023;
    specL[tt][k] = spec[(b * 128 + t0 + tt) * 1024 + k];
  }
  __syncthreads();
  int o = threadIdx.x & 31, p = threadIdx.x >> 5;
  float part[8] = {0.f,0.f,0.f,0.f,0.f,0.f,0.f,0.f};
  for (int i = 0; i < 128; ++i) {
    int k = p * 128 + ((i + p * 4) & 127);   // stagger: conflict-free banks across p
    float w = WT[k * 32 + o];
#pragma unroll
    for (int tt = 0; tt < 8; ++tt) part[tt] += w * specL[tt][k];
  }
#pragma unroll
  for (int tt = 0; tt < 8; ++tt) red[o][tt][p] = part[tt];
  __syncthreads();
  int oo = threadIdx.x >> 3, tt2 = threadIdx.x & 7;
  float s = bias[oo];
#pragma unroll
  for (int p2 = 0; p2 < 8; ++p2) s += red[oo][tt2][p2];
  h0[b * 4096 + oo * 128 + t0 + tt2] = s;
}

// ---------------- 8-block anticausal chain as per-step MFMA GEMM pairs ----------------
__global__ __launch_bounds__(1024) void k_chain(const float* __restrict__ h0,
                                                const short* __restrict__ Whg,
                                                const short* __restrict__ Wlg,
                                                const float* __restrict__ bb,
                                                float* __restrict__ accout) {
  __shared__ __align__(16) short Hh[192 * 40];   // rows stride 40 bf16 (80 B)
  __shared__ __align__(16) short Hl[192 * 40];
  __shared__ float Hf[128 * 33];                 // fp32 H for exact residual
  __shared__ float bL[256];
  __shared__ float red[16];
  int b = blockIdx.x, tid = threadIdx.x;

  for (int i = tid; i < 4096; i += 1024) {
    int t = i & 127;                 // h0 layout [o][t]
    int o = i >> 7;
    float val = h0[b * 4096 + i];
    Hf[t * 33 + o] = val;
    unsigned bits = __float_as_uint(val);
    float rem = val - __uint_as_float(bits & 0xffff0000u);
    Hh[t * 40 + o] = (short)(bits >> 16);
    Hl[t * 40 + o] = (short)(__float_as_uint(rem) >> 16);
  }
  for (int i = tid; i < 64 * 40; i += 1024) {    // zero pad rows 128..191
    Hh[128 * 40 + i] = 0;
    Hl[128 * 40 + i] = 0;
  }
  if (tid < 256) bL[tid] = bb[tid];
  __syncthreads();

  int wave = tid >> 6, lane = tid & 63;
  int quad = lane >> 4, l15 = lane & 15;
  int t0 = (wave & 7) * 16, o0 = (wave >> 3) * 16;
  int tD = t0 + quad * 4;          // D rows tD..tD+3
  int oD = o0 + l15;               // D col

  const bf16x8* Hh8 = (const bf16x8*)Hh;   // unit = row*5 + quad (40 bf16 = 5 units)
  const bf16x8* Hl8 = (const bf16x8*)Hl;
  const bf16x8* Wh8 = (const bf16x8*)Whg;  // unit = row*4 + quad (32 bf16 = 4 units)
  const bf16x8* Wl8 = (const bf16x8*)Wlg;

  float accsum[4] = {0.f, 0.f, 0.f, 0.f};
  const int DIL[8] = {1, 2, 4, 8, 16, 32, 64, 1};

#pragma unroll
  for (int s = 0; s < 8; ++s) {
    int arow = t0 + l15;
    int frow = arow + DIL[s];        // <= 191, pad rows give zeros
    bf16x8 Ah = Hh8[arow * 5 + quad];
    bf16x8 Al = Hl8[arow * 5 + quad];
    bf16x8 Fh = Hh8[frow * 5 + quad];
    bf16x8 Fl = Hl8[frow * 5 + quad];
    int w0row = ((s * 2 + 0) * 32 + oD) * 4 + quad;
    int w1row = ((s * 2 + 1) * 32 + oD) * 4 + quad;
    bf16x8 B0h = Wh8[w0row], B0l = Wl8[w0row];
    bf16x8 B1h = Wh8[w1row], B1l = Wl8[w1row];
    float bias = bL[s * 32 + oD];
    f32x4 acc = {bias, bias, bias, bias};
    MFMA16(acc, Ah, B0h); MFMA16(acc, Ah, B0l); MFMA16(acc, Al, B0h);
    MFMA16(acc, Fh, B1h); MFMA16(acc, Fh, B1l); MFMA16(acc, Fl, B1h);
    float hnew[4], lmax = 0.f;
#pragma unroll
    for (int r = 0; r < 4; ++r) {
      float sv = acc[r];
      sv = (sv > 0.f) ? sv : 0.2f * sv;       // leaky_relu 0.2
      sv += Hf[(tD + r) * 33 + oD];           // residual (exact fp32)
      hnew[r] = sv;
      lmax = fmaxf(lmax, fabsf(sv));
    }
#pragma unroll
    for (int off = 32; off > 0; off >>= 1)
      lmax = fmaxf(lmax, __shfl_down(lmax, off, 64));
    if (lane == 0) red[wave] = lmax;
    __syncthreads();                 // red visible; all H reads of this step done
    float mx = red[0];
#pragma unroll
    for (int i = 1; i < 16; ++i) mx = fmaxf(mx, red[i]);
    float nm = 1.f / (mx + 1e-8f);
#pragma unroll
    for (int r = 0; r < 4; ++r) {
      float hv = hnew[r] * nm;
      accsum[r] += hv;
      int t = tD + r;
      Hf[t * 33 + oD] = hv;
      unsigned bits = __float_as_uint(hv);
      float rem = hv - __uint_as_float(bits & 0xffff0000u);
      Hh[t * 40 + oD] = (short)(bits >> 16);
      Hl[t * 40 + oD] = (short)(__float_as_uint(rem) >> 16);
    }
    __syncthreads();                 // new H visible for next step
  }
#pragma unroll
  for (int r = 0; r < 4; ++r)
    accout[b * 4096 + (tD + r) * 32 + oD] = accsum[r];
}

// ---------------- sparse + dense, 4 t per block (4x weight reuse + ILP) ----------------
__global__ __launch_bounds__(256) void k_sparse_dense(const float* __restrict__ acc,
                                                      const float* __restrict__ WsT,
                                                      const float* __restrict__ bs,
                                                      const float* __restrict__ WdT,
                                                      const float* __restrict__ bd,
                                                      float* __restrict__ out_sparse,
                                                      float* __restrict__ v) {
  __shared__ float accL[4][32];
  __shared__ float sL[4][256];
  __shared__ float red[8][4][32];   // [p][tt][c]
  int b = blockIdx.x >> 5, tq = blockIdx.x & 31;
  int t0 = tq * 4;
  int tid = threadIdx.x;
  if (tid < 128)
    accL[tid >> 5][tid & 31] = acc[b * 4096 + (t0 + (tid >> 5)) * 32 + (tid & 31)];
  __syncthreads();
  float bsv = bs[tid];
  float s0 = bsv, s1 = bsv, s2 = bsv, s3 = bsv;
  for (int m = 0; m < 32; ++m) {
    float w = WsT[m * 256 + tid];
    s0 += w * accL[0][m]; s1 += w * accL[1][m];
    s2 += w * accL[2][m]; s3 += w * accL[3][m];
  }
  s0 = fmaxf(s0, 0.f); s1 = fmaxf(s1, 0.f); s2 = fmaxf(s2, 0.f); s3 = fmaxf(s3, 0.f);
  float* os = out_sparse + b * 32768 + tid * 128 + t0;
  os[0] = s0; os[1] = s1; os[2] = s2; os[3] = s3;
  sL[0][tid] = s0; sL[1][tid] = s1; sL[2][tid] = s2; sL[3][tid] = s3;
  __syncthreads();
  int c = tid & 31, p = tid >> 5;
  float p0 = 0.f, p1 = 0.f, p2 = 0.f, p3 = 0.f;
  for (int jj = 0; jj < 32; ++jj) {
    int o2 = p * 32 + jj;
    float w = WdT[o2 * 32 + c];
    p0 += w * sL[0][o2]; p1 += w * sL[1][o2];
    p2 += w * sL[2][o2]; p3 += w * sL[3][o2];
  }
  red[p][0][c] = p0; red[p][1][c] = p1; red[p][2][c] = p2; red[p][3][c] = p3;
  __syncthreads();
  if (tid < 128) {
    int tt = tid >> 5, cc = tid & 31;
    float vv = bd[cc];
#pragma unroll
    for (int p2i = 0; p2i < 8; ++p2i) vv += red[p2i][tt][cc];
    v[b * 4096 + cc * 128 + t0 + tt] = vv;
  }
}

// ---------------- final conv as MFMA GEMM, v5: single-phase K=512 ----------------
// v4 post-mortem: swizzle worked (k_conv ~22-28 us inferred), but structure still
// pays 5 barriers/block and serializes the A-expand twice between them; B-load
// pipelining is chopped into two 8-iter windows. v5: full K=512 A in LDS
// (AH/AL 32x520 = 66.5 KB + vwin 6 KB = 72.7 KB -> still 2 blocks/CU, same
// 4 waves/SIMD), ONE expand pass, ONE 16-ks MFMA loop, 3 barriers total.
// Accumulation order c=0..31 identical to v4 -> bitwise-same results.
// XCD-group swizzle unchanged (all 32 b-blocks of one (j,uc) share one XCD's L2).
__global__ __launch_bounds__(512, 4) void k_conv(const float* __restrict__ v,
                                                 const short* __restrict__ Bh,
                                                 const short* __restrict__ Bl,
                                                 float* __restrict__ y) {
  __shared__ __align__(16) short AH[32 * 520];   // [row 32][K 512 + pad 8]
  __shared__ __align__(16) short AL[32 * 520];
  __shared__ float vwin[2][16][48];              // [c-half][c_local][ii]

  // --- XCD-group swizzle: group e (20 of them) -> XCD e%8; batches fill slots.
  int xcd  = blockIdx.x & 7;
  int slot = blockIdx.x >> 3;
  int e, b;
  if      (slot < 32) { e = xcd;      b = slot; }
  else if (slot < 64) { e = xcd + 8;  b = slot - 32; }
  else                { e = (xcd < 4) ? (xcd + 16) : (xcd + 12);
                        b = (xcd < 4) ? (slot - 64) : (slot - 48); }
  int j, uc;
  if      (e < 2)  { j = 0; uc = e; }
  else if (e < 6)  { j = 1; uc = e - 2; }
  else if (e < 12) { j = 2; uc = e - 6; }
  else             { j = 3; uc = e - 12; }
  int D0 = 32 * j - 16 * uc;       // d = D0 - 15 + ii, ii in [0,46]

  // stage compact v windows (both c-halves): 2*16*47 floats
  for (int i = threadIdx.x; i < 1504; i += 512) {
    int ii = i % 47;
    int r  = i / 47;               // 0..31
    int c  = r & 15, ph = r >> 4;
    int d  = D0 - 15 + ii;
    vwin[ph][c][ii] = (d >= 0 && d < 128)
        ? v[b * 4096 + (16 * ph + c) * 128 + d] : 0.f;
  }
  __syncthreads();

  // expand Toeplitz A (hi/lo split), full K=512: 32 rows x 256 kk-pairs
  short2* AH2 = (short2*)AH;
  short2* AL2 = (short2*)AL;
  for (int i = threadIdx.x; i < 8192; i += 512) {
    int kk2 = i & 255;             // kk = 2*kk2 (pair shares c)
    int row = i >> 8;              // 0..31
    int c   = kk2 >> 3;            // 0..31
    int uu  = (kk2 & 7) * 2;
    int ii  = row - uu + 15;
    float v0 = vwin[c >> 4][c & 15][ii];
    float v1 = vwin[c >> 4][c & 15][ii - 1];
    unsigned w0 = __float_as_uint(v0), w1 = __float_as_uint(v1);
    float r0 = v0 - __uint_as_float(w0 & 0xffff0000u);
    float r1 = v1 - __uint_as_float(w1 & 0xffff0000u);
    int u2 = row * 260 + kk2;      // short2 units, row stride 260 (=520 shorts)
    AH2[u2] = make_short2((short)(w0 >> 16), (short)(w1 >> 16));
    AL2[u2] = make_short2((short)(__float_as_uint(r0) >> 16),
                          (short)(__float_as_uint(r1) >> 16));
  }
  __syncthreads();

  int lane = threadIdx.x & 63, wave = threadIdx.x >> 6;
  int quad = lane >> 4, l15 = lane & 15;
  int cq   = quad >> 1;            // low bit of c
  int og   = 2 * uc + (quad & 1);  // global u-octet
  int nt0  = wave * 2;             // 8 waves x 2 nt = 16 nt

  f32x4 acc00 = (f32x4)0.f, acc01 = (f32x4)0.f;   // [qs][t]
  f32x4 acc10 = (f32x4)0.f, acc11 = (f32x4)0.f;

  const bf16x8* AH8 = (const bf16x8*)AH;
  const bf16x8* AL8 = (const bf16x8*)AL;
  const bf16x8* Bh8 = (const bf16x8*)Bh;
  const bf16x8* Bl8 = (const bf16x8*)Bl;

  int abase0 = l15 * 65 + quad;          // bf16x8 units, row stride 65 (=520 shorts)
  int abase1 = (16 + l15) * 65 + quad;

#pragma unroll
  for (int ks = 0; ks < 16; ++ks) {
    bf16x8 ah0 = AH8[abase0 + ks * 4];
    bf16x8 al0 = AL8[abase0 + ks * 4];
    bf16x8 ah1 = AH8[abase1 + ks * 4];
    bf16x8 al1 = AL8[abase1 + ks * 4];
    int c   = 2 * ks + cq;
    int bb0 = (c * 16 + og) * 256 + l15;
    bf16x8 bh0 = Bh8[bb0 + nt0 * 16];
    bf16x8 bl0 = Bl8[bb0 + nt0 * 16];
    bf16x8 bh1 = Bh8[bb0 + (nt0 + 1) * 16];
    bf16x8 bl1 = Bl8[bb0 + (nt0 + 1) * 16];
    MFMA16(acc00, ah0, bh0); MFMA16(acc00, ah0, bl0); MFMA16(acc00, al0, bh0);
    MFMA16(acc10, ah1, bh0); MFMA16(acc10, ah1, bl0); MFMA16(acc10, al1, bh0);
    MFMA16(acc01, ah0, bh1); MFMA16(acc01, ah0, bl1); MFMA16(acc01, al0, bh1);
    MFMA16(acc11, ah1, bh1); MFMA16(acc11, ah1, bl1); MFMA16(acc11, al1, bh1);
  }

  {
    float* yb0 = y + b * 32768 + (32 * j + 0 * 16 + quad * 4) * 256 + l15;
    float* yb1 = y + b * 32768 + (32 * j + 1 * 16 + quad * 4) * 256 + l15;
#pragma unroll
    for (int reg = 0; reg < 4; ++reg) {
      atomicAdd(yb0 + reg * 256 + (nt0 + 0) * 16, acc00[reg]);
      atomicAdd(yb0 + reg * 256 + (nt0 + 1) * 16, acc01[reg]);
      atomicAdd(yb1 + reg * 256 + (nt0 + 0) * 16, acc10[reg]);
      atomicAdd(yb1 + reg * 256 + (nt0 + 1) * 16, acc11[reg]);
    }
  }
}

extern "C" void kernel_launch(void* const* d_in, const int* in_sizes, int n_in,
                              void* d_out, int out_size, void* d_ws, size_t ws_size,
                              hipStream_t stream) {
  const float* audio = (const float*)d_in[0];
  const float* Win   = (const float*)d_in[1];
  const float* bin   = (const float*)d_in[2];
  const float* bw    = (const float*)d_in[3];
  const float* bb    = (const float*)d_in[4];
  const float* Ws    = (const float*)d_in[5];
  const float* bs    = (const float*)d_in[6];
  const float* Wd    = (const float*)d_in[7];
  const float* bd    = (const float*)d_in[8];
  const float* reson = (const float*)d_in[9];

  float* out = (float*)d_out;           // [0,1048576) = y ; [1048576,2097152) = sparse
  float* ws  = (float*)d_ws;

  float* spec   = ws + WS_SPEC;
  float* h0     = ws + WS_H0;
  float* accb   = ws + WS_ACC;
  float* vbuf   = ws + WS_V;
  float* WT     = ws + WS_WTIN;
  float* WsT    = ws + WS_WST;
  float* WdT    = ws + WS_WDT;
  float* frames = ws + WS_FRAMES;
  // WS_RES region (dead after fusing overlap-add into k_mid) -> bf16 B packs
  short* Bh = (short*)(ws + WS_RES);               // 1,048,576 bf16 = 2 MB
  short* Bl = (short*)(ws + WS_RES + 524288u);     // 1,048,576 bf16 = 2 MB
  // chain-weight packs live in WS_V until k_sparse_dense overwrites it (after k_chain)
  short* Whg = (short*)(ws + WS_V);                // 16384 bf16 = 32 KB
  short* Wlg = (short*)(ws + WS_V + 8192u);        // 16384 bf16 = 32 KB

  // zero y region (atomicAdd target); d_out is poisoned before every launch
  hipMemsetAsync(d_out, 0, 1048576u * sizeof(float), stream);

  k_fft<<<2688, 256, 0, stream>>>(audio, reson, Win, Ws, Wd, bw,
                                  spec, frames, WT, WsT, WdT, Whg, Wlg);
  k_mid<<<1024, 256, 0, stream>>>(spec, WT, bin, h0, frames, Bh, Bl);
  k_chain<<<32, 1024, 0, stream>>>(h0, Whg, Wlg, bb, accb);
  k_sparse_dense<<<1024, 256, 0, stream>>>(accb, WsT, bs, WdT, bd, out + 1048576, vbuf);
  k_conv<<<640, 512, 0, stream>>>(vbuf, Bh, Bl, out);
}

// Round 5
// 194.355 us; speedup vs baseline: 1.0158x; 1.0158x over previous
//
#include <hip/hip_runtime.h>

#define PI_F 3.14159265358979323846f

typedef short bf16x8 __attribute__((ext_vector_type(8)));
typedef float f32x4 __attribute__((ext_vector_type(4)));

#define MFMA16(acc, a, b) \
  acc = __builtin_amdgcn_mfma_f32_16x16x32_bf16(a, b, acc, 0, 0, 0)

// ---------------- workspace layout (float offsets) ----------------
#define WS_SPEC   0u          // 32*128*1024  [b][t][k]
#define WS_H0     4194304u    // 32*32*128    [b][o][t]
#define WS_ACC    4325376u    // 32*128*32    [b][t][o]
#define WS_V      4456448u    // 32*32*128    [b][c][t]; ALSO: prep stashes the
                              // chain-weight bf16 packs in the first 16384 floats
                              // (region only becomes v after k_sparse_dense,
                              // which runs after k_chain has consumed the packs)
#define WS_WTIN   4587520u    // 1024*32      [k][o]
#define WS_WST    4620288u    // 32*256       [m][o2]
#define WS_WDT    4628480u    // 256*32       [o2][c]
#define WS_FRAMES 4636672u    // 32*32*2048   [c][f][j]
#define WS_RES    6733824u    // (dead: res assembly fused into obpack) -> Bh/Bl packs
// total 7782400 floats = ~29.7 MB

// ---- 2048-pt complex DIT FFT, bit-reversed input, 256 thr ----
// v6: reverted from LDS twiddle table (v5 regression: table reads ADDED LDS
// conflict traffic to an already LDS-limited kernel and halved blocks/CU).
// Inline __sincosf for stages 3..10 (proven ~40us form); stages 0-2 use exact
// constant twiddles (w=1 / w=-i / +-sqrt2/2) -> 12 of 44 sincosf and 8 of 44
// cmuls removed per thread with ZERO change to LDS pattern or occupancy.
__device__ __forceinline__ void fft2048_stages(float2* buf, int tid) {
  // stage 0: w = 1 (pure add/sub)
  for (int t = tid; t < 1024; t += 256) {
    int i0 = 2 * t, i1 = i0 + 1;
    float2 u = buf[i0], w = buf[i1];
    buf[i0] = make_float2(u.x + w.x, u.y + w.y);
    buf[i1] = make_float2(u.x - w.x, u.y - w.y);
  }
  __syncthreads();
  // stage 1: j=0 -> w=1 ; j=1 -> w=-i (tr=w.y, ti=-w.x)
  for (int t = tid; t < 1024; t += 256) {
    int j  = t & 1;
    int i0 = ((t >> 1) << 2) + j, i1 = i0 + 2;
    float2 u = buf[i0], w = buf[i1];
    float tr = j ? w.y : w.x;
    float ti = j ? -w.x : w.y;
    buf[i0] = make_float2(u.x + tr, u.y + ti);
    buf[i1] = make_float2(u.x - tr, u.y - ti);
  }
  __syncthreads();
  // stage 2: w = e^{-i pi j/4}, j=0..3: (1,0) (R,-R) (0,-1) (-R,-R), R=sqrt(2)/2
  for (int t = tid; t < 1024; t += 256) {
    int j  = t & 3;
    int i0 = ((t >> 2) << 3) + j, i1 = i0 + 4;
    const float R = 0.7071067811865476f;
    float c = (j == 0) ? 1.f : ((j == 1) ? R : ((j == 2) ? 0.f : -R));
    float s = (j == 0) ? 0.f : ((j == 2) ? -1.f : -R);
    float2 u = buf[i0], w = buf[i1];
    float tr = c * w.x - s * w.y;
    float ti = c * w.y + s * w.x;
    buf[i0] = make_float2(u.x + tr, u.y + ti);
    buf[i1] = make_float2(u.x - tr, u.y - ti);
  }
  __syncthreads();
  // stages 3..10: inline sincosf (known-good)
  for (int stage = 3; stage < 11; ++stage) {
    int half = 1 << stage;
    float base = -PI_F / (float)half;   // -2*pi/len
    for (int t = tid; t < 1024; t += 256) {
      int j  = t & (half - 1);
      int i0 = ((t >> stage) << (stage + 1)) + j;
      int i1 = i0 + half;
      float s, c;
      __sincosf(base * (float)j, &s, &c);   // e^{-i*2pi/len*j} = c + i*s
      float2 u = buf[i0];
      float2 w = buf[i1];
      float tr = c * w.x - s * w.y;
      float ti = c * w.y + s * w.x;
      buf[i0] = make_float2(u.x + tr, u.y + ti);
      buf[i1] = make_float2(u.x - tr, u.y - ti);
    }
    __syncthreads();
  }
}

// ---------------- fused FFT kernel: STFT pairs + resonance pairs + prep tail ----------------
// blk <  2048 : STFT (2 frames per block via complex pack)
// blk <  2560 : resonance frames (2 exponents per block via complex pack)
// blk >= 2560 : weight transposes + chain-weight bf16 packs (128 blocks)
__global__ __launch_bounds__(256) void k_fft(const float* __restrict__ audio,
                                             const float* __restrict__ resin,
                                             const float* __restrict__ Win,
                                             const float* __restrict__ Ws,
                                             const float* __restrict__ Wd,
                                             const float* __restrict__ bwIn,
                                             float* __restrict__ spec,
                                             float* __restrict__ frames,
                                             float* __restrict__ WT,
                                             float* __restrict__ WsT,
                                             float* __restrict__ WdT,
                                             short* __restrict__ Whg,
                                             short* __restrict__ Wlg) {
  __shared__ float2 buf[2048];
  int blk = blockIdx.x;

  if (blk >= 2560) {                  // ---- prep branch (no LDS use, no syncs) ----
    int i = (blk - 2560) * 256 + threadIdx.x;
    if (i < 32768) { int o = i >> 10, k = i & 1023; WT[k * 32 + o] = Win[i]; }
    if (i < 8192)  { int o2 = i >> 5, m = i & 31;   WsT[m * 256 + o2] = Ws[i]; }
    if (i < 8192)  { int c = i >> 8, o2 = i & 255;  WdT[o2 * 32 + c] = Wd[i]; }
    if (i < 16384) {
      // i = ((s*32+o)*32+m)*2 + w
      int w = i & 1, m = (i >> 1) & 31, o = (i >> 6) & 31, s = i >> 11;
      float val = bwIn[i];
      unsigned bits = __float_as_uint(val);
      float rem = val - __uint_as_float(bits & 0xffff0000u);
      int row = (s * 2 + w) * 32 + o;
      Whg[row * 32 + m] = (short)(bits >> 16);
      Wlg[row * 32 + m] = (short)(__float_as_uint(rem) >> 16);
    }
    return;
  }

  if (blk < 2048) {
    int b  = blk >> 6;
    int f0 = (blk & 63) * 2;      // frames f0, f0+1
    for (int j = threadIdx.x; j < 2048; j += 256) {
      float h = 0.5f - 0.5f * __cosf(0.0030679615757712823f * (float)j); // 2pi/2048
      int i1 = f0 * 256 + j;
      int i2 = i1 + 256;
      float a1 = (i1 < 32768) ? audio[b * 32768 + i1] : 0.f;
      float a2 = (i2 < 32768) ? audio[b * 32768 + i2] : 0.f;
      buf[__brev((unsigned)j) >> 21] = make_float2(a1 * h, a2 * h);
    }
    __syncthreads();
    fft2048_stages(buf, threadIdx.x);
    const float scale = 0.5f * 0.022097086912079608f;  // 0.5 / sqrt(2048)
    for (int k = threadIdx.x; k < 1024; k += 256) {
      float2 zk = buf[k];
      float2 zn = buf[(2048 - k) & 2047];
      float f1r = zk.x + zn.x, f1i = zk.y - zn.y;
      float f2r = zk.y + zn.y, f2i = zk.x - zn.x;
      spec[(b * 128 + f0) * 1024 + k]     = sqrtf(f1r * f1r + f1i * f1i) * scale;
      spec[(b * 128 + f0 + 1) * 1024 + k] = sqrtf(f2r * f2r + f2i * f2i) * scale;
    }
  } else {
    int r = blk - 2048;           // 0..511
    int c = r >> 4;
    int g = r & 15;               // frames 2g (exp 2g+1), 2g+1 (exp 2g+2)
    float e1 = (float)(2 * g + 1);
    for (int k = threadIdx.x; k < 2048; k += 256) {
      int kk = (k <= 1024) ? k : 2048 - k;   // Hermitian (real) extension
      float cv = resin[c * 1025 + kk];
      cv = fminf(fmaxf(cv, 0.f), 0.9999f);
      float m1 = __powf(cv, e1);
      float m2 = m1 * cv;
      buf[__brev((unsigned)k) >> 21] = make_float2(m1, m2);
    }
    __syncthreads();
    fft2048_stages(buf, threadIdx.x);
    for (int j = threadIdx.x; j < 2048; j += 256) {
      float h  = 0.5f - 0.5f * __cosf(0.0030679615757712823f * (float)j);
      float sc = h * (1.f / 2048.f);
      float2 z = buf[j];
      frames[(c * 32 + 2 * g) * 2048 + j]     = z.x * sc;
      frames[(c * 32 + 2 * g + 1) * 2048 + j] = z.y * sc;
    }
  }
}

// ---------------- proj_in: h0[b,o,t] = sum_k WT[k][o]*spec[b,t,k] + bias ----------------
__global__ __launch_bounds__(256) void k_proj_in(const float* __restrict__ spec,
                                                 const float* __restrict__ WT,
                                                 const float* __restrict__ bias,
                                                 float* __restrict__ h0) {
  __shared__ float specL[8][1024];
  __shared__ float red[32][8][8];   // [o][tt][p]
  int b  = blockIdx.x >> 4;
  int t0 = (blockIdx.x & 15) * 8;
  for (int i = threadIdx.x; i < 8192; i += 256) {
    int tt = i >> 10, k = i & 1023;
    specL[tt][k] = spec[(b * 128 + t0 + tt) * 1024 + k];
  }
  __syncthreads();
  int o = threadIdx.x & 31, p = threadIdx.x >> 5;
  float part[8] = {0.f,0.f,0.f,0.f,0.f,0.f,0.f,0.f};
  for (int i = 0; i < 128; ++i) {
    int k = p * 128 + ((i + p * 4) & 127);   // stagger: conflict-free banks across p
    float w = WT[k * 32 + o];
#pragma unroll
    for (int tt = 0; tt < 8; ++tt) part[tt] += w * specL[tt][k];
  }
#pragma unroll
  for (int tt = 0; tt < 8; ++tt) red[o][tt][p] = part[tt];
  __syncthreads();
  int oo = threadIdx.x >> 3, tt2 = threadIdx.x & 7;
  float s = bias[oo];
#pragma unroll
  for (int p2 = 0; p2 < 8; ++p2) s += red[oo][tt2][p2];
  h0[b * 4096 + oo * 128 + t0 + tt2] = s;
}

// ---------------- fused overlap-add + B-pack (separate launch: full occupancy) ----------------
__global__ __launch_bounds__(256) void k_obpack(const float* __restrict__ frames,
                                                short* __restrict__ Bh,
                                                short* __restrict__ Bl) {
  int c = blockIdx.x >> 4, o = blockIdx.x & 15;
  int r = threadIdx.x;
  bf16x8 hv, lv;
#pragma unroll
  for (int j = 0; j < 8; ++j) {
    int fo = 8 * o + j;
    int g  = fo >> 2;
    int j0 = ((fo & 3) << 8) + r;
    float val = frames[(c * 32 + g) * 2048 + j0];
    if (g > 0) val += frames[(c * 32 + g - 1) * 2048 + j0 + 1024];
    unsigned bits = __float_as_uint(val);
    float rem = val - __uint_as_float(bits & 0xffff0000u);
    hv[j] = (short)(bits >> 16);
    lv[j] = (short)(__float_as_uint(rem) >> 16);
  }
  int unit = (blockIdx.x * 16 + (r >> 4)) * 16 + (r & 15);
  ((bf16x8*)Bh)[unit] = hv;
  ((bf16x8*)Bl)[unit] = lv;
}

// ---------------- 8-block anticausal chain as per-step MFMA GEMM pairs ----------------
__global__ __launch_bounds__(1024) void k_chain(const float* __restrict__ h0,
                                                const short* __restrict__ Whg,
                                                const short* __restrict__ Wlg,
                                                const float* __restrict__ bb,
                                                float* __restrict__ accout) {
  __shared__ __align__(16) short Hh[192 * 40];   // rows stride 40 bf16 (80 B)
  __shared__ __align__(16) short Hl[192 * 40];
  __shared__ float Hf[128 * 33];                 // fp32 H for exact residual
  __shared__ float bL[256];
  __shared__ float red[16];
  int b = blockIdx.x, tid = threadIdx.x;

  for (int i = tid; i < 4096; i += 1024) {
    int t = i & 127;                 // h0 layout [o][t]
    int o = i >> 7;
    float val = h0[b * 4096 + i];
    Hf[t * 33 + o] = val;
    unsigned bits = __float_as_uint(val);
    float rem = val - __uint_as_float(bits & 0xffff0000u);
    Hh[t * 40 + o] = (short)(bits >> 16);
    Hl[t * 40 + o] = (short)(__float_as_uint(rem) >> 16);
  }
  for (int i = tid; i < 64 * 40; i += 1024) {    // zero pad rows 128..191
    Hh[128 * 40 + i] = 0;
    Hl[128 * 40 + i] = 0;
  }
  if (tid < 256) bL[tid] = bb[tid];
  __syncthreads();

  int wave = tid >> 6, lane = tid & 63;
  int quad = lane >> 4, l15 = lane & 15;
  int t0 = (wave & 7) * 16, o0 = (wave >> 3) * 16;
  int tD = t0 + quad * 4;          // D rows tD..tD+3
  int oD = o0 + l15;               // D col

  const bf16x8* Hh8 = (const bf16x8*)Hh;   // unit = row*5 + quad (40 bf16 = 5 units)
  const bf16x8* Hl8 = (const bf16x8*)Hl;
  const bf16x8* Wh8 = (const bf16x8*)Whg;  // unit = row*4 + quad (32 bf16 = 4 units)
  const bf16x8* Wl8 = (const bf16x8*)Wlg;

  float accsum[4] = {0.f, 0.f, 0.f, 0.f};
  const int DIL[8] = {1, 2, 4, 8, 16, 32, 64, 1};

#pragma unroll
  for (int s = 0; s < 8; ++s) {
    int arow = t0 + l15;
    int frow = arow + DIL[s];        // <= 191, pad rows give zeros
    bf16x8 Ah = Hh8[arow * 5 + quad];
    bf16x8 Al = Hl8[arow * 5 + quad];
    bf16x8 Fh = Hh8[frow * 5 + quad];
    bf16x8 Fl = Hl8[frow * 5 + quad];
    int w0row = ((s * 2 + 0) * 32 + oD) * 4 + quad;
    int w1row = ((s * 2 + 1) * 32 + oD) * 4 + quad;
    bf16x8 B0h = Wh8[w0row], B0l = Wl8[w0row];
    bf16x8 B1h = Wh8[w1row], B1l = Wl8[w1row];
    float bias = bL[s * 32 + oD];
    f32x4 acc = {bias, bias, bias, bias};
    MFMA16(acc, Ah, B0h); MFMA16(acc, Ah, B0l); MFMA16(acc, Al, B0h);
    MFMA16(acc, Fh, B1h); MFMA16(acc, Fh, B1l); MFMA16(acc, Fl, B1h);
    float hnew[4], lmax = 0.f;
#pragma unroll
    for (int r = 0; r < 4; ++r) {
      float sv = acc[r];
      sv = (sv > 0.f) ? sv : 0.2f * sv;       // leaky_relu 0.2
      sv += Hf[(tD + r) * 33 + oD];           // residual (exact fp32)
      hnew[r] = sv;
      lmax = fmaxf(lmax, fabsf(sv));
    }
#pragma unroll
    for (int off = 32; off > 0; off >>= 1)
      lmax = fmaxf(lmax, __shfl_down(lmax, off, 64));
    if (lane == 0) red[wave] = lmax;
    __syncthreads();                 // red visible; all H reads of this step done
    float mx = red[0];
#pragma unroll
    for (int i = 1; i < 16; ++i) mx = fmaxf(mx, red[i]);
    float nm = 1.f / (mx + 1e-8f);
#pragma unroll
    for (int r = 0; r < 4; ++r) {
      float hv = hnew[r] * nm;
      accsum[r] += hv;
      int t = tD + r;
      Hf[t * 33 + oD] = hv;
      unsigned bits = __float_as_uint(hv);
      float rem = hv - __uint_as_float(bits & 0xffff0000u);
      Hh[t * 40 + oD] = (short)(bits >> 16);
      Hl[t * 40 + oD] = (short)(__float_as_uint(rem) >> 16);
    }
    __syncthreads();                 // new H visible for next step
  }
#pragma unroll
  for (int r = 0; r < 4; ++r)
    accout[b * 4096 + (tD + r) * 32 + oD] = accsum[r];
}

// ---------------- sparse + dense, 4 t per block (4x weight reuse + ILP) ----------------
__global__ __launch_bounds__(256) void k_sparse_dense(const float* __restrict__ acc,
                                                      const float* __restrict__ WsT,
                                                      const float* __restrict__ bs,
                                                      const float* __restrict__ WdT,
                                                      const float* __restrict__ bd,
                                                      float* __restrict__ out_sparse,
                                                      float* __restrict__ v) {
  __shared__ float accL[4][32];
  __shared__ float sL[4][256];
  __shared__ float red[8][4][32];   // [p][tt][c]
  int b = blockIdx.x >> 5, tq = blockIdx.x & 31;
  int t0 = tq * 4;
  int tid = threadIdx.x;
  if (tid < 128)
    accL[tid >> 5][tid & 31] = acc[b * 4096 + (t0 + (tid >> 5)) * 32 + (tid & 31)];
  __syncthreads();
  float bsv = bs[tid];
  float s0 = bsv, s1 = bsv, s2 = bsv, s3 = bsv;
  for (int m = 0; m < 32; ++m) {
    float w = WsT[m * 256 + tid];
    s0 += w * accL[0][m]; s1 += w * accL[1][m];
    s2 += w * accL[2][m]; s3 += w * accL[3][m];
  }
  s0 = fmaxf(s0, 0.f); s1 = fmaxf(s1, 0.f); s2 = fmaxf(s2, 0.f); s3 = fmaxf(s3, 0.f);
  float* os = out_sparse + b * 32768 + tid * 128 + t0;
  os[0] = s0; os[1] = s1; os[2] = s2; os[3] = s3;
  sL[0][tid] = s0; sL[1][tid] = s1; sL[2][tid] = s2; sL[3][tid] = s3;
  __syncthreads();
  int c = tid & 31, p = tid >> 5;
  float p0 = 0.f, p1 = 0.f, p2 = 0.f, p3 = 0.f;
  for (int jj = 0; jj < 32; ++jj) {
    int o2 = p * 32 + jj;
    float w = WdT[o2 * 32 + c];
    p0 += w * sL[0][o2]; p1 += w * sL[1][o2];
    p2 += w * sL[2][o2]; p3 += w * sL[3][o2];
  }
  red[p][0][c] = p0; red[p][1][c] = p1; red[p][2][c] = p2; red[p][3][c] = p3;
  __syncthreads();
  if (tid < 128) {
    int tt = tid >> 5, cc = tid & 31;
    float vv = bd[cc];
#pragma unroll
    for (int p2i = 0; p2i < 8; ++p2i) vv += red[p2i][tt][cc];
    v[b * 4096 + cc * 128 + t0 + tt] = vv;
  }
}

// ---------------- final conv as MFMA GEMM, v5 structure: single-phase K=512 ----------------
// Full K=512 A in LDS (AH/AL 32x520 = 66.5 KB + vwin 6 KB = 72.7 KB -> 2
// blocks/CU, 4 waves/SIMD), ONE expand pass, ONE 16-ks MFMA loop, 3 barriers.
// XCD-group swizzle: all 32 b-blocks of one (j,uc) share one XCD's L2 slice.
__global__ __launch_bounds__(512, 4) void k_conv(const float* __restrict__ v,
                                                 const short* __restrict__ Bh,
                                                 const short* __restrict__ Bl,
                                                 float* __restrict__ y) {
  __shared__ __align__(16) short AH[32 * 520];   // [row 32][K 512 + pad 8]
  __shared__ __align__(16) short AL[32 * 520];
  __shared__ float vwin[2][16][48];              // [c-half][c_local][ii]

  // --- XCD-group swizzle: group e (20 of them) -> XCD e%8; batches fill slots.
  int xcd  = blockIdx.x & 7;
  int slot = blockIdx.x >> 3;
  int e, b;
  if      (slot < 32) { e = xcd;      b = slot; }
  else if (slot < 64) { e = xcd + 8;  b = slot - 32; }
  else                { e = (xcd < 4) ? (xcd + 16) : (xcd + 12);
                        b = (xcd < 4) ? (slot - 64) : (slot - 48); }
  int j, uc;
  if      (e < 2)  { j = 0; uc = e; }
  else if (e < 6)  { j = 1; uc = e - 2; }
  else if (e < 12) { j = 2; uc = e - 6; }
  else             { j = 3; uc = e - 12; }
  int D0 = 32 * j - 16 * uc;       // d = D0 - 15 + ii, ii in [0,46]

  // stage compact v windows (both c-halves): 2*16*47 floats
  for (int i = threadIdx.x; i < 1504; i += 512) {
    int ii = i % 47;
    int r  = i / 47;               // 0..31
    int c  = r & 15, ph = r >> 4;
    int d  = D0 - 15 + ii;
    vwin[ph][c][ii] = (d >= 0 && d < 128)
        ? v[b * 4096 + (16 * ph + c) * 128 + d] : 0.f;
  }
  __syncthreads();

  // expand Toeplitz A (hi/lo split), full K=512: 32 rows x 256 kk-pairs
  short2* AH2 = (short2*)AH;
  short2* AL2 = (short2*)AL;
  for (int i = threadIdx.x; i < 8192; i += 512) {
    int kk2 = i & 255;             // kk = 2*kk2 (pair shares c)
    int row = i >> 8;              // 0..31
    int c   = kk2 >> 3;            // 0..31
    int uu  = (kk2 & 7) * 2;
    int ii  = row - uu + 15;
    float v0 = vwin[c >> 4][c & 15][ii];
    float v1 = vwin[c >> 4][c & 15][ii - 1];
    unsigned w0 = __float_as_uint(v0), w1 = __float_as_uint(v1);
    float r0 = v0 - __uint_as_float(w0 & 0xffff0000u);
    float r1 = v1 - __uint_as_float(w1 & 0xffff0000u);
    int u2 = row * 260 + kk2;      // short2 units, row stride 260 (=520 shorts)
    AH2[u2] = make_short2((short)(w0 >> 16), (short)(w1 >> 16));
    AL2[u2] = make_short2((short)(__float_as_uint(r0) >> 16),
                          (short)(__float_as_uint(r1) >> 16));
  }
  __syncthreads();

  int lane = threadIdx.x & 63, wave = threadIdx.x >> 6;
  int quad = lane >> 4, l15 = lane & 15;
  int cq   = quad >> 1;            // low bit of c
  int og   = 2 * uc + (quad & 1);  // global u-octet
  int nt0  = wave * 2;             // 8 waves x 2 nt = 16 nt

  f32x4 acc00 = (f32x4)0.f, acc01 = (f32x4)0.f;   // [qs][t]
  f32x4 acc10 = (f32x4)0.f, acc11 = (f32x4)0.f;

  const bf16x8* AH8 = (const bf16x8*)AH;
  const bf16x8* AL8 = (const bf16x8*)AL;
  const bf16x8* Bh8 = (const bf16x8*)Bh;
  const bf16x8* Bl8 = (const bf16x8*)Bl;

  int abase0 = l15 * 65 + quad;          // bf16x8 units, row stride 65 (=520 shorts)
  int abase1 = (16 + l15) * 65 + quad;

#pragma unroll
  for (int ks = 0; ks < 16; ++ks) {
    bf16x8 ah0 = AH8[abase0 + ks * 4];
    bf16x8 al0 = AL8[abase0 + ks * 4];
    bf16x8 ah1 = AH8[abase1 + ks * 4];
    bf16x8 al1 = AL8[abase1 + ks * 4];
    int c   = 2 * ks + cq;
    int bb0 = (c * 16 + og) * 256 + l15;
    bf16x8 bh0 = Bh8[bb0 + nt0 * 16];
    bf16x8 bl0 = Bl8[bb0 + nt0 * 16];
    bf16x8 bh1 = Bh8[bb0 + (nt0 + 1) * 16];
    bf16x8 bl1 = Bl8[bb0 + (nt0 + 1) * 16];
    MFMA16(acc00, ah0, bh0); MFMA16(acc00, ah0, bl0); MFMA16(acc00, al0, bh0);
    MFMA16(acc10, ah1, bh0); MFMA16(acc10, ah1, bl0); MFMA16(acc10, al1, bh0);
    MFMA16(acc01, ah0, bh1); MFMA16(acc01, ah0, bl1); MFMA16(acc01, al0, bh1);
    MFMA16(acc11, ah1, bh1); MFMA16(acc11, ah1, bl1); MFMA16(acc11, al1, bh1);
  }

  {
    float* yb0 = y + b * 32768 + (32 * j + 0 * 16 + quad * 4) * 256 + l15;
    float* yb1 = y + b * 32768 + (32 * j + 1 * 16 + quad * 4) * 256 + l15;
#pragma unroll
    for (int reg = 0; reg < 4; ++reg) {
      atomicAdd(yb0 + reg * 256 + (nt0 + 0) * 16, acc00[reg]);
      atomicAdd(yb0 + reg * 256 + (nt0 + 1) * 16, acc01[reg]);
      atomicAdd(yb1 + reg * 256 + (nt0 + 0) * 16, acc10[reg]);
      atomicAdd(yb1 + reg * 256 + (nt0 + 1) * 16, acc11[reg]);
    }
  }
}

extern "C" void kernel_launch(void* const* d_in, const int* in_sizes, int n_in,
                              void* d_out, int out_size, void* d_ws, size_t ws_size,
                              hipStream_t stream) {
  const float* audio = (const float*)d_in[0];
  const float* Win   = (const float*)d_in[1];
  const float* bin   = (const float*)d_in[2];
  const float* bw    = (const float*)d_in[3];
  const float* bb    = (const float*)d_in[4];
  const float* Ws    = (const float*)d_in[5];
  const float* bs    = (const float*)d_in[6];
  const float* Wd    = (const float*)d_in[7];
  const float* bd    = (const float*)d_in[8];
  const float* reson = (const float*)d_in[9];

  float* out = (float*)d_out;           // [0,1048576) = y ; [1048576,2097152) = sparse
  float* ws  = (float*)d_ws;

  float* spec   = ws + WS_SPEC;
  float* h0     = ws + WS_H0;
  float* accb   = ws + WS_ACC;
  float* vbuf   = ws + WS_V;
  float* WT     = ws + WS_WTIN;
  float* WsT    = ws + WS_WST;
  float* WdT    = ws + WS_WDT;
  float* frames = ws + WS_FRAMES;
  // WS_RES region (dead after fusing overlap-add into k_obpack) -> bf16 B packs
  short* Bh = (short*)(ws + WS_RES);               // 1,048,576 bf16 = 2 MB
  short* Bl = (short*)(ws + WS_RES + 524288u);     // 1,048,576 bf16 = 2 MB
  // chain-weight packs live in WS_V until k_sparse_dense overwrites it (after k_chain)
  short* Whg = (short*)(ws + WS_V);                // 16384 bf16 = 32 KB
  short* Wlg = (short*)(ws + WS_V + 8192u);        // 16384 bf16 = 32 KB

  // zero y region (atomicAdd target); d_out is poisoned before every launch
  hipMemsetAsync(d_out, 0, 1048576u * sizeof(float), stream);

  k_fft<<<2688, 256, 0, stream>>>(audio, reson, Win, Ws, Wd, bw,
                                  spec, frames, WT, WsT, WdT, Whg, Wlg);
  k_obpack<<<512, 256, 0, stream>>>(frames, Bh, Bl);
  k_proj_in<<<512, 256, 0, stream>>>(spec, WT, bin, h0);
  k_chain<<<32, 1024, 0, stream>>>(h0, Whg, Wlg, bb, accb);
  k_sparse_dense<<<1024, 256, 0, stream>>>(accb, WsT, bs, WdT, bd, out + 1048576, vbuf);
  k_conv<<<640, 512, 0, stream>>>(vbuf, Bh, Bl, out);
}

// Round 6
// 188.573 us; speedup vs baseline: 1.0470x; 1.0307x over previous
//
#include <hip/hip_runtime.h>

#define PI_F 3.14159265358979323846f

typedef short bf16x8 __attribute__((ext_vector_type(8)));
typedef float f32x4 __attribute__((ext_vector_type(4)));

#define MFMA16(acc, a, b) \
  acc = __builtin_amdgcn_mfma_f32_16x16x32_bf16(a, b, acc, 0, 0, 0)

// ---------------- workspace layout (float offsets) ----------------
#define WS_SPEC   0u          // 32*128*1024  [b][t][k]
#define WS_H0     4194304u    // 32*32*128    [b][o][t]
#define WS_ACC    4325376u    // 32*128*32    [b][t][o]
#define WS_V      4456448u    // 32*32*128    [b][c][t]; ALSO: prep stashes the
                              // chain-weight bf16 packs in the first 16384 floats
                              // (region only becomes v after k_sparse_dense,
                              // which runs after k_chain has consumed the packs)
#define WS_WTIN   4587520u    // 1024*32      [k][o]
#define WS_WST    4620288u    // 32*256       [m][o2]
#define WS_WDT    4628480u    // 256*32       [o2][c]
#define WS_FRAMES 4636672u    // 32*32*2048   [c][f][j]
#define WS_RES    6733824u    // (dead: res assembly fused into obpack) -> Bh/Bl packs
// total 7782400 floats = ~29.7 MB

// ---- 2048-pt complex DIT FFT, bit-reversed input, 256 thr ----
// v7: sincosf budget 32 -> 8 per thread with IDENTICAL LDS pattern/occupancy.
// Stages 0-2: exact constant twiddles. Stages 3-8 (half<=256): all 4 butterflies
// of a thread share j = tid & (half-1) (256 == 0 mod half) -> ONE sincosf each.
// Stage 9: j's differ by exactly -pi/2 -> (c,s) and (s,-c). Stage 10: j's step
// by -pi/4 -> 1 sincosf + 3 exact sqrt2/2 rotations. Twiddles match the old
// per-butterfly __sincosf to <=1 ulp (stages 3-8 bitwise-identical).
#define BFLY(I0, I1, C, S)                                   \
  { float2 u = buf[I0]; float2 w = buf[I1];                  \
    float tr = (C) * w.x - (S) * w.y;                        \
    float ti = (C) * w.y + (S) * w.x;                        \
    buf[I0] = make_float2(u.x + tr, u.y + ti);               \
    buf[I1] = make_float2(u.x - tr, u.y - ti); }

__device__ __forceinline__ void fft2048_stages(float2* buf, int tid) {
  // stage 0: w = 1 (pure add/sub)
  for (int t = tid; t < 1024; t += 256) {
    int i0 = 2 * t, i1 = i0 + 1;
    float2 u = buf[i0], w = buf[i1];
    buf[i0] = make_float2(u.x + w.x, u.y + w.y);
    buf[i1] = make_float2(u.x - w.x, u.y - w.y);
  }
  __syncthreads();
  // stage 1: j=0 -> w=1 ; j=1 -> w=-i (tr=w.y, ti=-w.x)
  for (int t = tid; t < 1024; t += 256) {
    int j  = t & 1;
    int i0 = ((t >> 1) << 2) + j, i1 = i0 + 2;
    float2 u = buf[i0], w = buf[i1];
    float tr = j ? w.y : w.x;
    float ti = j ? -w.x : w.y;
    buf[i0] = make_float2(u.x + tr, u.y + ti);
    buf[i1] = make_float2(u.x - tr, u.y - ti);
  }
  __syncthreads();
  // stage 2: w = e^{-i pi j/4}, j=0..3: (1,0) (R,-R) (0,-1) (-R,-R), R=sqrt(2)/2
  for (int t = tid; t < 1024; t += 256) {
    int j  = t & 3;
    int i0 = ((t >> 2) << 3) + j, i1 = i0 + 4;
    const float R = 0.7071067811865476f;
    float c = (j == 0) ? 1.f : ((j == 1) ? R : ((j == 2) ? 0.f : -R));
    float s = (j == 0) ? 0.f : ((j == 2) ? -1.f : -R);
    BFLY(i0, i1, c, s);
  }
  __syncthreads();
  // stages 3..8: half = 8..256; j = tid & (half-1) shared by all 4 butterflies
  for (int stage = 3; stage <= 8; ++stage) {
    int half = 1 << stage;
    int j = tid & (half - 1);
    float s, c;
    __sincosf(-PI_F / (float)half * (float)j, &s, &c);
    for (int t = tid; t < 1024; t += 256) {
      int i0 = ((t >> stage) << (stage + 1)) + j;
      int i1 = i0 + half;
      BFLY(i0, i1, c, s);
    }
    __syncthreads();
  }
  // stage 9: half=512. t = tid, tid+512 use theta = -pi*tid/512 -> (c,s);
  // t = tid+256, tid+768 use theta - pi/2 -> (s,-c).
  {
    float s, c;
    __sincosf(-PI_F / 512.f * (float)tid, &s, &c);
    BFLY(tid,        tid + 512,  c, s);
    BFLY(1024 + tid, 1536 + tid, c, s);
    BFLY(tid + 256,  tid + 768,  s, -c);
    BFLY(1280 + tid, 1792 + tid, s, -c);
  }
  __syncthreads();
  // stage 10: half=1024. theta_k = -pi*(tid+256k)/1024 = theta0 - k*pi/4.
  {
    float s0, c0;
    __sincosf(-PI_F / 1024.f * (float)tid, &s0, &c0);
    const float R = 0.7071067811865476f;
    BFLY(tid,       tid + 1024, c0, s0);
    BFLY(tid + 256, tid + 1280, R * (c0 + s0), R * (s0 - c0));
    BFLY(tid + 512, tid + 1536, s0, -c0);
    BFLY(tid + 768, tid + 1792, R * (s0 - c0), -R * (s0 + c0));
  }
  __syncthreads();
}

// ---------------- fused FFT kernel: STFT pairs + resonance pairs + prep tail ----------------
// blk <  2048 : STFT (2 frames per block via complex pack)
// blk <  2560 : resonance frames (2 exponents per block via complex pack)
// blk >= 2560 : weight transposes + chain-weight bf16 packs (128 blocks)
__global__ __launch_bounds__(256) void k_fft(const float* __restrict__ audio,
                                             const float* __restrict__ resin,
                                             const float* __restrict__ Win,
                                             const float* __restrict__ Ws,
                                             const float* __restrict__ Wd,
                                             const float* __restrict__ bwIn,
                                             float* __restrict__ spec,
                                             float* __restrict__ frames,
                                             float* __restrict__ WT,
                                             float* __restrict__ WsT,
                                             float* __restrict__ WdT,
                                             short* __restrict__ Whg,
                                             short* __restrict__ Wlg) {
  __shared__ float2 buf[2048];
  int blk = blockIdx.x;

  if (blk >= 2560) {                  // ---- prep branch (no LDS use, no syncs) ----
    int i = (blk - 2560) * 256 + threadIdx.x;
    if (i < 32768) { int o = i >> 10, k = i & 1023; WT[k * 32 + o] = Win[i]; }
    if (i < 8192)  { int o2 = i >> 5, m = i & 31;   WsT[m * 256 + o2] = Ws[i]; }
    if (i < 8192)  { int c = i >> 8, o2 = i & 255;  WdT[o2 * 32 + c] = Wd[i]; }
    if (i < 16384) {
      // i = ((s*32+o)*32+m)*2 + w
      int w = i & 1, m = (i >> 1) & 31, o = (i >> 6) & 31, s = i >> 11;
      float val = bwIn[i];
      unsigned bits = __float_as_uint(val);
      float rem = val - __uint_as_float(bits & 0xffff0000u);
      int row = (s * 2 + w) * 32 + o;
      Whg[row * 32 + m] = (short)(bits >> 16);
      Wlg[row * 32 + m] = (short)(__float_as_uint(rem) >> 16);
    }
    return;
  }

  if (blk < 2048) {
    int b  = blk >> 6;
    int f0 = (blk & 63) * 2;      // frames f0, f0+1
    for (int j = threadIdx.x; j < 2048; j += 256) {
      float h = 0.5f - 0.5f * __cosf(0.0030679615757712823f * (float)j); // 2pi/2048
      int i1 = f0 * 256 + j;
      int i2 = i1 + 256;
      float a1 = (i1 < 32768) ? audio[b * 32768 + i1] : 0.f;
      float a2 = (i2 < 32768) ? audio[b * 32768 + i2] : 0.f;
      buf[__brev((unsigned)j) >> 21] = make_float2(a1 * h, a2 * h);
    }
    __syncthreads();
    fft2048_stages(buf, threadIdx.x);
    const float scale = 0.5f * 0.022097086912079608f;  // 0.5 / sqrt(2048)
    for (int k = threadIdx.x; k < 1024; k += 256) {
      float2 zk = buf[k];
      float2 zn = buf[(2048 - k) & 2047];
      float f1r = zk.x + zn.x, f1i = zk.y - zn.y;
      float f2r = zk.y + zn.y, f2i = zk.x - zn.x;
      spec[(b * 128 + f0) * 1024 + k]     = sqrtf(f1r * f1r + f1i * f1i) * scale;
      spec[(b * 128 + f0 + 1) * 1024 + k] = sqrtf(f2r * f2r + f2i * f2i) * scale;
    }
  } else {
    int r = blk - 2048;           // 0..511
    int c = r >> 4;
    int g = r & 15;               // frames 2g (exp 2g+1), 2g+1 (exp 2g+2)
    float e1 = (float)(2 * g + 1);
    for (int k = threadIdx.x; k < 2048; k += 256) {
      int kk = (k <= 1024) ? k : 2048 - k;   // Hermitian (real) extension
      float cv = resin[c * 1025 + kk];
      cv = fminf(fmaxf(cv, 0.f), 0.9999f);
      float m1 = __powf(cv, e1);
      float m2 = m1 * cv;
      buf[__brev((unsigned)k) >> 21] = make_float2(m1, m2);
    }
    __syncthreads();
    fft2048_stages(buf, threadIdx.x);
    for (int j = threadIdx.x; j < 2048; j += 256) {
      float h  = 0.5f - 0.5f * __cosf(0.0030679615757712823f * (float)j);
      float sc = h * (1.f / 2048.f);
      float2 z = buf[j];
      frames[(c * 32 + 2 * g) * 2048 + j]     = z.x * sc;
      frames[(c * 32 + 2 * g + 1) * 2048 + j] = z.y * sc;
    }
  }
}

// ---------------- proj_in: h0[b,o,t] = sum_k WT[k][o]*spec[b,t,k] + bias ----------------
__global__ __launch_bounds__(256) void k_proj_in(const float* __restrict__ spec,
                                                 const float* __restrict__ WT,
                                                 const float* __restrict__ bias,
                                                 float* __restrict__ h0) {
  __shared__ float specL[8][1024];
  __shared__ float red[32][8][8];   // [o][tt][p]
  int b  = blockIdx.x >> 4;
  int t0 = (blockIdx.x & 15) * 8;
  for (int i = threadIdx.x; i < 8192; i += 256) {
    int tt = i >> 10, k = i & 1023;
    specL[tt][k] = spec[(b * 128 + t0 + tt) * 1024 + k];
  }
  __syncthreads();
  int o = threadIdx.x & 31, p = threadIdx.x >> 5;
  float part[8] = {0.f,0.f,0.f,0.f,0.f,0.f,0.f,0.f};
  for (int i = 0; i < 128; ++i) {
    int k = p * 128 + ((i + p * 4) & 127);   // stagger: conflict-free banks across p
    float w = WT[k * 32 + o];
#pragma unroll
    for (int tt = 0; tt < 8; ++tt) part[tt] += w * specL[tt][k];
  }
#pragma unroll
  for (int tt = 0; tt < 8; ++tt) red[o][tt][p] = part[tt];
  __syncthreads();
  int oo = threadIdx.x >> 3, tt2 = threadIdx.x & 7;
  float s = bias[oo];
#pragma unroll
  for (int p2 = 0; p2 < 8; ++p2) s += red[oo][tt2][p2];
  h0[b * 4096 + oo * 128 + t0 + tt2] = s;
}

// ---------------- fused overlap-add + B-pack (separate launch: full occupancy) ----------------
__global__ __launch_bounds__(256) void k_obpack(const float* __restrict__ frames,
                                                short* __restrict__ Bh,
                                                short* __restrict__ Bl) {
  int c = blockIdx.x >> 4, o = blockIdx.x & 15;
  int r = threadIdx.x;
  bf16x8 hv, lv;
#pragma unroll
  for (int j = 0; j < 8; ++j) {
    int fo = 8 * o + j;
    int g  = fo >> 2;
    int j0 = ((fo & 3) << 8) + r;
    float val = frames[(c * 32 + g) * 2048 + j0];
    if (g > 0) val += frames[(c * 32 + g - 1) * 2048 + j0 + 1024];
    unsigned bits = __float_as_uint(val);
    float rem = val - __uint_as_float(bits & 0xffff0000u);
    hv[j] = (short)(bits >> 16);
    lv[j] = (short)(__float_as_uint(rem) >> 16);
  }
  int unit = (blockIdx.x * 16 + (r >> 4)) * 16 + (r & 15);
  ((bf16x8*)Bh)[unit] = hv;
  ((bf16x8*)Bl)[unit] = lv;
}

// ---------------- 8-block anticausal chain as per-step MFMA GEMM pairs ----------------
__global__ __launch_bounds__(1024) void k_chain(const float* __restrict__ h0,
                                                const short* __restrict__ Whg,
                                                const short* __restrict__ Wlg,
                                                const float* __restrict__ bb,
                                                float* __restrict__ accout) {
  __shared__ __align__(16) short Hh[192 * 40];   // rows stride 40 bf16 (80 B)
  __shared__ __align__(16) short Hl[192 * 40];
  __shared__ float Hf[128 * 33];                 // fp32 H for exact residual
  __shared__ float bL[256];
  __shared__ float red[16];
  int b = blockIdx.x, tid = threadIdx.x;

  for (int i = tid; i < 4096; i += 1024) {
    int t = i & 127;                 // h0 layout [o][t]
    int o = i >> 7;
    float val = h0[b * 4096 + i];
    Hf[t * 33 + o] = val;
    unsigned bits = __float_as_uint(val);
    float rem = val - __uint_as_float(bits & 0xffff0000u);
    Hh[t * 40 + o] = (short)(bits >> 16);
    Hl[t * 40 + o] = (short)(__float_as_uint(rem) >> 16);
  }
  for (int i = tid; i < 64 * 40; i += 1024) {    // zero pad rows 128..191
    Hh[128 * 40 + i] = 0;
    Hl[128 * 40 + i] = 0;
  }
  if (tid < 256) bL[tid] = bb[tid];
  __syncthreads();

  int wave = tid >> 6, lane = tid & 63;
  int quad = lane >> 4, l15 = lane & 15;
  int t0 = (wave & 7) * 16, o0 = (wave >> 3) * 16;
  int tD = t0 + quad * 4;          // D rows tD..tD+3
  int oD = o0 + l15;               // D col

  const bf16x8* Hh8 = (const bf16x8*)Hh;   // unit = row*5 + quad (40 bf16 = 5 units)
  const bf16x8* Hl8 = (const bf16x8*)Hl;
  const bf16x8* Wh8 = (const bf16x8*)Whg;  // unit = row*4 + quad (32 bf16 = 4 units)
  const bf16x8* Wl8 = (const bf16x8*)Wlg;

  float accsum[4] = {0.f, 0.f, 0.f, 0.f};
  const int DIL[8] = {1, 2, 4, 8, 16, 32, 64, 1};

#pragma unroll
  for (int s = 0; s < 8; ++s) {
    int arow = t0 + l15;
    int frow = arow + DIL[s];        // <= 191, pad rows give zeros
    bf16x8 Ah = Hh8[arow * 5 + quad];
    bf16x8 Al = Hl8[arow * 5 + quad];
    bf16x8 Fh = Hh8[frow * 5 + quad];
    bf16x8 Fl = Hl8[frow * 5 + quad];
    int w0row = ((s * 2 + 0) * 32 + oD) * 4 + quad;
    int w1row = ((s * 2 + 1) * 32 + oD) * 4 + quad;
    bf16x8 B0h = Wh8[w0row], B0l = Wl8[w0row];
    bf16x8 B1h = Wh8[w1row], B1l = Wl8[w1row];
    float bias = bL[s * 32 + oD];
    f32x4 acc = {bias, bias, bias, bias};
    MFMA16(acc, Ah, B0h); MFMA16(acc, Ah, B0l); MFMA16(acc, Al, B0h);
    MFMA16(acc, Fh, B1h); MFMA16(acc, Fh, B1l); MFMA16(acc, Fl, B1h);
    float hnew[4], lmax = 0.f;
#pragma unroll
    for (int r = 0; r < 4; ++r) {
      float sv = acc[r];
      sv = (sv > 0.f) ? sv : 0.2f * sv;       // leaky_relu 0.2
      sv += Hf[(tD + r) * 33 + oD];           // residual (exact fp32)
      hnew[r] = sv;
      lmax = fmaxf(lmax, fabsf(sv));
    }
#pragma unroll
    for (int off = 32; off > 0; off >>= 1)
      lmax = fmaxf(lmax, __shfl_down(lmax, off, 64));
    if (lane == 0) red[wave] = lmax;
    __syncthreads();                 // red visible; all H reads of this step done
    float mx = red[0];
#pragma unroll
    for (int i = 1; i < 16; ++i) mx = fmaxf(mx, red[i]);
    float nm = 1.f / (mx + 1e-8f);
#pragma unroll
    for (int r = 0; r < 4; ++r) {
      float hv = hnew[r] * nm;
      accsum[r] += hv;
      int t = tD + r;
      Hf[t * 33 + oD] = hv;
      unsigned bits = __float_as_uint(hv);
      float rem = hv - __uint_as_float(bits & 0xffff0000u);
      Hh[t * 40 + oD] = (short)(bits >> 16);
      Hl[t * 40 + oD] = (short)(__float_as_uint(rem) >> 16);
    }
    __syncthreads();                 // new H visible for next step
  }
#pragma unroll
  for (int r = 0; r < 4; ++r)
    accout[b * 4096 + (tD + r) * 32 + oD] = accsum[r];
}

// ---------------- sparse + dense, 4 t per block (4x weight reuse + ILP) ----------------
__global__ __launch_bounds__(256) void k_sparse_dense(const float* __restrict__ acc,
                                                      const float* __restrict__ WsT,
                                                      const float* __restrict__ bs,
                                                      const float* __restrict__ WdT,
                                                      const float* __restrict__ bd,
                                                      float* __restrict__ out_sparse,
                                                      float* __restrict__ v) {
  __shared__ float accL[4][32];
  __shared__ float sL[4][256];
  __shared__ float red[8][4][32];   // [p][tt][c]
  int b = blockIdx.x >> 5, tq = blockIdx.x & 31;
  int t0 = tq * 4;
  int tid = threadIdx.x;
  if (tid < 128)
    accL[tid >> 5][tid & 31] = acc[b * 4096 + (t0 + (tid >> 5)) * 32 + (tid & 31)];
  __syncthreads();
  float bsv = bs[tid];
  float s0 = bsv, s1 = bsv, s2 = bsv, s3 = bsv;
  for (int m = 0; m < 32; ++m) {
    float w = WsT[m * 256 + tid];
    s0 += w * accL[0][m]; s1 += w * accL[1][m];
    s2 += w * accL[2][m]; s3 += w * accL[3][m];
  }
  s0 = fmaxf(s0, 0.f); s1 = fmaxf(s1, 0.f); s2 = fmaxf(s2, 0.f); s3 = fmaxf(s3, 0.f);
  float* os = out_sparse + b * 32768 + tid * 128 + t0;
  os[0] = s0; os[1] = s1; os[2] = s2; os[3] = s3;
  sL[0][tid] = s0; sL[1][tid] = s1; sL[2][tid] = s2; sL[3][tid] = s3;
  __syncthreads();
  int c = tid & 31, p = tid >> 5;
  float p0 = 0.f, p1 = 0.f, p2 = 0.f, p3 = 0.f;
  for (int jj = 0; jj < 32; ++jj) {
    int o2 = p * 32 + jj;
    float w = WdT[o2 * 32 + c];
    p0 += w * sL[0][o2]; p1 += w * sL[1][o2];
    p2 += w * sL[2][o2]; p3 += w * sL[3][o2];
  }
  red[p][0][c] = p0; red[p][1][c] = p1; red[p][2][c] = p2; red[p][3][c] = p3;
  __syncthreads();
  if (tid < 128) {
    int tt = tid >> 5, cc = tid & 31;
    float vv = bd[cc];
#pragma unroll
    for (int p2i = 0; p2i < 8; ++p2i) vv += red[p2i][tt][cc];
    v[b * 4096 + cc * 128 + t0 + tt] = vv;
  }
}

// ---------------- final conv as MFMA GEMM, v4 two-phase (REVERTED from v5) ----------------
// v5/v6 post-mortem: single-phase K=512 (72.7 KB LDS) dropped blocks/CU 4->2 ->
// 16 waves/CU vs v4's 32 -> ~5us regression. k_conv is LATENCY-bound: occupancy
// is the binding resource; v4's 39.9 KB two-phase keeps 4 blocks/CU (full 32
// waves). This is the exact round-3 code (best total, 189.45).
// XCD-group swizzle: all 32 b-blocks of one (j,uc) share one XCD's L2 slice.
__global__ __launch_bounds__(512, 4) void k_conv(const float* __restrict__ v,
                                                 const short* __restrict__ Bh,
                                                 const short* __restrict__ Bl,
                                                 float* __restrict__ y) {
  __shared__ __align__(16) short AH[32 * 264];   // [row 32][K 256 + pad 8]
  __shared__ __align__(16) short AL[32 * 264];
  __shared__ float vwin[2][16][48];              // [c-half][c_local][ii]

  // --- XCD-group swizzle: group e (20 of them) -> XCD e%8; batches fill slots.
  int xcd  = blockIdx.x & 7;
  int slot = blockIdx.x >> 3;
  int e, b;
  if      (slot < 32) { e = xcd;      b = slot; }
  else if (slot < 64) { e = xcd + 8;  b = slot - 32; }
  else                { e = (xcd < 4) ? (xcd + 16) : (xcd + 12);
                        b = (xcd < 4) ? (slot - 64) : (slot - 48); }
  int j, uc;
  if      (e < 2)  { j = 0; uc = e; }
  else if (e < 6)  { j = 1; uc = e - 2; }
  else if (e < 12) { j = 2; uc = e - 6; }
  else             { j = 3; uc = e - 12; }
  int D0 = 32 * j - 16 * uc;       // d = D0 - 15 + ii, ii in [0,46]

  // stage compact v windows (both c-halves): 2*16*47 floats
  for (int i = threadIdx.x; i < 1504; i += 512) {
    int ii = i % 47;
    int r  = i / 47;               // 0..31
    int c  = r & 15, ph = r >> 4;
    int d  = D0 - 15 + ii;
    vwin[ph][c][ii] = (d >= 0 && d < 128)
        ? v[b * 4096 + (16 * ph + c) * 128 + d] : 0.f;
  }
  __syncthreads();

  int lane = threadIdx.x & 63, wave = threadIdx.x >> 6;
  int quad = lane >> 4, l15 = lane & 15;
  int cq   = quad >> 1;            // low bit of c
  int og   = 2 * uc + (quad & 1);  // global u-octet
  int nt0  = wave * 2;             // 8 waves x 2 nt = 16 nt

  f32x4 acc00 = (f32x4)0.f, acc01 = (f32x4)0.f;   // [qs][t]
  f32x4 acc10 = (f32x4)0.f, acc11 = (f32x4)0.f;

  const bf16x8* AH8 = (const bf16x8*)AH;
  const bf16x8* AL8 = (const bf16x8*)AL;
  const bf16x8* Bh8 = (const bf16x8*)Bh;
  const bf16x8* Bl8 = (const bf16x8*)Bl;
  short2* AH2 = (short2*)AH;
  short2* AL2 = (short2*)AL;

  int abase0 = (0 * 16 + l15) * 33 + quad;   // bf16x8 units, row stride 33
  int abase1 = (1 * 16 + l15) * 33 + quad;

  for (int p = 0; p < 2; ++p) {
    // expand Toeplitz A (hi/lo split) for this c-half: 32 rows x 128 kk-pairs
    for (int i = threadIdx.x; i < 4096; i += 512) {
      int kk2 = i & 127;           // kk = 2*kk2 (pair shares c_local)
      int row = i >> 7;            // 0..31
      int cl  = kk2 >> 3;
      int uu  = (kk2 & 7) * 2;
      int ii  = row - uu + 15;
      float v0 = vwin[p][cl][ii];
      float v1 = vwin[p][cl][ii - 1];
      unsigned w0 = __float_as_uint(v0), w1 = __float_as_uint(v1);
      float r0 = v0 - __uint_as_float(w0 & 0xffff0000u);
      float r1 = v1 - __uint_as_float(w1 & 0xffff0000u);
      int u2 = row * 132 + kk2;    // short2 units, row stride 132
      AH2[u2] = make_short2((short)(w0 >> 16), (short)(w1 >> 16));
      AL2[u2] = make_short2((short)(__float_as_uint(r0) >> 16),
                            (short)(__float_as_uint(r1) >> 16));
    }
    __syncthreads();

#pragma unroll
    for (int ks = 0; ks < 8; ++ks) {
      bf16x8 ah0 = AH8[abase0 + ks * 4];
      bf16x8 al0 = AL8[abase0 + ks * 4];
      bf16x8 ah1 = AH8[abase1 + ks * 4];
      bf16x8 al1 = AL8[abase1 + ks * 4];
      int c   = 16 * p + 2 * ks + cq;
      int bb0 = (c * 16 + og) * 256 + l15;
      bf16x8 bh0 = Bh8[bb0 + nt0 * 16];
      bf16x8 bl0 = Bl8[bb0 + nt0 * 16];
      bf16x8 bh1 = Bh8[bb0 + (nt0 + 1) * 16];
      bf16x8 bl1 = Bl8[bb0 + (nt0 + 1) * 16];
      MFMA16(acc00, ah0, bh0); MFMA16(acc00, ah0, bl0); MFMA16(acc00, al0, bh0);
      MFMA16(acc10, ah1, bh0); MFMA16(acc10, ah1, bl0); MFMA16(acc10, al1, bh0);
      MFMA16(acc01, ah0, bh1); MFMA16(acc01, ah0, bl1); MFMA16(acc01, al0, bh1);
      MFMA16(acc11, ah1, bh1); MFMA16(acc11, ah1, bl1); MFMA16(acc11, al1, bh1);
    }
    __syncthreads();               // A consumed; safe to overwrite in next phase
  }

  {
    float* yb0 = y + b * 32768 + (32 * j + 0 * 16 + quad * 4) * 256 + l15;
    float* yb1 = y + b * 32768 + (32 * j + 1 * 16 + quad * 4) * 256 + l15;
#pragma unroll
    for (int reg = 0; reg < 4; ++reg) {
      atomicAdd(yb0 + reg * 256 + (nt0 + 0) * 16, acc00[reg]);
      atomicAdd(yb0 + reg * 256 + (nt0 + 1) * 16, acc01[reg]);
      atomicAdd(yb1 + reg * 256 + (nt0 + 0) * 16, acc10[reg]);
      atomicAdd(yb1 + reg * 256 + (nt0 + 1) * 16, acc11[reg]);
    }
  }
}

extern "C" void kernel_launch(void* const* d_in, const int* in_sizes, int n_in,
                              void* d_out, int out_size, void* d_ws, size_t ws_size,
                              hipStream_t stream) {
  const float* audio = (const float*)d_in[0];
  const float* Win   = (const float*)d_in[1];
  const float* bin   = (const float*)d_in[2];
  const float* bw    = (const float*)d_in[3];
  const float* bb    = (const float*)d_in[4];
  const float* Ws    = (const float*)d_in[5];
  const float* bs    = (const float*)d_in[6];
  const float* Wd    = (const float*)d_in[7];
  const float* bd    = (const float*)d_in[8];
  const float* reson = (const float*)d_in[9];

  float* out = (float*)d_out;           // [0,1048576) = y ; [1048576,2097152) = sparse
  float* ws  = (float*)d_ws;

  float* spec   = ws + WS_SPEC;
  float* h0     = ws + WS_H0;
  float* accb   = ws + WS_ACC;
  float* vbuf   = ws + WS_V;
  float* WT     = ws + WS_WTIN;
  float* WsT    = ws + WS_WST;
  float* WdT    = ws + WS_WDT;
  float* frames = ws + WS_FRAMES;
  // WS_RES region (dead after fusing overlap-add into k_obpack) -> bf16 B packs
  short* Bh = (short*)(ws + WS_RES);               // 1,048,576 bf16 = 2 MB
  short* Bl = (short*)(ws + WS_RES + 524288u);     // 1,048,576 bf16 = 2 MB
  // chain-weight packs live in WS_V until k_sparse_dense overwrites it (after k_chain)
  short* Whg = (short*)(ws + WS_V);                // 16384 bf16 = 32 KB
  short* Wlg = (short*)(ws + WS_V + 8192u);        // 16384 bf16 = 32 KB

  // zero y region (atomicAdd target); d_out is poisoned before every launch
  hipMemsetAsync(d_out, 0, 1048576u * sizeof(float), stream);

  k_fft<<<2688, 256, 0, stream>>>(audio, reson, Win, Ws, Wd, bw,
                                  spec, frames, WT, WsT, WdT, Whg, Wlg);
  k_obpack<<<512, 256, 0, stream>>>(frames, Bh, Bl);
  k_proj_in<<<512, 256, 0, stream>>>(spec, WT, bin, h0);
  k_chain<<<32, 1024, 0, stream>>>(h0, Whg, Wlg, bb, accb);
  k_sparse_dense<<<1024, 256, 0, stream>>>(accb, WsT, bs, WdT, bd, out + 1048576, vbuf);
  k_conv<<<640, 512, 0, stream>>>(vbuf, Bh, Bl, out);
}

// Round 7
// 181.267 us; speedup vs baseline: 1.0892x; 1.0403x over previous
//
#include <hip/hip_runtime.h>

#define PI_F 3.14159265358979323846f

typedef short bf16x8 __attribute__((ext_vector_type(8)));
typedef float f32x4 __attribute__((ext_vector_type(4)));

#define MFMA16(acc, a, b) \
  acc = __builtin_amdgcn_mfma_f32_16x16x32_bf16(a, b, acc, 0, 0, 0)

// ---------------- workspace layout (float offsets) ----------------
#define WS_SPEC   0u          // 32*128*1024  [b][t][k]
#define WS_H0     4194304u    // 32*32*128    [b][o][t]
#define WS_ACC    4325376u    // 32*128*32    [b][t][o]
#define WS_V      4456448u    // 32*32*128    [b][c][t]; ALSO: prep stashes the
                              // chain-weight bf16 packs in the first 16384 floats
                              // (region only becomes v after k_sparse_dense,
                              // which runs after k_chain has consumed the packs)
#define WS_WTIN   4587520u    // 1024*32      [k][o]
#define WS_WST    4620288u    // 32*256       [m][o2]
#define WS_WDT    4628480u    // 256*32       [o2][c]
#define WS_FRAMES 4636672u    // 32*32*2048   [c][f][j]
#define WS_RES    6733824u    // (dead: res assembly fused into obpack) -> Bh/Bl packs
// total 7782400 floats = ~29.7 MB

// ---- 2048-pt complex DIT FFT, bit-reversed input, 256 thr ----
// v8: k_fft is LDS-bound (v7 falsified transcendental theory: cutting 32->8
// sincosf moved ~1us). Two levers, arithmetic bitwise-identical:
// (a) fuse radix-2 stage PAIRS in registers: quads {a,a+h,a+2h,a+3h}, stage-s
//     butterflies then stage-(s+1) butterflies on 4 regs. Second s+1 pair's
//     twiddle is exactly -i*w' (e^{-i pi (j+h)/2h} = -i e^{-i pi j/2h}).
//     11 LDS passes -> 6; barriers 11 -> 6; LDS traffic ~halved.
// (b) pad buf via BIX(a)=a+(a>>4) (17.4 KB, occupancy unchanged): low-stage
//     quad patterns were 8-16-way bank conflicts; padding spreads to <=4-way.
#define BIX(a) ((a) + ((a) >> 4))

#define BFLY(I0, I1, C, S)                                   \
  { float2 u = buf[I0]; float2 w = buf[I1];                  \
    float tr = (C) * w.x - (S) * w.y;                        \
    float ti = (C) * w.y + (S) * w.x;                        \
    buf[I0] = make_float2(u.x + tr, u.y + ti);               \
    buf[I1] = make_float2(u.x - tr, u.y - ti); }

// fused stages (s, s+1): ws=(cs,ss) for stage s, w'=(cp,sp) for stage s+1.
__device__ __forceinline__ void quad_bfly(float2* buf, int a, int h,
                                          float cs, float ss, float cp, float sp) {
  float2 x0 = buf[BIX(a)],         x1 = buf[BIX(a + h)];
  float2 x2 = buf[BIX(a + 2 * h)], x3 = buf[BIX(a + 3 * h)];
  float t1x = cs * x1.x - ss * x1.y, t1y = cs * x1.y + ss * x1.x;
  float t3x = cs * x3.x - ss * x3.y, t3y = cs * x3.y + ss * x3.x;
  float2 y0 = make_float2(x0.x + t1x, x0.y + t1y);
  float2 y1 = make_float2(x0.x - t1x, x0.y - t1y);
  float2 y2 = make_float2(x2.x + t3x, x2.y + t3y);
  float2 y3 = make_float2(x2.x - t3x, x2.y - t3y);
  float u2x = cp * y2.x - sp * y2.y, u2y = cp * y2.y + sp * y2.x;
  float u3x = sp * y3.x + cp * y3.y, u3y = sp * y3.y - cp * y3.x;  // (-i w')*y3
  buf[BIX(a)]         = make_float2(y0.x + u2x, y0.y + u2y);
  buf[BIX(a + 2 * h)] = make_float2(y0.x - u2x, y0.y - u2y);
  buf[BIX(a + h)]     = make_float2(y1.x + u3x, y1.y + u3y);
  buf[BIX(a + 3 * h)] = make_float2(y1.x - u3x, y1.y - u3y);
}

__device__ __forceinline__ void fft2048_stages(float2* buf, int tid) {
  const float R = 0.7071067811865476f;
  // fused (0,1): ws=1; w' in {1,-i} -> pure adds/swaps
  for (int g = tid; g < 512; g += 256) {
    int a = g << 2;
    float2 x0 = buf[BIX(a)],     x1 = buf[BIX(a + 1)];
    float2 x2 = buf[BIX(a + 2)], x3 = buf[BIX(a + 3)];
    float2 y0 = make_float2(x0.x + x1.x, x0.y + x1.y);
    float2 y1 = make_float2(x0.x - x1.x, x0.y - x1.y);
    float2 y2 = make_float2(x2.x + x3.x, x2.y + x3.y);
    float2 y3 = make_float2(x2.x - x3.x, x2.y - x3.y);
    buf[BIX(a)]     = make_float2(y0.x + y2.x, y0.y + y2.y);
    buf[BIX(a + 2)] = make_float2(y0.x - y2.x, y0.y - y2.y);
    buf[BIX(a + 1)] = make_float2(y1.x + y3.y, y1.y - y3.x);   // -i*y3
    buf[BIX(a + 3)] = make_float2(y1.x - y3.y, y1.y + y3.x);
  }
  __syncthreads();
  // fused (2,3): h=4; ws = e^{-i pi j/4}, w' = e^{-i pi j/8} (exact constants)
  {
    int j = tid & 3;
    const float C8 = 0.9238795325112867f, S8 = 0.3826834323650898f;
    float cs = (j == 0) ? 1.f : ((j == 1) ? R : ((j == 2) ? 0.f : -R));
    float ss = (j == 0) ? 0.f : ((j == 2) ? -1.f : -R);
    float cp = (j == 0) ? 1.f : ((j == 1) ? C8 : ((j == 2) ? R : S8));
    float sp = (j == 0) ? 0.f : ((j == 1) ? -S8 : ((j == 2) ? -R : -C8));
    for (int g = tid; g < 512; g += 256) {
      int a = ((g >> 2) << 4) + j;
      quad_bfly(buf, a, 4, cs, ss, cp, sp);
    }
  }
  __syncthreads();
  // fused (4,5),(6,7),(8,9): h = 16,64,256; j = tid&(h-1) shared by both quads
#pragma unroll
  for (int s = 4; s <= 8; s += 2) {
    int h = 1 << s;
    int j = tid & (h - 1);
    float ss, cs, sp, cp;
    __sincosf(-PI_F / (float)h * (float)j, &ss, &cs);            // ws
    __sincosf(-PI_F / (float)(2 * h) * (float)j, &sp, &cp);      // w'
    for (int g = tid; g < 512; g += 256) {
      int a = ((g >> s) << (s + 2)) + j;
      quad_bfly(buf, a, h, cs, ss, cp, sp);
    }
    __syncthreads();
  }
  // stage 10 alone: theta_k = -pi*(tid+256k)/1024 = theta0 - k*pi/4
  {
    float s0, c0;
    __sincosf(-PI_F / 1024.f * (float)tid, &s0, &c0);
    BFLY(BIX(tid),       BIX(tid + 1024), c0, s0);
    BFLY(BIX(tid + 256), BIX(tid + 1280), R * (c0 + s0), R * (s0 - c0));
    BFLY(BIX(tid + 512), BIX(tid + 1536), s0, -c0);
    BFLY(BIX(tid + 768), BIX(tid + 1792), R * (s0 - c0), -R * (s0 + c0));
  }
  __syncthreads();
}

// ---------------- fused FFT kernel: STFT pairs + resonance pairs + prep tail ----------------
// blk <  2048 : STFT (2 frames per block via complex pack)
// blk <  2560 : resonance frames (2 exponents per block via complex pack)
// blk >= 2560 : weight transposes + chain-weight bf16 packs (128 blocks)
__global__ __launch_bounds__(256) void k_fft(const float* __restrict__ audio,
                                             const float* __restrict__ resin,
                                             const float* __restrict__ Win,
                                             const float* __restrict__ Ws,
                                             const float* __restrict__ Wd,
                                             const float* __restrict__ bwIn,
                                             float* __restrict__ spec,
                                             float* __restrict__ frames,
                                             float* __restrict__ WT,
                                             float* __restrict__ WsT,
                                             float* __restrict__ WdT,
                                             short* __restrict__ Whg,
                                             short* __restrict__ Wlg) {
  __shared__ float2 buf[2176];        // 2048 + BIX padding
  int blk = blockIdx.x;

  if (blk >= 2560) {                  // ---- prep branch (no LDS use, no syncs) ----
    int i = (blk - 2560) * 256 + threadIdx.x;
    if (i < 32768) { int o = i >> 10, k = i & 1023; WT[k * 32 + o] = Win[i]; }
    if (i < 8192)  { int o2 = i >> 5, m = i & 31;   WsT[m * 256 + o2] = Ws[i]; }
    if (i < 8192)  { int c = i >> 8, o2 = i & 255;  WdT[o2 * 32 + c] = Wd[i]; }
    if (i < 16384) {
      // i = ((s*32+o)*32+m)*2 + w
      int w = i & 1, m = (i >> 1) & 31, o = (i >> 6) & 31, s = i >> 11;
      float val = bwIn[i];
      unsigned bits = __float_as_uint(val);
      float rem = val - __uint_as_float(bits & 0xffff0000u);
      int row = (s * 2 + w) * 32 + o;
      Whg[row * 32 + m] = (short)(bits >> 16);
      Wlg[row * 32 + m] = (short)(__float_as_uint(rem) >> 16);
    }
    return;
  }

  if (blk < 2048) {
    int b  = blk >> 6;
    int f0 = (blk & 63) * 2;      // frames f0, f0+1
    for (int j = threadIdx.x; j < 2048; j += 256) {
      float h = 0.5f - 0.5f * __cosf(0.0030679615757712823f * (float)j); // 2pi/2048
      int i1 = f0 * 256 + j;
      int i2 = i1 + 256;
      float a1 = (i1 < 32768) ? audio[b * 32768 + i1] : 0.f;
      float a2 = (i2 < 32768) ? audio[b * 32768 + i2] : 0.f;
      buf[BIX(__brev((unsigned)j) >> 21)] = make_float2(a1 * h, a2 * h);
    }
    __syncthreads();
    fft2048_stages(buf, threadIdx.x);
    const float scale = 0.5f * 0.022097086912079608f;  // 0.5 / sqrt(2048)
    for (int k = threadIdx.x; k < 1024; k += 256) {
      float2 zk = buf[BIX(k)];
      float2 zn = buf[BIX((2048 - k) & 2047)];
      float f1r = zk.x + zn.x, f1i = zk.y - zn.y;
      float f2r = zk.y + zn.y, f2i = zk.x - zn.x;
      spec[(b * 128 + f0) * 1024 + k]     = sqrtf(f1r * f1r + f1i * f1i) * scale;
      spec[(b * 128 + f0 + 1) * 1024 + k] = sqrtf(f2r * f2r + f2i * f2i) * scale;
    }
  } else {
    int r = blk - 2048;           // 0..511
    int c = r >> 4;
    int g = r & 15;               // frames 2g (exp 2g+1), 2g+1 (exp 2g+2)
    float e1 = (float)(2 * g + 1);
    for (int k = threadIdx.x; k < 2048; k += 256) {
      int kk = (k <= 1024) ? k : 2048 - k;   // Hermitian (real) extension
      float cv = resin[c * 1025 + kk];
      cv = fminf(fmaxf(cv, 0.f), 0.9999f);
      float m1 = __powf(cv, e1);
      float m2 = m1 * cv;
      buf[BIX(__brev((unsigned)k) >> 21)] = make_float2(m1, m2);
    }
    __syncthreads();
    fft2048_stages(buf, threadIdx.x);
    for (int j = threadIdx.x; j < 2048; j += 256) {
      float h  = 0.5f - 0.5f * __cosf(0.0030679615757712823f * (float)j);
      float sc = h * (1.f / 2048.f);
      float2 z = buf[BIX(j)];
      frames[(c * 32 + 2 * g) * 2048 + j]     = z.x * sc;
      frames[(c * 32 + 2 * g + 1) * 2048 + j] = z.y * sc;
    }
  }
}

// ---------------- proj_in: h0[b,o,t] = sum_k WT[k][o]*spec[b,t,k] + bias ----------------
__global__ __launch_bounds__(256) void k_proj_in(const float* __restrict__ spec,
                                                 const float* __restrict__ WT,
                                                 const float* __restrict__ bias,
                                                 float* __restrict__ h0) {
  __shared__ float specL[8][1024];
  __shared__ float red[32][8][8];   // [o][tt][p]
  int b  = blockIdx.x >> 4;
  int t0 = (blockIdx.x & 15) * 8;
  for (int i = threadIdx.x; i < 8192; i += 256) {
    int tt = i >> 10, k = i & 1023;
    specL[tt][k] = spec[(b * 128 + t0 + tt) * 1024 + k];
  }
  __syncthreads();
  int o = threadIdx.x & 31, p = threadIdx.x >> 5;
  float part[8] = {0.f,0.f,0.f,0.f,0.f,0.f,0.f,0.f};
  for (int i = 0; i < 128; ++i) {
    int k = p * 128 + ((i + p * 4) & 127);   // stagger: conflict-free banks across p
    float w = WT[k * 32 + o];
#pragma unroll
    for (int tt = 0; tt < 8; ++tt) part[tt] += w * specL[tt][k];
  }
#pragma unroll
  for (int tt = 0; tt < 8; ++tt) red[o][tt][p] = part[tt];
  __syncthreads();
  int oo = threadIdx.x >> 3, tt2 = threadIdx.x & 7;
  float s = bias[oo];
#pragma unroll
  for (int p2 = 0; p2 < 8; ++p2) s += red[oo][tt2][p2];
  h0[b * 4096 + oo * 128 + t0 + tt2] = s;
}

// ---------------- fused overlap-add + B-pack (separate launch: full occupancy) ----------------
__global__ __launch_bounds__(256) void k_obpack(const float* __restrict__ frames,
                                                short* __restrict__ Bh,
                                                short* __restrict__ Bl) {
  int c = blockIdx.x >> 4, o = blockIdx.x & 15;
  int r = threadIdx.x;
  bf16x8 hv, lv;
#pragma unroll
  for (int j = 0; j < 8; ++j) {
    int fo = 8 * o + j;
    int g  = fo >> 2;
    int j0 = ((fo & 3) << 8) + r;
    float val = frames[(c * 32 + g) * 2048 + j0];
    if (g > 0) val += frames[(c * 32 + g - 1) * 2048 + j0 + 1024];
    unsigned bits = __float_as_uint(val);
    float rem = val - __uint_as_float(bits & 0xffff0000u);
    hv[j] = (short)(bits >> 16);
    lv[j] = (short)(__float_as_uint(rem) >> 16);
  }
  int unit = (blockIdx.x * 16 + (r >> 4)) * 16 + (r & 15);
  ((bf16x8*)Bh)[unit] = hv;
  ((bf16x8*)Bl)[unit] = lv;
}

// ---------------- 8-block anticausal chain as per-step MFMA GEMM pairs ----------------
__global__ __launch_bounds__(1024) void k_chain(const float* __restrict__ h0,
                                                const short* __restrict__ Whg,
                                                const short* __restrict__ Wlg,
                                                const float* __restrict__ bb,
                                                float* __restrict__ accout) {
  __shared__ __align__(16) short Hh[192 * 40];   // rows stride 40 bf16 (80 B)
  __shared__ __align__(16) short Hl[192 * 40];
  __shared__ float Hf[128 * 33];                 // fp32 H for exact residual
  __shared__ float bL[256];
  __shared__ float red[16];
  int b = blockIdx.x, tid = threadIdx.x;

  for (int i = tid; i < 4096; i += 1024) {
    int t = i & 127;                 // h0 layout [o][t]
    int o = i >> 7;
    float val = h0[b * 4096 + i];
    Hf[t * 33 + o] = val;
    unsigned bits = __float_as_uint(val);
    float rem = val - __uint_as_float(bits & 0xffff0000u);
    Hh[t * 40 + o] = (short)(bits >> 16);
    Hl[t * 40 + o] = (short)(__float_as_uint(rem) >> 16);
  }
  for (int i = tid; i < 64 * 40; i += 1024) {    // zero pad rows 128..191
    Hh[128 * 40 + i] = 0;
    Hl[128 * 40 + i] = 0;
  }
  if (tid < 256) bL[tid] = bb[tid];
  __syncthreads();

  int wave = tid >> 6, lane = tid & 63;
  int quad = lane >> 4, l15 = lane & 15;
  int t0 = (wave & 7) * 16, o0 = (wave >> 3) * 16;
  int tD = t0 + quad * 4;          // D rows tD..tD+3
  int oD = o0 + l15;               // D col

  const bf16x8* Hh8 = (const bf16x8*)Hh;   // unit = row*5 + quad (40 bf16 = 5 units)
  const bf16x8* Hl8 = (const bf16x8*)Hl;
  const bf16x8* Wh8 = (const bf16x8*)Whg;  // unit = row*4 + quad (32 bf16 = 4 units)
  const bf16x8* Wl8 = (const bf16x8*)Wlg;

  float accsum[4] = {0.f, 0.f, 0.f, 0.f};
  const int DIL[8] = {1, 2, 4, 8, 16, 32, 64, 1};

#pragma unroll
  for (int s = 0; s < 8; ++s) {
    int arow = t0 + l15;
    int frow = arow + DIL[s];        // <= 191, pad rows give zeros
    bf16x8 Ah = Hh8[arow * 5 + quad];
    bf16x8 Al = Hl8[arow * 5 + quad];
    bf16x8 Fh = Hh8[frow * 5 + quad];
    bf16x8 Fl = Hl8[frow * 5 + quad];
    int w0row = ((s * 2 + 0) * 32 + oD) * 4 + quad;
    int w1row = ((s * 2 + 1) * 32 + oD) * 4 + quad;
    bf16x8 B0h = Wh8[w0row], B0l = Wl8[w0row];
    bf16x8 B1h = Wh8[w1row], B1l = Wl8[w1row];
    float bias = bL[s * 32 + oD];
    f32x4 acc = {bias, bias, bias, bias};
    MFMA16(acc, Ah, B0h); MFMA16(acc, Ah, B0l); MFMA16(acc, Al, B0h);
    MFMA16(acc, Fh, B1h); MFMA16(acc, Fh, B1l); MFMA16(acc, Fl, B1h);
    float hnew[4], lmax = 0.f;
#pragma unroll
    for (int r = 0; r < 4; ++r) {
      float sv = acc[r];
      sv = (sv > 0.f) ? sv : 0.2f * sv;       // leaky_relu 0.2
      sv += Hf[(tD + r) * 33 + oD];           // residual (exact fp32)
      hnew[r] = sv;
      lmax = fmaxf(lmax, fabsf(sv));
    }
#pragma unroll
    for (int off = 32; off > 0; off >>= 1)
      lmax = fmaxf(lmax, __shfl_down(lmax, off, 64));
    if (lane == 0) red[wave] = lmax;
    __syncthreads();                 // red visible; all H reads of this step done
    float mx = red[0];
#pragma unroll
    for (int i = 1; i < 16; ++i) mx = fmaxf(mx, red[i]);
    float nm = 1.f / (mx + 1e-8f);
#pragma unroll
    for (int r = 0; r < 4; ++r) {
      float hv = hnew[r] * nm;
      accsum[r] += hv;
      int t = tD + r;
      Hf[t * 33 + oD] = hv;
      unsigned bits = __float_as_uint(hv);
      float rem = hv - __uint_as_float(bits & 0xffff0000u);
      Hh[t * 40 + oD] = (short)(bits >> 16);
      Hl[t * 40 + oD] = (short)(__float_as_uint(rem) >> 16);
    }
    __syncthreads();                 // new H visible for next step
  }
#pragma unroll
  for (int r = 0; r < 4; ++r)
    accout[b * 4096 + (tD + r) * 32 + oD] = accsum[r];
}

// ---------------- sparse + dense, 4 t per block (4x weight reuse + ILP) ----------------
__global__ __launch_bounds__(256) void k_sparse_dense(const float* __restrict__ acc,
                                                      const float* __restrict__ WsT,
                                                      const float* __restrict__ bs,
                                                      const float* __restrict__ WdT,
                                                      const float* __restrict__ bd,
                                                      float* __restrict__ out_sparse,
                                                      float* __restrict__ v) {
  __shared__ float accL[4][32];
  __shared__ float sL[4][256];
  __shared__ float red[8][4][32];   // [p][tt][c]
  int b = blockIdx.x >> 5, tq = blockIdx.x & 31;
  int t0 = tq * 4;
  int tid = threadIdx.x;
  if (tid < 128)
    accL[tid >> 5][tid & 31] = acc[b * 4096 + (t0 + (tid >> 5)) * 32 + (tid & 31)];
  __syncthreads();
  float bsv = bs[tid];
  float s0 = bsv, s1 = bsv, s2 = bsv, s3 = bsv;
  for (int m = 0; m < 32; ++m) {
    float w = WsT[m * 256 + tid];
    s0 += w * accL[0][m]; s1 += w * accL[1][m];
    s2 += w * accL[2][m]; s3 += w * accL[3][m];
  }
  s0 = fmaxf(s0, 0.f); s1 = fmaxf(s1, 0.f); s2 = fmaxf(s2, 0.f); s3 = fmaxf(s3, 0.f);
  float* os = out_sparse + b * 32768 + tid * 128 + t0;
  os[0] = s0; os[1] = s1; os[2] = s2; os[3] = s3;
  sL[0][tid] = s0; sL[1][tid] = s1; sL[2][tid] = s2; sL[3][tid] = s3;
  __syncthreads();
  int c = tid & 31, p = tid >> 5;
  float p0 = 0.f, p1 = 0.f, p2 = 0.f, p3 = 0.f;
  for (int jj = 0; jj < 32; ++jj) {
    int o2 = p * 32 + jj;
    float w = WdT[o2 * 32 + c];
    p0 += w * sL[0][o2]; p1 += w * sL[1][o2];
    p2 += w * sL[2][o2]; p3 += w * sL[3][o2];
  }
  red[p][0][c] = p0; red[p][1][c] = p1; red[p][2][c] = p2; red[p][3][c] = p3;
  __syncthreads();
  if (tid < 128) {
    int tt = tid >> 5, cc = tid & 31;
    float vv = bd[cc];
#pragma unroll
    for (int p2i = 0; p2i < 8; ++p2i) vv += red[p2i][tt][cc];
    v[b * 4096 + cc * 128 + t0 + tt] = vv;
  }
}

// ---------------- final conv as MFMA GEMM, v4 two-phase (proven best) ----------------
// Two-phase K=256 keeps LDS at 39.9 KB -> 4 blocks/CU (full 32 waves) -- k_conv
// is latency-bound and occupancy is the binding resource (v2/v5 lessons).
// XCD-group swizzle: all 32 b-blocks of one (j,uc) share one XCD's L2 slice.
__global__ __launch_bounds__(512, 4) void k_conv(const float* __restrict__ v,
                                                 const short* __restrict__ Bh,
                                                 const short* __restrict__ Bl,
                                                 float* __restrict__ y) {
  __shared__ __align__(16) short AH[32 * 264];   // [row 32][K 256 + pad 8]
  __shared__ __align__(16) short AL[32 * 264];
  __shared__ float vwin[2][16][48];              // [c-half][c_local][ii]

  // --- XCD-group swizzle: group e (20 of them) -> XCD e%8; batches fill slots.
  int xcd  = blockIdx.x & 7;
  int slot = blockIdx.x >> 3;
  int e, b;
  if      (slot < 32) { e = xcd;      b = slot; }
  else if (slot < 64) { e = xcd + 8;  b = slot - 32; }
  else                { e = (xcd < 4) ? (xcd + 16) : (xcd + 12);
                        b = (xcd < 4) ? (slot - 64) : (slot - 48); }
  int j, uc;
  if      (e < 2)  { j = 0; uc = e; }
  else if (e < 6)  { j = 1; uc = e - 2; }
  else if (e < 12) { j = 2; uc = e - 6; }
  else             { j = 3; uc = e - 12; }
  int D0 = 32 * j - 16 * uc;       // d = D0 - 15 + ii, ii in [0,46]

  // stage compact v windows (both c-halves): 2*16*47 floats
  for (int i = threadIdx.x; i < 1504; i += 512) {
    int ii = i % 47;
    int r  = i / 47;               // 0..31
    int c  = r & 15, ph = r >> 4;
    int d  = D0 - 15 + ii;
    vwin[ph][c][ii] = (d >= 0 && d < 128)
        ? v[b * 4096 + (16 * ph + c) * 128 + d] : 0.f;
  }
  __syncthreads();

  int lane = threadIdx.x & 63, wave = threadIdx.x >> 6;
  int quad = lane >> 4, l15 = lane & 15;
  int cq   = quad >> 1;            // low bit of c
  int og   = 2 * uc + (quad & 1);  // global u-octet
  int nt0  = wave * 2;             // 8 waves x 2 nt = 16 nt

  f32x4 acc00 = (f32x4)0.f, acc01 = (f32x4)0.f;   // [qs][t]
  f32x4 acc10 = (f32x4)0.f, acc11 = (f32x4)0.f;

  const bf16x8* AH8 = (const bf16x8*)AH;
  const bf16x8* AL8 = (const bf16x8*)AL;
  const bf16x8* Bh8 = (const bf16x8*)Bh;
  const bf16x8* Bl8 = (const bf16x8*)Bl;
  short2* AH2 = (short2*)AH;
  short2* AL2 = (short2*)AL;

  int abase0 = (0 * 16 + l15) * 33 + quad;   // bf16x8 units, row stride 33
  int abase1 = (1 * 16 + l15) * 33 + quad;

  for (int p = 0; p < 2; ++p) {
    // expand Toeplitz A (hi/lo split) for this c-half: 32 rows x 128 kk-pairs
    for (int i = threadIdx.x; i < 4096; i += 512) {
      int kk2 = i & 127;           // kk = 2*kk2 (pair shares c_local)
      int row = i >> 7;            // 0..31
      int cl  = kk2 >> 3;
      int uu  = (kk2 & 7) * 2;
      int ii  = row - uu + 15;
      float v0 = vwin[p][cl][ii];
      float v1 = vwin[p][cl][ii - 1];
      unsigned w0 = __float_as_uint(v0), w1 = __float_as_uint(v1);
      float r0 = v0 - __uint_as_float(w0 & 0xffff0000u);
      float r1 = v1 - __uint_as_float(w1 & 0xffff0000u);
      int u2 = row * 132 + kk2;    // short2 units, row stride 132
      AH2[u2] = make_short2((short)(w0 >> 16), (short)(w1 >> 16));
      AL2[u2] = make_short2((short)(__float_as_uint(r0) >> 16),
                            (short)(__float_as_uint(r1) >> 16));
    }
    __syncthreads();

#pragma unroll
    for (int ks = 0; ks < 8; ++ks) {
      bf16x8 ah0 = AH8[abase0 + ks * 4];
      bf16x8 al0 = AL8[abase0 + ks * 4];
      bf16x8 ah1 = AH8[abase1 + ks * 4];
      bf16x8 al1 = AL8[abase1 + ks * 4];
      int c   = 16 * p + 2 * ks + cq;
      int bb0 = (c * 16 + og) * 256 + l15;
      bf16x8 bh0 = Bh8[bb0 + nt0 * 16];
      bf16x8 bl0 = Bl8[bb0 + nt0 * 16];
      bf16x8 bh1 = Bh8[bb0 + (nt0 + 1) * 16];
      bf16x8 bl1 = Bl8[bb0 + (nt0 + 1) * 16];
      MFMA16(acc00, ah0, bh0); MFMA16(acc00, ah0, bl0); MFMA16(acc00, al0, bh0);
      MFMA16(acc10, ah1, bh0); MFMA16(acc10, ah1, bl0); MFMA16(acc10, al1, bh0);
      MFMA16(acc01, ah0, bh1); MFMA16(acc01, ah0, bl1); MFMA16(acc01, al0, bh1);
      MFMA16(acc11, ah1, bh1); MFMA16(acc11, ah1, bl1); MFMA16(acc11, al1, bh1);
    }
    __syncthreads();               // A consumed; safe to overwrite in next phase
  }

  {
    float* yb0 = y + b * 32768 + (32 * j + 0 * 16 + quad * 4) * 256 + l15;
    float* yb1 = y + b * 32768 + (32 * j + 1 * 16 + quad * 4) * 256 + l15;
#pragma unroll
    for (int reg = 0; reg < 4; ++reg) {
      atomicAdd(yb0 + reg * 256 + (nt0 + 0) * 16, acc00[reg]);
      atomicAdd(yb0 + reg * 256 + (nt0 + 1) * 16, acc01[reg]);
      atomicAdd(yb1 + reg * 256 + (nt0 + 0) * 16, acc10[reg]);
      atomicAdd(yb1 + reg * 256 + (nt0 + 1) * 16, acc11[reg]);
    }
  }
}

extern "C" void kernel_launch(void* const* d_in, const int* in_sizes, int n_in,
                              void* d_out, int out_size, void* d_ws, size_t ws_size,
                              hipStream_t stream) {
  const float* audio = (const float*)d_in[0];
  const float* Win   = (const float*)d_in[1];
  const float* bin   = (const float*)d_in[2];
  const float* bw    = (const float*)d_in[3];
  const float* bb    = (const float*)d_in[4];
  const float* Ws    = (const float*)d_in[5];
  const float* bs    = (const float*)d_in[6];
  const float* Wd    = (const float*)d_in[7];
  const float* bd    = (const float*)d_in[8];
  const float* reson = (const float*)d_in[9];

  float* out = (float*)d_out;           // [0,1048576) = y ; [1048576,2097152) = sparse
  float* ws  = (float*)d_ws;

  float* spec   = ws + WS_SPEC;
  float* h0     = ws + WS_H0;
  float* accb   = ws + WS_ACC;
  float* vbuf   = ws + WS_V;
  float* WT     = ws + WS_WTIN;
  float* WsT    = ws + WS_WST;
  float* WdT    = ws + WS_WDT;
  float* frames = ws + WS_FRAMES;
  // WS_RES region (dead after fusing overlap-add into k_obpack) -> bf16 B packs
  short* Bh = (short*)(ws + WS_RES);               // 1,048,576 bf16 = 2 MB
  short* Bl = (short*)(ws + WS_RES + 524288u);     // 1,048,576 bf16 = 2 MB
  // chain-weight packs live in WS_V until k_sparse_dense overwrites it (after k_chain)
  short* Whg = (short*)(ws + WS_V);                // 16384 bf16 = 32 KB
  short* Wlg = (short*)(ws + WS_V + 8192u);        // 16384 bf16 = 32 KB

  // zero y region (atomicAdd target); d_out is poisoned before every launch
  hipMemsetAsync(d_out, 0, 1048576u * sizeof(float), stream);

  k_fft<<<2688, 256, 0, stream>>>(audio, reson, Win, Ws, Wd, bw,
                                  spec, frames, WT, WsT, WdT, Whg, Wlg);
  k_obpack<<<512, 256, 0, stream>>>(frames, Bh, Bl);
  k_proj_in<<<512, 256, 0, stream>>>(spec, WT, bin, h0);
  k_chain<<<32, 1024, 0, stream>>>(h0, Whg, Wlg, bb, accb);
  k_sparse_dense<<<1024, 256, 0, stream>>>(accb, WsT, bs, WdT, bd, out + 1048576, vbuf);
  k_conv<<<640, 512, 0, stream>>>(vbuf, Bh, Bl, out);
}

// Round 9
// 177.648 us; speedup vs baseline: 1.1113x; 1.0204x over previous
//
#include <hip/hip_runtime.h>

#define PI_F 3.14159265358979323846f

typedef short bf16x8 __attribute__((ext_vector_type(8)));
typedef float f32x4 __attribute__((ext_vector_type(4)));

#define MFMA16(acc, a, b) \
  acc = __builtin_amdgcn_mfma_f32_16x16x32_bf16(a, b, acc, 0, 0, 0)

// ---------------- workspace layout (float offsets) ----------------
#define WS_SPEC   0u          // 32*128*1024  [b][t][k]
#define WS_H0     4194304u    // 32*32*128    [b][o][t]
#define WS_ACC    4325376u    // 32*128*32    [b][t][o]
#define WS_V      4456448u    // 32*32*128    [b][c][t]; ALSO: prep stashes the
                              // chain-weight bf16 packs in the first 16384 floats
                              // (region only becomes v after k_sparse_dense,
                              // which runs after k_chain has consumed the packs)
#define WS_WTIN   4587520u    // 1024*32      [k][o]
#define WS_WST    4620288u    // 32*256       [m][o2]
#define WS_WDT    4628480u    // 256*32       [o2][c]
#define WS_FRAMES 4636672u    // 32*32*2048   [c][f][j]
#define WS_RES    6733824u    // (dead: res assembly fused into obpack) -> Bh/Bl packs
// total 7782400 floats = ~29.7 MB

// ---- 2048-pt complex DIT FFT, bit-reversed input, 256 thr ----
// v9: radix-8 fusion -- 6 LDS passes (v8) -> 4: triples (0-2),(3-5),(6-8) as
// octets in registers + fused pair (9,10). k_fft is LDS-pass-bound (v7/v8
// evidence: gains track LDS passes removed, not transcendentals). One sincosf
// per triple: v = e^{-i pi j/4h}; w' = v^2; ws = v^4; intra-octet twiddles are
// v*{1, w8, -i, w8^3} with w8 = e^{-i pi/4} exact constants. BIX padding kept.
#define BIX(a) ((a) + ((a) >> 4))

#define BFLY(I0, I1, C, S)                                   \
  { float2 u = buf[I0]; float2 w = buf[I1];                  \
    float tr = (C) * w.x - (S) * w.y;                        \
    float ti = (C) * w.y + (S) * w.x;                        \
    buf[I0] = make_float2(u.x + tr, u.y + ti);               \
    buf[I1] = make_float2(u.x - tr, u.y - ti); }

#define CMULV(RX, RY, C, S, W) \
  { RX = (C) * (W).x - (S) * (W).y; RY = (C) * (W).y + (S) * (W).x; }

// fused stages (s, s+1): ws=(cs,ss) for stage s, w'=(cp,sp) for stage s+1.
__device__ __forceinline__ void quad_bfly(float2* buf, int a, int h,
                                          float cs, float ss, float cp, float sp) {
  float2 x0 = buf[BIX(a)],         x1 = buf[BIX(a + h)];
  float2 x2 = buf[BIX(a + 2 * h)], x3 = buf[BIX(a + 3 * h)];
  float t1x = cs * x1.x - ss * x1.y, t1y = cs * x1.y + ss * x1.x;
  float t3x = cs * x3.x - ss * x3.y, t3y = cs * x3.y + ss * x3.x;
  float2 y0 = make_float2(x0.x + t1x, x0.y + t1y);
  float2 y1 = make_float2(x0.x - t1x, x0.y - t1y);
  float2 y2 = make_float2(x2.x + t3x, x2.y + t3y);
  float2 y3 = make_float2(x2.x - t3x, x2.y - t3y);
  float u2x = cp * y2.x - sp * y2.y, u2y = cp * y2.y + sp * y2.x;
  float u3x = sp * y3.x + cp * y3.y, u3y = sp * y3.y - cp * y3.x;  // (-i w')*y3
  buf[BIX(a)]         = make_float2(y0.x + u2x, y0.y + u2y);
  buf[BIX(a + 2 * h)] = make_float2(y0.x - u2x, y0.y - u2y);
  buf[BIX(a + h)]     = make_float2(y1.x + u3x, y1.y + u3y);
  buf[BIX(a + 3 * h)] = make_float2(y1.x - u3x, y1.y - u3y);
}

// fused stages (s, s+1, s+2) on octet {a + k*h}, k=0..7. v = e^{-i pi j/4h},
// j = a & (h-1). Stage s uses v^4, s+1 uses v^2 (and -i*v^2), s+2 uses
// v, v*w8, -i*v, v*w8^3 (w8 = e^{-i pi/4}).
__device__ __forceinline__ void octet_bfly(float2* buf, int a, int h,
                                           float cv, float sv) {
  const float R = 0.7071067811865476f;
  float c1 = cv * cv - sv * sv, s1 = 2.f * cv * sv;   // w' = v^2
  float c2 = c1 * c1 - s1 * s1, s2 = 2.f * c1 * s1;   // ws = v^4
  float2 x0 = buf[BIX(a)],         x1 = buf[BIX(a + h)];
  float2 x2 = buf[BIX(a + 2 * h)], x3 = buf[BIX(a + 3 * h)];
  float2 x4 = buf[BIX(a + 4 * h)], x5 = buf[BIX(a + 5 * h)];
  float2 x6 = buf[BIX(a + 6 * h)], x7 = buf[BIX(a + 7 * h)];
  float tx, ty;
  // stage s: (c2,s2) on (x0,x1),(x2,x3),(x4,x5),(x6,x7)
  CMULV(tx, ty, c2, s2, x1);
  float2 y0 = make_float2(x0.x + tx, x0.y + ty), y1 = make_float2(x0.x - tx, x0.y - ty);
  CMULV(tx, ty, c2, s2, x3);
  float2 y2 = make_float2(x2.x + tx, x2.y + ty), y3 = make_float2(x2.x - tx, x2.y - ty);
  CMULV(tx, ty, c2, s2, x5);
  float2 y4 = make_float2(x4.x + tx, x4.y + ty), y5 = make_float2(x4.x - tx, x4.y - ty);
  CMULV(tx, ty, c2, s2, x7);
  float2 y6 = make_float2(x6.x + tx, x6.y + ty), y7 = make_float2(x6.x - tx, x6.y - ty);
  // stage s+1: (c1,s1) on (y0,y2),(y4,y6); -i*w' on (y1,y3),(y5,y7)
  CMULV(tx, ty, c1, s1, y2);
  float2 z0 = make_float2(y0.x + tx, y0.y + ty), z2 = make_float2(y0.x - tx, y0.y - ty);
  CMULV(tx, ty, c1, s1, y3);    // -i*u = (u.y, -u.x)
  float2 z1 = make_float2(y1.x + ty, y1.y - tx), z3 = make_float2(y1.x - ty, y1.y + tx);
  CMULV(tx, ty, c1, s1, y6);
  float2 z4 = make_float2(y4.x + tx, y4.y + ty), z6 = make_float2(y4.x - tx, y4.y - ty);
  CMULV(tx, ty, c1, s1, y7);
  float2 z5 = make_float2(y5.x + ty, y5.y - tx), z7 = make_float2(y5.x - ty, y5.y + tx);
  // stage s+2: v on (z0,z4); v*w8 on (z1,z5); -i*v on (z2,z6); v*w8^3 on (z3,z7)
  float ca = R * (cv + sv), sa = R * (sv - cv);   // v*w8
  float cb = sv,            sb = -cv;             // -i*v
  float cc = R * (sv - cv), sc = -R * (cv + sv);  // v*w8^3
  CMULV(tx, ty, cv, sv, z4);
  buf[BIX(a)]         = make_float2(z0.x + tx, z0.y + ty);
  buf[BIX(a + 4 * h)] = make_float2(z0.x - tx, z0.y - ty);
  CMULV(tx, ty, ca, sa, z5);
  buf[BIX(a + h)]     = make_float2(z1.x + tx, z1.y + ty);
  buf[BIX(a + 5 * h)] = make_float2(z1.x - tx, z1.y - ty);
  CMULV(tx, ty, cb, sb, z6);
  buf[BIX(a + 2 * h)] = make_float2(z2.x + tx, z2.y + ty);
  buf[BIX(a + 6 * h)] = make_float2(z2.x - tx, z2.y - ty);
  CMULV(tx, ty, cc, sc, z7);
  buf[BIX(a + 3 * h)] = make_float2(z3.x + tx, z3.y + ty);
  buf[BIX(a + 7 * h)] = make_float2(z3.x - tx, z3.y - ty);
}

__device__ __forceinline__ void fft2048_stages(float2* buf, int tid) {
  // pass 1: stages 0-2, h=1, one octet per thread, v = 1 (all-constant)
  octet_bfly(buf, tid << 3, 1, 1.f, 0.f);
  __syncthreads();
  // pass 2: stages 3-5, h=8
  {
    int j = tid & 7;
    int a = ((tid >> 3) << 6) + j;
    float sv, cv;
    __sincosf(-PI_F / 32.f * (float)j, &sv, &cv);
    octet_bfly(buf, a, 8, cv, sv);
  }
  __syncthreads();
  // pass 3: stages 6-8, h=64
  {
    int j = tid & 63;
    int a = ((tid >> 6) << 9) + j;
    float sv, cv;
    __sincosf(-PI_F / 256.f * (float)j, &sv, &cv);
    octet_bfly(buf, a, 64, cv, sv);
  }
  __syncthreads();
  // pass 4: stages 9-10 fused pair, h=512; 512 quads, 2 per thread (a = g < 512)
  for (int g = tid; g < 512; g += 256) {
    float sp, cp;
    __sincosf(-PI_F / 1024.f * (float)g, &sp, &cp);   // w' (stage 10)
    float c2 = cp * cp - sp * sp, s2 = 2.f * cp * sp; // ws = w'^2 (stage 9)
    quad_bfly(buf, g, 512, c2, s2, cp, sp);
  }
  __syncthreads();
}

// ---------------- fused FFT kernel: STFT pairs + resonance pairs + prep tail ----------------
// blk <  2048 : STFT (2 frames per block via complex pack)
// blk <  2560 : resonance frames (2 exponents per block via complex pack)
// blk >= 2560 : weight transposes + chain-weight bf16 packs (128 blocks)
__global__ __launch_bounds__(256) void k_fft(const float* __restrict__ audio,
                                             const float* __restrict__ resin,
                                             const float* __restrict__ Win,
                                             const float* __restrict__ Ws,
                                             const float* __restrict__ Wd,
                                             const float* __restrict__ bwIn,
                                             float* __restrict__ spec,
                                             float* __restrict__ frames,
                                             float* __restrict__ WT,
                                             float* __restrict__ WsT,
                                             float* __restrict__ WdT,
                                             short* __restrict__ Whg,
                                             short* __restrict__ Wlg) {
  __shared__ float2 buf[2176];        // 2048 + BIX padding
  int blk = blockIdx.x;

  if (blk >= 2560) {                  // ---- prep branch (no LDS use, no syncs) ----
    int i = (blk - 2560) * 256 + threadIdx.x;
    if (i < 32768) { int o = i >> 10, k = i & 1023; WT[k * 32 + o] = Win[i]; }
    if (i < 8192)  { int o2 = i >> 5, m = i & 31;   WsT[m * 256 + o2] = Ws[i]; }
    if (i < 8192)  { int c = i >> 8, o2 = i & 255;  WdT[o2 * 32 + c] = Wd[i]; }
    if (i < 16384) {
      // i = ((s*32+o)*32+m)*2 + w
      int w = i & 1, m = (i >> 1) & 31, o = (i >> 6) & 31, s = i >> 11;
      float val = bwIn[i];
      unsigned bits = __float_as_uint(val);
      float rem = val - __uint_as_float(bits & 0xffff0000u);
      int row = (s * 2 + w) * 32 + o;
      Whg[row * 32 + m] = (short)(bits >> 16);
      Wlg[row * 32 + m] = (short)(__float_as_uint(rem) >> 16);
    }
    return;
  }

  if (blk < 2048) {
    int b  = blk >> 6;
    int f0 = (blk & 63) * 2;      // frames f0, f0+1
    for (int j = threadIdx.x; j < 2048; j += 256) {
      float h = 0.5f - 0.5f * __cosf(0.0030679615757712823f * (float)j); // 2pi/2048
      int i1 = f0 * 256 + j;
      int i2 = i1 + 256;
      float a1 = (i1 < 32768) ? audio[b * 32768 + i1] : 0.f;
      float a2 = (i2 < 32768) ? audio[b * 32768 + i2] : 0.f;
      buf[BIX(__brev((unsigned)j) >> 21)] = make_float2(a1 * h, a2 * h);
    }
    __syncthreads();
    fft2048_stages(buf, threadIdx.x);
    const float scale = 0.5f * 0.022097086912079608f;  // 0.5 / sqrt(2048)
    for (int k = threadIdx.x; k < 1024; k += 256) {
      float2 zk = buf[BIX(k)];
      float2 zn = buf[BIX((2048 - k) & 2047)];
      float f1r = zk.x + zn.x, f1i = zk.y - zn.y;
      float f2r = zk.y + zn.y, f2i = zk.x - zn.x;
      spec[(b * 128 + f0) * 1024 + k]     = sqrtf(f1r * f1r + f1i * f1i) * scale;
      spec[(b * 128 + f0 + 1) * 1024 + k] = sqrtf(f2r * f2r + f2i * f2i) * scale;
    }
  } else {
    int r = blk - 2048;           // 0..511
    int c = r >> 4;
    int g = r & 15;               // frames 2g (exp 2g+1), 2g+1 (exp 2g+2)
    float e1 = (float)(2 * g + 1);
    for (int k = threadIdx.x; k < 2048; k += 256) {
      int kk = (k <= 1024) ? k : 2048 - k;   // Hermitian (real) extension
      float cv = resin[c * 1025 + kk];
      cv = fminf(fmaxf(cv, 0.f), 0.9999f);
      float m1 = __powf(cv, e1);
      float m2 = m1 * cv;
      buf[BIX(__brev((unsigned)k) >> 21)] = make_float2(m1, m2);
    }
    __syncthreads();
    fft2048_stages(buf, threadIdx.x);
    for (int j = threadIdx.x; j < 2048; j += 256) {
      float h  = 0.5f - 0.5f * __cosf(0.0030679615757712823f * (float)j);
      float sc = h * (1.f / 2048.f);
      float2 z = buf[BIX(j)];
      frames[(c * 32 + 2 * g) * 2048 + j]     = z.x * sc;
      frames[(c * 32 + 2 * g + 1) * 2048 + j] = z.y * sc;
    }
  }
}

// ---------------- proj_in: h0[b,o,t] = sum_k Win[o][k]*spec[b,t,k] + bias ----------------
// v9: LDS-instruction diet. Old inner loop: 1024 ds_read_b32/thread (~20us
// per-CU LDS time -- same disease as the FFT). New: k in float4 chunks -> 8
// ds_read_b128 per 4 k (256 b128/thread, 4x fewer instrs); weight read is one
// float4 straight from Win's o-major row (no transpose needed). Occupancy
// unchanged (40 KB). Same FLOPs, same k coverage per (o,p) thread.
__global__ __launch_bounds__(256) void k_proj_in(const float* __restrict__ spec,
                                                 const float* __restrict__ Win,
                                                 const float* __restrict__ bias,
                                                 float* __restrict__ h0) {
  __shared__ float specL[8][1024];
  __shared__ float red[32][8][8];   // [o][tt][p]
  int b  = blockIdx.x >> 4;
  int t0 = (blockIdx.x & 15) * 8;
  for (int i = threadIdx.x; i < 8192; i += 256) {
    int tt = i >> 10, k = i & 1023;
    specL[tt][k] = spec[(b * 128 + t0 + tt) * 1024 + k];
  }
  __syncthreads();
  int o = threadIdx.x & 31, p = threadIdx.x >> 5;
  float part[8] = {0.f,0.f,0.f,0.f,0.f,0.f,0.f,0.f};
  const float4* Wrow = (const float4*)(Win + o * 1024);   // Win is [o][k]
  for (int k4 = p * 32; k4 < p * 32 + 32; ++k4) {         // 128 k per thread
    float4 w4 = Wrow[k4];
    int k = k4 * 4;
#pragma unroll
    for (int tt = 0; tt < 8; ++tt) {
      float4 s4 = *(const float4*)&specL[tt][k];
      part[tt] += w4.x * s4.x + w4.y * s4.y + w4.z * s4.z + w4.w * s4.w;
    }
  }
#pragma unroll
  for (int tt = 0; tt < 8; ++tt) red[o][tt][p] = part[tt];
  __syncthreads();
  int oo = threadIdx.x >> 3, tt2 = threadIdx.x & 7;
  float s = bias[oo];
#pragma unroll
  for (int p2 = 0; p2 < 8; ++p2) s += red[oo][tt2][p2];
  h0[b * 4096 + oo * 128 + t0 + tt2] = s;
}

// ---------------- fused overlap-add + B-pack (separate launch: full occupancy) ----------------
__global__ __launch_bounds__(256) void k_obpack(const float* __restrict__ frames,
                                                short* __restrict__ Bh,
                                                short* __restrict__ Bl) {
  int c = blockIdx.x >> 4, o = blockIdx.x & 15;
  int r = threadIdx.x;
  bf16x8 hv, lv;
#pragma unroll
  for (int j = 0; j < 8; ++j) {
    int fo = 8 * o + j;
    int g  = fo >> 2;
    int j0 = ((fo & 3) << 8) + r;
    float val = frames[(c * 32 + g) * 2048 + j0];
    if (g > 0) val += frames[(c * 32 + g - 1) * 2048 + j0 + 1024];
    unsigned bits = __float_as_uint(val);
    float rem = val - __uint_as_float(bits & 0xffff0000u);
    hv[j] = (short)(bits >> 16);
    lv[j] = (short)(__float_as_uint(rem) >> 16);
  }
  int unit = (blockIdx.x * 16 + (r >> 4)) * 16 + (r & 15);
  ((bf16x8*)Bh)[unit] = hv;
  ((bf16x8*)Bl)[unit] = lv;
}

// ---------------- 8-block anticausal chain as per-step MFMA GEMM pairs ----------------
__global__ __launch_bounds__(1024) void k_chain(const float* __restrict__ h0,
                                                const short* __restrict__ Whg,
                                                const short* __restrict__ Wlg,
                                                const float* __restrict__ bb,
                                                float* __restrict__ accout) {
  __shared__ __align__(16) short Hh[192 * 40];   // rows stride 40 bf16 (80 B)
  __shared__ __align__(16) short Hl[192 * 40];
  __shared__ float Hf[128 * 33];                 // fp32 H for exact residual
  __shared__ float bL[256];
  __shared__ float red[16];
  int b = blockIdx.x, tid = threadIdx.x;

  for (int i = tid; i < 4096; i += 1024) {
    int t = i & 127;                 // h0 layout [o][t]
    int o = i >> 7;
    float val = h0[b * 4096 + i];
    Hf[t * 33 + o] = val;
    unsigned bits = __float_as_uint(val);
    float rem = val - __uint_as_float(bits & 0xffff0000u);
    Hh[t * 40 + o] = (short)(bits >> 16);
    Hl[t * 40 + o] = (short)(__float_as_uint(rem) >> 16);
  }
  for (int i = tid; i < 64 * 40; i += 1024) {    // zero pad rows 128..191
    Hh[128 * 40 + i] = 0;
    Hl[128 * 40 + i] = 0;
  }
  if (tid < 256) bL[tid] = bb[tid];
  __syncthreads();

  int wave = tid >> 6, lane = tid & 63;
  int quad = lane >> 4, l15 = lane & 15;
  int t0 = (wave & 7) * 16, o0 = (wave >> 3) * 16;
  int tD = t0 + quad * 4;          // D rows tD..tD+3
  int oD = o0 + l15;               // D col

  const bf16x8* Hh8 = (const bf16x8*)Hh;   // unit = row*5 + quad (40 bf16 = 5 units)
  const bf16x8* Hl8 = (const bf16x8*)Hl;
  const bf16x8* Wh8 = (const bf16x8*)Whg;  // unit = row*4 + quad (32 bf16 = 4 units)
  const bf16x8* Wl8 = (const bf16x8*)Wlg;

  float accsum[4] = {0.f, 0.f, 0.f, 0.f};
  const int DIL[8] = {1, 2, 4, 8, 16, 32, 64, 1};

#pragma unroll
  for (int s = 0; s < 8; ++s) {
    int arow = t0 + l15;
    int frow = arow + DIL[s];        // <= 191, pad rows give zeros
    bf16x8 Ah = Hh8[arow * 5 + quad];
    bf16x8 Al = Hl8[arow * 5 + quad];
    bf16x8 Fh = Hh8[frow * 5 + quad];
    bf16x8 Fl = Hl8[frow * 5 + quad];
    int w0row = ((s * 2 + 0) * 32 + oD) * 4 + quad;
    int w1row = ((s * 2 + 1) * 32 + oD) * 4 + quad;
    bf16x8 B0h = Wh8[w0row], B0l = Wl8[w0row];
    bf16x8 B1h = Wh8[w1row], B1l = Wl8[w1row];
    float bias = bL[s * 32 + oD];
    f32x4 acc = {bias, bias, bias, bias};
    MFMA16(acc, Ah, B0h); MFMA16(acc, Ah, B0l); MFMA16(acc, Al, B0h);
    MFMA16(acc, Fh, B1h); MFMA16(acc, Fh, B1l); MFMA16(acc, Fl, B1h);
    float hnew[4], lmax = 0.f;
#pragma unroll
    for (int r = 0; r < 4; ++r) {
      float sv = acc[r];
      sv = (sv > 0.f) ? sv : 0.2f * sv;       // leaky_relu 0.2
      sv += Hf[(tD + r) * 33 + oD];           // residual (exact fp32)
      hnew[r] = sv;
      lmax = fmaxf(lmax, fabsf(sv));
    }
#pragma unroll
    for (int off = 32; off > 0; off >>= 1)
      lmax = fmaxf(lmax, __shfl_down(lmax, off, 64));
    if (lane == 0) red[wave] = lmax;
    __syncthreads();                 // red visible; all H reads of this step done
    float mx = red[0];
#pragma unroll
    for (int i = 1; i < 16; ++i) mx = fmaxf(mx, red[i]);
    float nm = 1.f / (mx + 1e-8f);
#pragma unroll
    for (int r = 0; r < 4; ++r) {
      float hv = hnew[r] * nm;
      accsum[r] += hv;
      int t = tD + r;
      Hf[t * 33 + oD] = hv;
      unsigned bits = __float_as_uint(hv);
      float rem = hv - __uint_as_float(bits & 0xffff0000u);
      Hh[t * 40 + oD] = (short)(bits >> 16);
      Hl[t * 40 + oD] = (short)(__float_as_uint(rem) >> 16);
    }
    __syncthreads();                 // new H visible for next step
  }
#pragma unroll
  for (int r = 0; r < 4; ++r)
    accout[b * 4096 + (tD + r) * 32 + oD] = accsum[r];
}

// ---------------- sparse + dense, 4 t per block (4x weight reuse + ILP) ----------------
__global__ __launch_bounds__(256) void k_sparse_dense(const float* __restrict__ acc,
                                                      const float* __restrict__ WsT,
                                                      const float* __restrict__ bs,
                                                      const float* __restrict__ WdT,
                                                      const float* __restrict__ bd,
                                                      float* __restrict__ out_sparse,
                                                      float* __restrict__ v) {
  __shared__ float accL[4][32];
  __shared__ float sL[4][256];
  __shared__ float red[8][4][32];   // [p][tt][c]
  int b = blockIdx.x >> 5, tq = blockIdx.x & 31;
  int t0 = tq * 4;
  int tid = threadIdx.x;
  if (tid < 128)
    accL[tid >> 5][tid & 31] = acc[b * 4096 + (t0 + (tid >> 5)) * 32 + (tid & 31)];
  __syncthreads();
  float bsv = bs[tid];
  float s0 = bsv, s1 = bsv, s2 = bsv, s3 = bsv;
  for (int m = 0; m < 32; ++m) {
    float w = WsT[m * 256 + tid];
    s0 += w * accL[0][m]; s1 += w * accL[1][m];
    s2 += w * accL[2][m]; s3 += w * accL[3][m];
  }
  s0 = fmaxf(s0, 0.f); s1 = fmaxf(s1, 0.f); s2 = fmaxf(s2, 0.f); s3 = fmaxf(s3, 0.f);
  float* os = out_sparse + b * 32768 + tid * 128 + t0;
  os[0] = s0; os[1] = s1; os[2] = s2; os[3] = s3;
  sL[0][tid] = s0; sL[1][tid] = s1; sL[2][tid] = s2; sL[3][tid] = s3;
  __syncthreads();
  int c = tid & 31, p = tid >> 5;
  float p0 = 0.f, p1 = 0.f, p2 = 0.f, p3 = 0.f;
  for (int jj = 0; jj < 32; ++jj) {
    int o2 = p * 32 + jj;
    float w = WdT[o2 * 32 + c];
    p0 += w * sL[0][o2]; p1 += w * sL[1][o2];
    p2 += w * sL[2][o2]; p3 += w * sL[3][o2];
  }
  red[p][0][c] = p0; red[p][1][c] = p1; red[p][2][c] = p2; red[p][3][c] = p3;
  __syncthreads();
  if (tid < 128) {
    int tt = tid >> 5, cc = tid & 31;
    float vv = bd[cc];
#pragma unroll
    for (int p2i = 0; p2i < 8; ++p2i) vv += red[p2i][tt][cc];
    v[b * 4096 + cc * 128 + t0 + tt] = vv;
  }
}

// ---------------- final conv as MFMA GEMM, v4 two-phase (proven best) ----------------
// Two-phase K=256 keeps LDS at 39.9 KB -> 4 blocks/CU (full 32 waves) -- k_conv
// is latency-bound and occupancy is the binding resource (v2/v5 lessons).
// XCD-group swizzle: all 32 b-blocks of one (j,uc) share one XCD's L2 slice.
__global__ __launch_bounds__(512, 4) void k_conv(const float* __restrict__ v,
                                                 const short* __restrict__ Bh,
                                                 const short* __restrict__ Bl,
                                                 float* __restrict__ y) {
  __shared__ __align__(16) short AH[32 * 264];   // [row 32][K 256 + pad 8]
  __shared__ __align__(16) short AL[32 * 264];
  __shared__ float vwin[2][16][48];              // [c-half][c_local][ii]

  // --- XCD-group swizzle: group e (20 of them) -> XCD e%8; batches fill slots.
  int xcd  = blockIdx.x & 7;
  int slot = blockIdx.x >> 3;
  int e, b;
  if      (slot < 32) { e = xcd;      b = slot; }
  else if (slot < 64) { e = xcd + 8;  b = slot - 32; }
  else                { e = (xcd < 4) ? (xcd + 16) : (xcd + 12);
                        b = (xcd < 4) ? (slot - 64) : (slot - 48); }
  int j, uc;
  if      (e < 2)  { j = 0; uc = e; }
  else if (e < 6)  { j = 1; uc = e - 2; }
  else if (e < 12) { j = 2; uc = e - 6; }
  else             { j = 3; uc = e - 12; }
  int D0 = 32 * j - 16 * uc;       // d = D0 - 15 + ii, ii in [0,46]

  // stage compact v windows (both c-halves): 2*16*47 floats
  for (int i = threadIdx.x; i < 1504; i += 512) {
    int ii = i % 47;
    int r  = i / 47;               // 0..31
    int c  = r & 15, ph = r >> 4;
    int d  = D0 - 15 + ii;
    vwin[ph][c][ii] = (d >= 0 && d < 128)
        ? v[b * 4096 + (16 * ph + c) * 128 + d] : 0.f;
  }
  __syncthreads();

  int lane = threadIdx.x & 63, wave = threadIdx.x >> 6;
  int quad = lane >> 4, l15 = lane & 15;
  int cq   = quad >> 1;            // low bit of c
  int og   = 2 * uc + (quad & 1);  // global u-octet
  int nt0  = wave * 2;             // 8 waves x 2 nt = 16 nt

  f32x4 acc00 = (f32x4)0.f, acc01 = (f32x4)0.f;   // [qs][t]
  f32x4 acc10 = (f32x4)0.f, acc11 = (f32x4)0.f;

  const bf16x8* AH8 = (const bf16x8*)AH;
  const bf16x8* AL8 = (const bf16x8*)AL;
  const bf16x8* Bh8 = (const bf16x8*)Bh;
  const bf16x8* Bl8 = (const bf16x8*)Bl;
  short2* AH2 = (short2*)AH;
  short2* AL2 = (short2*)AL;

  int abase0 = (0 * 16 + l15) * 33 + quad;   // bf16x8 units, row stride 33
  int abase1 = (1 * 16 + l15) * 33 + quad;

  for (int p = 0; p < 2; ++p) {
    // expand Toeplitz A (hi/lo split) for this c-half: 32 rows x 128 kk-pairs
    for (int i = threadIdx.x; i < 4096; i += 512) {
      int kk2 = i & 127;           // kk = 2*kk2 (pair shares c_local)
      int row = i >> 7;            // 0..31
      int cl  = kk2 >> 3;
      int uu  = (kk2 & 7) * 2;
      int ii  = row - uu + 15;
      float v0 = vwin[p][cl][ii];
      float v1 = vwin[p][cl][ii - 1];
      unsigned w0 = __float_as_uint(v0), w1 = __float_as_uint(v1);
      float r0 = v0 - __uint_as_float(w0 & 0xffff0000u);
      float r1 = v1 - __uint_as_float(w1 & 0xffff0000u);
      int u2 = row * 132 + kk2;    // short2 units, row stride 132
      AH2[u2] = make_short2((short)(w0 >> 16), (short)(w1 >> 16));
      AL2[u2] = make_short2((short)(__float_as_uint(r0) >> 16),
                            (short)(__float_as_uint(r1) >> 16));
    }
    __syncthreads();

#pragma unroll
    for (int ks = 0; ks < 8; ++ks) {
      bf16x8 ah0 = AH8[abase0 + ks * 4];
      bf16x8 al0 = AL8[abase0 + ks * 4];
      bf16x8 ah1 = AH8[abase1 + ks * 4];
      bf16x8 al1 = AL8[abase1 + ks * 4];
      int c   = 16 * p + 2 * ks + cq;
      int bb0 = (c * 16 + og) * 256 + l15;
      bf16x8 bh0 = Bh8[bb0 + nt0 * 16];
      bf16x8 bl0 = Bl8[bb0 + nt0 * 16];
      bf16x8 bh1 = Bh8[bb0 + (nt0 + 1) * 16];
      bf16x8 bl1 = Bl8[bb0 + (nt0 + 1) * 16];
      MFMA16(acc00, ah0, bh0); MFMA16(acc00, ah0, bl0); MFMA16(acc00, al0, bh0);
      MFMA16(acc10, ah1, bh0); MFMA16(acc10, ah1, bl0); MFMA16(acc10, al1, bh0);
      MFMA16(acc01, ah0, bh1); MFMA16(acc01, ah0, bl1); MFMA16(acc01, al0, bh1);
      MFMA16(acc11, ah1, bh1); MFMA16(acc11, ah1, bl1); MFMA16(acc11, al1, bh1);
    }
    __syncthreads();               // A consumed; safe to overwrite in next phase
  }

  {
    float* yb0 = y + b * 32768 + (32 * j + 0 * 16 + quad * 4) * 256 + l15;
    float* yb1 = y + b * 32768 + (32 * j + 1 * 16 + quad * 4) * 256 + l15;
#pragma unroll
    for (int reg = 0; reg < 4; ++reg) {
      atomicAdd(yb0 + reg * 256 + (nt0 + 0) * 16, acc00[reg]);
      atomicAdd(yb0 + reg * 256 + (nt0 + 1) * 16, acc01[reg]);
      atomicAdd(yb1 + reg * 256 + (nt0 + 0) * 16, acc10[reg]);
      atomicAdd(yb1 + reg * 256 + (nt0 + 1) * 16, acc11[reg]);
    }
  }
}

extern "C" void kernel_launch(void* const* d_in, const int* in_sizes, int n_in,
                              void* d_out, int out_size, void* d_ws, size_t ws_size,
                              hipStream_t stream) {
  const float* audio = (const float*)d_in[0];
  const float* Win   = (const float*)d_in[1];
  const float* bin   = (const float*)d_in[2];
  const float* bw    = (const float*)d_in[3];
  const float* bb    = (const float*)d_in[4];
  const float* Ws    = (const float*)d_in[5];
  const float* bs    = (const float*)d_in[6];
  const float* Wd    = (const float*)d_in[7];
  const float* bd    = (const float*)d_in[8];
  const float* reson = (const float*)d_in[9];

  float* out = (float*)d_out;           // [0,1048576) = y ; [1048576,2097152) = sparse
  float* ws  = (float*)d_ws;

  float* spec   = ws + WS_SPEC;
  float* h0     = ws + WS_H0;
  float* accb   = ws + WS_ACC;
  float* vbuf   = ws + WS_V;
  float* WT     = ws + WS_WTIN;
  float* WsT    = ws + WS_WST;
  float* WdT    = ws + WS_WDT;
  float* frames = ws + WS_FRAMES;
  // WS_RES region (dead after fusing overlap-add into k_obpack) -> bf16 B packs
  short* Bh = (short*)(ws + WS_RES);               // 1,048,576 bf16 = 2 MB
  short* Bl = (short*)(ws + WS_RES + 524288u);     // 1,048,576 bf16 = 2 MB
  // chain-weight packs live in WS_V until k_sparse_dense overwrites it (after k_chain)
  short* Whg = (short*)(ws + WS_V);                // 16384 bf16 = 32 KB
  short* Wlg = (short*)(ws + WS_V + 8192u);        // 16384 bf16 = 32 KB

  // zero y region (atomicAdd target); d_out is poisoned before every launch
  hipMemsetAsync(d_out, 0, 1048576u * sizeof(float), stream);

  k_fft<<<2688, 256, 0, stream>>>(audio, reson, Win, Ws, Wd, bw,
                                  spec, frames, WT, WsT, WdT, Whg, Wlg);
  k_obpack<<<512, 256, 0, stream>>>(frames, Bh, Bl);
  k_proj_in<<<512, 256, 0, stream>>>(spec, Win, bin, h0);
  k_chain<<<32, 1024, 0, stream>>>(h0, Whg, Wlg, bb, accb);
  k_sparse_dense<<<1024, 256, 0, stream>>>(accb, WsT, bs, WdT, bd, out + 1048576, vbuf);
  k_conv<<<640, 512, 0, stream>>>(vbuf, Bh, Bl, out);
}

// Round 10
// 174.457 us; speedup vs baseline: 1.1317x; 1.0183x over previous
//
#include <hip/hip_runtime.h>

#define PI_F 3.14159265358979323846f

typedef short bf16x8 __attribute__((ext_vector_type(8)));
typedef float f32x4 __attribute__((ext_vector_type(4)));

#define MFMA16(acc, a, b) \
  acc = __builtin_amdgcn_mfma_f32_16x16x32_bf16(a, b, acc, 0, 0, 0)

// ---------------- workspace layout (float offsets) ----------------
#define WS_SPEC   0u          // 32*128*1024  [b][t][k]
#define WS_H0     4194304u    // 32*32*128    [b][o][t]
#define WS_ACC    4325376u    // 32*128*32    [b][t][o]
#define WS_V      4456448u    // 32*32*128    [b][c][t]; ALSO: prep stashes the
                              // chain-weight bf16 packs in the first 16384 floats
#define WS_WTIN   4587520u    // 1024*32      [k][o] (legacy, unused by proj_in v9+)
#define WS_WST    4620288u    // 32*256       [m][o2]
#define WS_WDT    4628480u    // 256*32       [o2][c]
#define WS_FRAMES 4636672u    // 32*32*2048   [c][f][j]
#define WS_RES    6733824u    // (dead: res assembly fused into obpack) -> Bh/Bl packs
// total 7782400 floats = ~29.7 MB

// ---- 2048-pt complex DIT FFT, bit-reversed input, 256 thr ----
// v9 structure (proven): radix-8 fusion, 4 LDS passes; BIX padding.
#define BIX(a) ((a) + ((a) >> 4))

#define BFLY(I0, I1, C, S)                                   \
  { float2 u = buf[I0]; float2 w = buf[I1];                  \
    float tr = (C) * w.x - (S) * w.y;                        \
    float ti = (C) * w.y + (S) * w.x;                        \
    buf[I0] = make_float2(u.x + tr, u.y + ti);               \
    buf[I1] = make_float2(u.x - tr, u.y - ti); }

#define CMULV(RX, RY, C, S, W) \
  { RX = (C) * (W).x - (S) * (W).y; RY = (C) * (W).y + (S) * (W).x; }

// fused stages (s, s+1): ws=(cs,ss) for stage s, w'=(cp,sp) for stage s+1.
__device__ __forceinline__ void quad_bfly(float2* buf, int a, int h,
                                          float cs, float ss, float cp, float sp) {
  float2 x0 = buf[BIX(a)],         x1 = buf[BIX(a + h)];
  float2 x2 = buf[BIX(a + 2 * h)], x3 = buf[BIX(a + 3 * h)];
  float t1x = cs * x1.x - ss * x1.y, t1y = cs * x1.y + ss * x1.x;
  float t3x = cs * x3.x - ss * x3.y, t3y = cs * x3.y + ss * x3.x;
  float2 y0 = make_float2(x0.x + t1x, x0.y + t1y);
  float2 y1 = make_float2(x0.x - t1x, x0.y - t1y);
  float2 y2 = make_float2(x2.x + t3x, x2.y + t3y);
  float2 y3 = make_float2(x2.x - t3x, x2.y - t3y);
  float u2x = cp * y2.x - sp * y2.y, u2y = cp * y2.y + sp * y2.x;
  float u3x = sp * y3.x + cp * y3.y, u3y = sp * y3.y - cp * y3.x;  // (-i w')*y3
  buf[BIX(a)]         = make_float2(y0.x + u2x, y0.y + u2y);
  buf[BIX(a + 2 * h)] = make_float2(y0.x - u2x, y0.y - u2y);
  buf[BIX(a + h)]     = make_float2(y1.x + u3x, y1.y + u3y);
  buf[BIX(a + 3 * h)] = make_float2(y1.x - u3x, y1.y - u3y);
}

// fused stages (s, s+1, s+2) on octet {a + k*h}, k=0..7. v = e^{-i pi j/4h}.
__device__ __forceinline__ void octet_bfly(float2* buf, int a, int h,
                                           float cv, float sv) {
  const float R = 0.7071067811865476f;
  float c1 = cv * cv - sv * sv, s1 = 2.f * cv * sv;   // w' = v^2
  float c2 = c1 * c1 - s1 * s1, s2 = 2.f * c1 * s1;   // ws = v^4
  float2 x0 = buf[BIX(a)],         x1 = buf[BIX(a + h)];
  float2 x2 = buf[BIX(a + 2 * h)], x3 = buf[BIX(a + 3 * h)];
  float2 x4 = buf[BIX(a + 4 * h)], x5 = buf[BIX(a + 5 * h)];
  float2 x6 = buf[BIX(a + 6 * h)], x7 = buf[BIX(a + 7 * h)];
  float tx, ty;
  CMULV(tx, ty, c2, s2, x1);
  float2 y0 = make_float2(x0.x + tx, x0.y + ty), y1 = make_float2(x0.x - tx, x0.y - ty);
  CMULV(tx, ty, c2, s2, x3);
  float2 y2 = make_float2(x2.x + tx, x2.y + ty), y3 = make_float2(x2.x - tx, x2.y - ty);
  CMULV(tx, ty, c2, s2, x5);
  float2 y4 = make_float2(x4.x + tx, x4.y + ty), y5 = make_float2(x4.x - tx, x4.y - ty);
  CMULV(tx, ty, c2, s2, x7);
  float2 y6 = make_float2(x6.x + tx, x6.y + ty), y7 = make_float2(x6.x - tx, x6.y - ty);
  CMULV(tx, ty, c1, s1, y2);
  float2 z0 = make_float2(y0.x + tx, y0.y + ty), z2 = make_float2(y0.x - tx, y0.y - ty);
  CMULV(tx, ty, c1, s1, y3);    // -i*u = (u.y, -u.x)
  float2 z1 = make_float2(y1.x + ty, y1.y - tx), z3 = make_float2(y1.x - ty, y1.y + tx);
  CMULV(tx, ty, c1, s1, y6);
  float2 z4 = make_float2(y4.x + tx, y4.y + ty), z6 = make_float2(y4.x - tx, y4.y - ty);
  CMULV(tx, ty, c1, s1, y7);
  float2 z5 = make_float2(y5.x + ty, y5.y - tx), z7 = make_float2(y5.x - ty, y5.y + tx);
  float ca = R * (cv + sv), sa = R * (sv - cv);   // v*w8
  float cb = sv,            sb = -cv;             // -i*v
  float cc = R * (sv - cv), sc = -R * (cv + sv);  // v*w8^3
  CMULV(tx, ty, cv, sv, z4);
  buf[BIX(a)]         = make_float2(z0.x + tx, z0.y + ty);
  buf[BIX(a + 4 * h)] = make_float2(z0.x - tx, z0.y - ty);
  CMULV(tx, ty, ca, sa, z5);
  buf[BIX(a + h)]     = make_float2(z1.x + tx, z1.y + ty);
  buf[BIX(a + 5 * h)] = make_float2(z1.x - tx, z1.y - ty);
  CMULV(tx, ty, cb, sb, z6);
  buf[BIX(a + 2 * h)] = make_float2(z2.x + tx, z2.y + ty);
  buf[BIX(a + 6 * h)] = make_float2(z2.x - tx, z2.y - ty);
  CMULV(tx, ty, cc, sc, z7);
  buf[BIX(a + 3 * h)] = make_float2(z3.x + tx, z3.y + ty);
  buf[BIX(a + 7 * h)] = make_float2(z3.x - tx, z3.y - ty);
}

__device__ __forceinline__ void fft2048_stages(float2* buf, int tid) {
  octet_bfly(buf, tid << 3, 1, 1.f, 0.f);
  __syncthreads();
  {
    int j = tid & 7;
    int a = ((tid >> 3) << 6) + j;
    float sv, cv;
    __sincosf(-PI_F / 32.f * (float)j, &sv, &cv);
    octet_bfly(buf, a, 8, cv, sv);
  }
  __syncthreads();
  {
    int j = tid & 63;
    int a = ((tid >> 6) << 9) + j;
    float sv, cv;
    __sincosf(-PI_F / 256.f * (float)j, &sv, &cv);
    octet_bfly(buf, a, 64, cv, sv);
  }
  __syncthreads();
  for (int g = tid; g < 512; g += 256) {
    float sp, cp;
    __sincosf(-PI_F / 1024.f * (float)g, &sp, &cp);   // w' (stage 10)
    float c2 = cp * cp - sp * sp, s2 = 2.f * cp * sp; // ws = w'^2 (stage 9)
    quad_bfly(buf, g, 512, c2, s2, cp, sp);
  }
  __syncthreads();
}

// ---------------- fused FFT kernel: STFT pairs + resonance pairs + prep tail ----------------
__global__ __launch_bounds__(256) void k_fft(const float* __restrict__ audio,
                                             const float* __restrict__ resin,
                                             const float* __restrict__ Win,
                                             const float* __restrict__ Ws,
                                             const float* __restrict__ Wd,
                                             const float* __restrict__ bwIn,
                                             float* __restrict__ spec,
                                             float* __restrict__ frames,
                                             float* __restrict__ WT,
                                             float* __restrict__ WsT,
                                             float* __restrict__ WdT,
                                             short* __restrict__ Whg,
                                             short* __restrict__ Wlg) {
  __shared__ float2 buf[2176];        // 2048 + BIX padding
  int blk = blockIdx.x;

  if (blk >= 2560) {                  // ---- prep branch (no LDS use, no syncs) ----
    int i = (blk - 2560) * 256 + threadIdx.x;
    if (i < 8192)  { int o2 = i >> 5, m = i & 31;   WsT[m * 256 + o2] = Ws[i]; }
    if (i < 8192)  { int c = i >> 8, o2 = i & 255;  WdT[o2 * 32 + c] = Wd[i]; }
    if (i < 16384) {
      // i = ((s*32+o)*32+m)*2 + w
      int w = i & 1, m = (i >> 1) & 31, o = (i >> 6) & 31, s = i >> 11;
      float val = bwIn[i];
      unsigned bits = __float_as_uint(val);
      float rem = val - __uint_as_float(bits & 0xffff0000u);
      int row = (s * 2 + w) * 32 + o;
      Whg[row * 32 + m] = (short)(bits >> 16);
      Wlg[row * 32 + m] = (short)(__float_as_uint(rem) >> 16);
    }
    return;
  }

  if (blk < 2048) {
    int b  = blk >> 6;
    int f0 = (blk & 63) * 2;      // frames f0, f0+1
    for (int j = threadIdx.x; j < 2048; j += 256) {
      float h = 0.5f - 0.5f * __cosf(0.0030679615757712823f * (float)j); // 2pi/2048
      int i1 = f0 * 256 + j;
      int i2 = i1 + 256;
      float a1 = (i1 < 32768) ? audio[b * 32768 + i1] : 0.f;
      float a2 = (i2 < 32768) ? audio[b * 32768 + i2] : 0.f;
      buf[BIX(__brev((unsigned)j) >> 21)] = make_float2(a1 * h, a2 * h);
    }
    __syncthreads();
    fft2048_stages(buf, threadIdx.x);
    const float scale = 0.5f * 0.022097086912079608f;  // 0.5 / sqrt(2048)
    for (int k = threadIdx.x; k < 1024; k += 256) {
      float2 zk = buf[BIX(k)];
      float2 zn = buf[BIX((2048 - k) & 2047)];
      float f1r = zk.x + zn.x, f1i = zk.y - zn.y;
      float f2r = zk.y + zn.y, f2i = zk.x - zn.x;
      spec[(b * 128 + f0) * 1024 + k]     = sqrtf(f1r * f1r + f1i * f1i) * scale;
      spec[(b * 128 + f0 + 1) * 1024 + k] = sqrtf(f2r * f2r + f2i * f2i) * scale;
    }
  } else {
    int r = blk - 2048;           // 0..511
    int c = r >> 4;
    int g = r & 15;               // frames 2g (exp 2g+1), 2g+1 (exp 2g+2)
    float e1 = (float)(2 * g + 1);
    for (int k = threadIdx.x; k < 2048; k += 256) {
      int kk = (k <= 1024) ? k : 2048 - k;   // Hermitian (real) extension
      float cv = resin[c * 1025 + kk];
      cv = fminf(fmaxf(cv, 0.f), 0.9999f);
      float m1 = __powf(cv, e1);
      float m2 = m1 * cv;
      buf[BIX(__brev((unsigned)k) >> 21)] = make_float2(m1, m2);
    }
    __syncthreads();
    fft2048_stages(buf, threadIdx.x);
    for (int j = threadIdx.x; j < 2048; j += 256) {
      float h  = 0.5f - 0.5f * __cosf(0.0030679615757712823f * (float)j);
      float sc = h * (1.f / 2048.f);
      float2 z = buf[BIX(j)];
      frames[(c * 32 + 2 * g) * 2048 + j]     = z.x * sc;
      frames[(c * 32 + 2 * g + 1) * 2048 + j] = z.y * sc;
    }
  }
}

// ---------------- proj_in: h0[b,o,t] = sum_k Win[o][k]*spec[b,t,k] + bias ----------------
// v9 form (proven): float4 LDS reads (broadcast across half-wave), Win o-major.
__global__ __launch_bounds__(256) void k_proj_in(const float* __restrict__ spec,
                                                 const float* __restrict__ Win,
                                                 const float* __restrict__ bias,
                                                 float* __restrict__ h0) {
  __shared__ float specL[8][1024];
  __shared__ float red[32][8][8];   // [o][tt][p]
  int b  = blockIdx.x >> 4;
  int t0 = (blockIdx.x & 15) * 8;
  for (int i = threadIdx.x; i < 8192; i += 256) {
    int tt = i >> 10, k = i & 1023;
    specL[tt][k] = spec[(b * 128 + t0 + tt) * 1024 + k];
  }
  __syncthreads();
  int o = threadIdx.x & 31, p = threadIdx.x >> 5;
  float part[8] = {0.f,0.f,0.f,0.f,0.f,0.f,0.f,0.f};
  const float4* Wrow = (const float4*)(Win + o * 1024);   // Win is [o][k]
  for (int k4 = p * 32; k4 < p * 32 + 32; ++k4) {         // 128 k per thread
    float4 w4 = Wrow[k4];
    int k = k4 * 4;
#pragma unroll
    for (int tt = 0; tt < 8; ++tt) {
      float4 s4 = *(const float4*)&specL[tt][k];
      part[tt] += w4.x * s4.x + w4.y * s4.y + w4.z * s4.z + w4.w * s4.w;
    }
  }
#pragma unroll
  for (int tt = 0; tt < 8; ++tt) red[o][tt][p] = part[tt];
  __syncthreads();
  int oo = threadIdx.x >> 3, tt2 = threadIdx.x & 7;
  float s = bias[oo];
#pragma unroll
  for (int p2 = 0; p2 < 8; ++p2) s += red[oo][tt2][p2];
  h0[b * 4096 + oo * 128 + t0 + tt2] = s;
}

// ---------------- chain (blocks 0..31) + fused overlap-add/B-pack (blocks 32..159) ----------------
// v10: obpack is INDEPENDENT of the proj_in->chain->sparse_dense spine (only
// k_conv consumes Bh/Bl), and k_chain uses exactly 32 blocks = 32 CUs, leaving
// 224 CUs idle. Merging obpack into this launch hides its entire duration and
// removes one launch slot. obpack blocks: 1024 thr = 4 old 256-thr blocks.
__global__ __launch_bounds__(1024) void k_chain(const float* __restrict__ h0,
                                                const short* __restrict__ Whg,
                                                const short* __restrict__ Wlg,
                                                const float* __restrict__ bb,
                                                float* __restrict__ accout,
                                                const float* __restrict__ frames,
                                                short* __restrict__ Bh,
                                                short* __restrict__ Bl) {
  __shared__ __align__(16) short Hh[192 * 40];   // rows stride 40 bf16 (80 B)
  __shared__ __align__(16) short Hl[192 * 40];
  __shared__ float Hf[128 * 33];                 // fp32 H for exact residual
  __shared__ float bL[256];
  __shared__ float red[16];
  int blk = blockIdx.x, tid = threadIdx.x;

  if (blk >= 32) {                  // ---- obpack branch (no LDS use, no syncs) ----
    int ubb = (blk - 32) * 4 + (tid >> 8);   // old obpack block id 0..511
    int r   = tid & 255;
    int c   = ubb >> 4, o = ubb & 15;
    bf16x8 hv, lv;
#pragma unroll
    for (int j = 0; j < 8; ++j) {
      int fo = 8 * o + j;
      int g  = fo >> 2;
      int j0 = ((fo & 3) << 8) + r;
      float val = frames[(c * 32 + g) * 2048 + j0];
      if (g > 0) val += frames[(c * 32 + g - 1) * 2048 + j0 + 1024];
      unsigned bits = __float_as_uint(val);
      float rem = val - __uint_as_float(bits & 0xffff0000u);
      hv[j] = (short)(bits >> 16);
      lv[j] = (short)(__float_as_uint(rem) >> 16);
    }
    int unit = (ubb * 16 + (r >> 4)) * 16 + (r & 15);
    ((bf16x8*)Bh)[unit] = hv;
    ((bf16x8*)Bl)[unit] = lv;
    return;
  }

  int b = blk;
  for (int i = tid; i < 4096; i += 1024) {
    int t = i & 127;                 // h0 layout [o][t]
    int o = i >> 7;
    float val = h0[b * 4096 + i];
    Hf[t * 33 + o] = val;
    unsigned bits = __float_as_uint(val);
    float rem = val - __uint_as_float(bits & 0xffff0000u);
    Hh[t * 40 + o] = (short)(bits >> 16);
    Hl[t * 40 + o] = (short)(__float_as_uint(rem) >> 16);
  }
  for (int i = tid; i < 64 * 40; i += 1024) {    // zero pad rows 128..191
    Hh[128 * 40 + i] = 0;
    Hl[128 * 40 + i] = 0;
  }
  if (tid < 256) bL[tid] = bb[tid];
  __syncthreads();

  int wave = tid >> 6, lane = tid & 63;
  int quad = lane >> 4, l15 = lane & 15;
  int t0 = (wave & 7) * 16, o0 = (wave >> 3) * 16;
  int tD = t0 + quad * 4;          // D rows tD..tD+3
  int oD = o0 + l15;               // D col

  const bf16x8* Hh8 = (const bf16x8*)Hh;   // unit = row*5 + quad (40 bf16 = 5 units)
  const bf16x8* Hl8 = (const bf16x8*)Hl;
  const bf16x8* Wh8 = (const bf16x8*)Whg;  // unit = row*4 + quad (32 bf16 = 4 units)
  const bf16x8* Wl8 = (const bf16x8*)Wlg;

  float accsum[4] = {0.f, 0.f, 0.f, 0.f};
  const int DIL[8] = {1, 2, 4, 8, 16, 32, 64, 1};

#pragma unroll
  for (int s = 0; s < 8; ++s) {
    int arow = t0 + l15;
    int frow = arow + DIL[s];        // <= 191, pad rows give zeros
    bf16x8 Ah = Hh8[arow * 5 + quad];
    bf16x8 Al = Hl8[arow * 5 + quad];
    bf16x8 Fh = Hh8[frow * 5 + quad];
    bf16x8 Fl = Hl8[frow * 5 + quad];
    int w0row = ((s * 2 + 0) * 32 + oD) * 4 + quad;
    int w1row = ((s * 2 + 1) * 32 + oD) * 4 + quad;
    bf16x8 B0h = Wh8[w0row], B0l = Wl8[w0row];
    bf16x8 B1h = Wh8[w1row], B1l = Wl8[w1row];
    float bias = bL[s * 32 + oD];
    f32x4 acc = {bias, bias, bias, bias};
    MFMA16(acc, Ah, B0h); MFMA16(acc, Ah, B0l); MFMA16(acc, Al, B0h);
    MFMA16(acc, Fh, B1h); MFMA16(acc, Fh, B1l); MFMA16(acc, Fl, B1h);
    float hnew[4], lmax = 0.f;
#pragma unroll
    for (int r = 0; r < 4; ++r) {
      float sv = acc[r];
      sv = (sv > 0.f) ? sv : 0.2f * sv;       // leaky_relu 0.2
      sv += Hf[(tD + r) * 33 + oD];           // residual (exact fp32)
      hnew[r] = sv;
      lmax = fmaxf(lmax, fabsf(sv));
    }
#pragma unroll
    for (int off = 32; off > 0; off >>= 1)
      lmax = fmaxf(lmax, __shfl_down(lmax, off, 64));
    if (lane == 0) red[wave] = lmax;
    __syncthreads();                 // red visible; all H reads of this step done
    float mx = red[0];
#pragma unroll
    for (int i = 1; i < 16; ++i) mx = fmaxf(mx, red[i]);
    float nm = 1.f / (mx + 1e-8f);
#pragma unroll
    for (int r = 0; r < 4; ++r) {
      float hv = hnew[r] * nm;
      accsum[r] += hv;
      int t = tD + r;
      Hf[t * 33 + oD] = hv;
      unsigned bits = __float_as_uint(hv);
      float rem = hv - __uint_as_float(bits & 0xffff0000u);
      Hh[t * 40 + oD] = (short)(bits >> 16);
      Hl[t * 40 + oD] = (short)(__float_as_uint(rem) >> 16);
    }
    __syncthreads();                 // new H visible for next step
  }
#pragma unroll
  for (int r = 0; r < 4; ++r)
    accout[b * 4096 + (tD + r) * 32 + oD] = accsum[r];
}

// ---------------- sparse + dense, 8 t per block (v10: halve weight L2 re-reads) ----------------
__global__ __launch_bounds__(256) void k_sparse_dense(const float* __restrict__ acc,
                                                      const float* __restrict__ WsT,
                                                      const float* __restrict__ bs,
                                                      const float* __restrict__ WdT,
                                                      const float* __restrict__ bd,
                                                      float* __restrict__ out_sparse,
                                                      float* __restrict__ v) {
  __shared__ float accL[8][32];
  __shared__ float sL[8][256];
  __shared__ float red[8][8][32];   // [p][tt][c]
  int b = blockIdx.x >> 4, tq = blockIdx.x & 15;
  int t0 = tq * 8;
  int tid = threadIdx.x;
  accL[tid >> 5][tid & 31] = acc[b * 4096 + (t0 + (tid >> 5)) * 32 + (tid & 31)];
  __syncthreads();
  float bsv = bs[tid];
  float s[8];
#pragma unroll
  for (int j = 0; j < 8; ++j) s[j] = bsv;
  for (int m = 0; m < 32; ++m) {
    float w = WsT[m * 256 + tid];
#pragma unroll
    for (int j = 0; j < 8; ++j) s[j] += w * accL[j][m];
  }
  float* os = out_sparse + b * 32768 + tid * 128 + t0;
#pragma unroll
  for (int j = 0; j < 8; ++j) {
    s[j] = fmaxf(s[j], 0.f);
    os[j] = s[j];
    sL[j][tid] = s[j];
  }
  __syncthreads();
  int c = tid & 31, p = tid >> 5;
  float pp[8] = {0.f,0.f,0.f,0.f,0.f,0.f,0.f,0.f};
  for (int jj = 0; jj < 32; ++jj) {
    int o2 = p * 32 + jj;
    float w = WdT[o2 * 32 + c];
#pragma unroll
    for (int j = 0; j < 8; ++j) pp[j] += w * sL[j][o2];
  }
#pragma unroll
  for (int j = 0; j < 8; ++j) red[p][j][c] = pp[j];
  __syncthreads();
  {
    int tt = tid >> 5, cc = tid & 31;
    float vv = bd[cc];
#pragma unroll
    for (int p2i = 0; p2i < 8; ++p2i) vv += red[p2i][tt][cc];
    v[b * 4096 + cc * 128 + t0 + tt] = vv;
  }
}

// ---------------- final conv as MFMA GEMM, v4 two-phase (proven best) ----------------
// Two-phase K=256 keeps LDS at 39.9 KB -> 4 blocks/CU (full 32 waves) -- k_conv
// is latency-bound and occupancy is the binding resource (v2/v5 lessons).
// XCD-group swizzle: all 32 b-blocks of one (j,uc) share one XCD's L2 slice.
__global__ __launch_bounds__(512, 4) void k_conv(const float* __restrict__ v,
                                                 const short* __restrict__ Bh,
                                                 const short* __restrict__ Bl,
                                                 float* __restrict__ y) {
  __shared__ __align__(16) short AH[32 * 264];   // [row 32][K 256 + pad 8]
  __shared__ __align__(16) short AL[32 * 264];
  __shared__ float vwin[2][16][48];              // [c-half][c_local][ii]

  // --- XCD-group swizzle: group e (20 of them) -> XCD e%8; batches fill slots.
  int xcd  = blockIdx.x & 7;
  int slot = blockIdx.x >> 3;
  int e, b;
  if      (slot < 32) { e = xcd;      b = slot; }
  else if (slot < 64) { e = xcd + 8;  b = slot - 32; }
  else                { e = (xcd < 4) ? (xcd + 16) : (xcd + 12);
                        b = (xcd < 4) ? (slot - 64) : (slot - 48); }
  int j, uc;
  if      (e < 2)  { j = 0; uc = e; }
  else if (e < 6)  { j = 1; uc = e - 2; }
  else if (e < 12) { j = 2; uc = e - 6; }
  else             { j = 3; uc = e - 12; }
  int D0 = 32 * j - 16 * uc;       // d = D0 - 15 + ii, ii in [0,46]

  // stage compact v windows (both c-halves): 2*16*47 floats
  for (int i = threadIdx.x; i < 1504; i += 512) {
    int ii = i % 47;
    int r  = i / 47;               // 0..31
    int c  = r & 15, ph = r >> 4;
    int d  = D0 - 15 + ii;
    vwin[ph][c][ii] = (d >= 0 && d < 128)
        ? v[b * 4096 + (16 * ph + c) * 128 + d] : 0.f;
  }
  __syncthreads();

  int lane = threadIdx.x & 63, wave = threadIdx.x >> 6;
  int quad = lane >> 4, l15 = lane & 15;
  int cq   = quad >> 1;            // low bit of c
  int og   = 2 * uc + (quad & 1);  // global u-octet
  int nt0  = wave * 2;             // 8 waves x 2 nt = 16 nt

  f32x4 acc00 = (f32x4)0.f, acc01 = (f32x4)0.f;   // [qs][t]
  f32x4 acc10 = (f32x4)0.f, acc11 = (f32x4)0.f;

  const bf16x8* AH8 = (const bf16x8*)AH;
  const bf16x8* AL8 = (const bf16x8*)AL;
  const bf16x8* Bh8 = (const bf16x8*)Bh;
  const bf16x8* Bl8 = (const bf16x8*)Bl;
  short2* AH2 = (short2*)AH;
  short2* AL2 = (short2*)AL;

  int abase0 = (0 * 16 + l15) * 33 + quad;   // bf16x8 units, row stride 33
  int abase1 = (1 * 16 + l15) * 33 + quad;

  for (int p = 0; p < 2; ++p) {
    // expand Toeplitz A (hi/lo split) for this c-half: 32 rows x 128 kk-pairs
    for (int i = threadIdx.x; i < 4096; i += 512) {
      int kk2 = i & 127;           // kk = 2*kk2 (pair shares c_local)
      int row = i >> 7;            // 0..31
      int cl  = kk2 >> 3;
      int uu  = (kk2 & 7) * 2;
      int ii  = row - uu + 15;
      float v0 = vwin[p][cl][ii];
      float v1 = vwin[p][cl][ii - 1];
      unsigned w0 = __float_as_uint(v0), w1 = __float_as_uint(v1);
      float r0 = v0 - __uint_as_float(w0 & 0xffff0000u);
      float r1 = v1 - __uint_as_float(w1 & 0xffff0000u);
      int u2 = row * 132 + kk2;    // short2 units, row stride 132
      AH2[u2] = make_short2((short)(w0 >> 16), (short)(w1 >> 16));
      AL2[u2] = make_short2((short)(__float_as_uint(r0) >> 16),
                            (short)(__float_as_uint(r1) >> 16));
    }
    __syncthreads();

#pragma unroll
    for (int ks = 0; ks < 8; ++ks) {
      bf16x8 ah0 = AH8[abase0 + ks * 4];
      bf16x8 al0 = AL8[abase0 + ks * 4];
      bf16x8 ah1 = AH8[abase1 + ks * 4];
      bf16x8 al1 = AL8[abase1 + ks * 4];
      int c   = 16 * p + 2 * ks + cq;
      int bb0 = (c * 16 + og) * 256 + l15;
      bf16x8 bh0 = Bh8[bb0 + nt0 * 16];
      bf16x8 bl0 = Bl8[bb0 + nt0 * 16];
      bf16x8 bh1 = Bh8[bb0 + (nt0 + 1) * 16];
      bf16x8 bl1 = Bl8[bb0 + (nt0 + 1) * 16];
      MFMA16(acc00, ah0, bh0); MFMA16(acc00, ah0, bl0); MFMA16(acc00, al0, bh0);
      MFMA16(acc10, ah1, bh0); MFMA16(acc10, ah1, bl0); MFMA16(acc10, al1, bh0);
      MFMA16(acc01, ah0, bh1); MFMA16(acc01, ah0, bl1); MFMA16(acc01, al0, bh1);
      MFMA16(acc11, ah1, bh1); MFMA16(acc11, ah1, bl1); MFMA16(acc11, al1, bh1);
    }
    __syncthreads();               // A consumed; safe to overwrite in next phase
  }

  {
    float* yb0 = y + b * 32768 + (32 * j + 0 * 16 + quad * 4) * 256 + l15;
    float* yb1 = y + b * 32768 + (32 * j + 1 * 16 + quad * 4) * 256 + l15;
#pragma unroll
    for (int reg = 0; reg < 4; ++reg) {
      atomicAdd(yb0 + reg * 256 + (nt0 + 0) * 16, acc00[reg]);
      atomicAdd(yb0 + reg * 256 + (nt0 + 1) * 16, acc01[reg]);
      atomicAdd(yb1 + reg * 256 + (nt0 + 0) * 16, acc10[reg]);
      atomicAdd(yb1 + reg * 256 + (nt0 + 1) * 16, acc11[reg]);
    }
  }
}

extern "C" void kernel_launch(void* const* d_in, const int* in_sizes, int n_in,
                              void* d_out, int out_size, void* d_ws, size_t ws_size,
                              hipStream_t stream) {
  const float* audio = (const float*)d_in[0];
  const float* Win   = (const float*)d_in[1];
  const float* bin   = (const float*)d_in[2];
  const float* bw    = (const float*)d_in[3];
  const float* bb    = (const float*)d_in[4];
  const float* Ws    = (const float*)d_in[5];
  const float* bs    = (const float*)d_in[6];
  const float* Wd    = (const float*)d_in[7];
  const float* bd    = (const float*)d_in[8];
  const float* reson = (const float*)d_in[9];

  float* out = (float*)d_out;           // [0,1048576) = y ; [1048576,2097152) = sparse
  float* ws  = (float*)d_ws;

  float* spec   = ws + WS_SPEC;
  float* h0     = ws + WS_H0;
  float* accb   = ws + WS_ACC;
  float* vbuf   = ws + WS_V;
  float* WT     = ws + WS_WTIN;
  float* WsT    = ws + WS_WST;
  float* WdT    = ws + WS_WDT;
  float* frames = ws + WS_FRAMES;
  // WS_RES region (dead after fusing overlap-add into chain launch) -> bf16 B packs
  short* Bh = (short*)(ws + WS_RES);               // 1,048,576 bf16 = 2 MB
  short* Bl = (short*)(ws + WS_RES + 524288u);     // 1,048,576 bf16 = 2 MB
  // chain-weight packs live in WS_V until k_sparse_dense overwrites it (after k_chain)
  short* Whg = (short*)(ws + WS_V);                // 16384 bf16 = 32 KB
  short* Wlg = (short*)(ws + WS_V + 8192u);        // 16384 bf16 = 32 KB

  // zero y region (atomicAdd target); d_out is poisoned before every launch
  hipMemsetAsync(d_out, 0, 1048576u * sizeof(float), stream);

  k_fft<<<2688, 256, 0, stream>>>(audio, reson, Win, Ws, Wd, bw,
                                  spec, frames, WT, WsT, WdT, Whg, Wlg);
  k_proj_in<<<512, 256, 0, stream>>>(spec, Win, bin, h0);
  k_chain<<<160, 1024, 0, stream>>>(h0, Whg, Wlg, bb, accb, frames, Bh, Bl);
  k_sparse_dense<<<512, 256, 0, stream>>>(accb, WsT, bs, WdT, bd, out + 1048576, vbuf);
  k_conv<<<640, 512, 0, stream>>>(vbuf, Bh, Bl, out);
}

// Round 11
// 172.435 us; speedup vs baseline: 1.1449x; 1.0117x over previous
//
#include <hip/hip_runtime.h>

#define PI_F 3.14159265358979323846f

typedef short bf16x8 __attribute__((ext_vector_type(8)));
typedef float f32x4 __attribute__((ext_vector_type(4)));

#define MFMA16(acc, a, b) \
  acc = __builtin_amdgcn_mfma_f32_16x16x32_bf16(a, b, acc, 0, 0, 0)

// ---------------- workspace layout (float offsets) ----------------
#define WS_SPEC   0u          // 32*128*1024  [b][t][k]
#define WS_H0     4194304u    // 32*32*128    [b][o][t]
#define WS_ACC    4325376u    // 32*128*32    [b][t][o]
#define WS_V      4456448u    // 32*32*128    [b][c][t]; ALSO: prep stashes the
                              // chain-weight bf16 packs in the first 16384 floats
#define WS_WTIN   4587520u    // 1024*32      [k][o] (legacy, unused by proj_in v9+)
#define WS_WST    4620288u    // 32*256       [m][o2]
#define WS_WDT    4628480u    // 256*32       [o2][c]
#define WS_FRAMES 4636672u    // 32*32*2048   [c][f][j]
#define WS_RES    6733824u    // (dead: res assembly fused into obpack) -> Bh/Bl packs
// total 7782400 floats = ~29.7 MB

// ---- 2048-pt complex DIT FFT, bit-reversed input, 256 thr ----
// v9 structure (proven): radix-8 fusion, 4 LDS passes; BIX padding.
#define BIX(a) ((a) + ((a) >> 4))

#define BFLY(I0, I1, C, S)                                   \
  { float2 u = buf[I0]; float2 w = buf[I1];                  \
    float tr = (C) * w.x - (S) * w.y;                        \
    float ti = (C) * w.y + (S) * w.x;                        \
    buf[I0] = make_float2(u.x + tr, u.y + ti);               \
    buf[I1] = make_float2(u.x - tr, u.y - ti); }

#define CMULV(RX, RY, C, S, W) \
  { RX = (C) * (W).x - (S) * (W).y; RY = (C) * (W).y + (S) * (W).x; }

// fused stages (s, s+1): ws=(cs,ss) for stage s, w'=(cp,sp) for stage s+1.
__device__ __forceinline__ void quad_bfly(float2* buf, int a, int h,
                                          float cs, float ss, float cp, float sp) {
  float2 x0 = buf[BIX(a)],         x1 = buf[BIX(a + h)];
  float2 x2 = buf[BIX(a + 2 * h)], x3 = buf[BIX(a + 3 * h)];
  float t1x = cs * x1.x - ss * x1.y, t1y = cs * x1.y + ss * x1.x;
  float t3x = cs * x3.x - ss * x3.y, t3y = cs * x3.y + ss * x3.x;
  float2 y0 = make_float2(x0.x + t1x, x0.y + t1y);
  float2 y1 = make_float2(x0.x - t1x, x0.y - t1y);
  float2 y2 = make_float2(x2.x + t3x, x2.y + t3y);
  float2 y3 = make_float2(x2.x - t3x, x2.y - t3y);
  float u2x = cp * y2.x - sp * y2.y, u2y = cp * y2.y + sp * y2.x;
  float u3x = sp * y3.x + cp * y3.y, u3y = sp * y3.y - cp * y3.x;  // (-i w')*y3
  buf[BIX(a)]         = make_float2(y0.x + u2x, y0.y + u2y);
  buf[BIX(a + 2 * h)] = make_float2(y0.x - u2x, y0.y - u2y);
  buf[BIX(a + h)]     = make_float2(y1.x + u3x, y1.y + u3y);
  buf[BIX(a + 3 * h)] = make_float2(y1.x - u3x, y1.y - u3y);
}

// fused stages (s, s+1, s+2) on octet {a + k*h}, k=0..7. v = e^{-i pi j/4h}.
__device__ __forceinline__ void octet_bfly(float2* buf, int a, int h,
                                           float cv, float sv) {
  const float R = 0.7071067811865476f;
  float c1 = cv * cv - sv * sv, s1 = 2.f * cv * sv;   // w' = v^2
  float c2 = c1 * c1 - s1 * s1, s2 = 2.f * c1 * s1;   // ws = v^4
  float2 x0 = buf[BIX(a)],         x1 = buf[BIX(a + h)];
  float2 x2 = buf[BIX(a + 2 * h)], x3 = buf[BIX(a + 3 * h)];
  float2 x4 = buf[BIX(a + 4 * h)], x5 = buf[BIX(a + 5 * h)];
  float2 x6 = buf[BIX(a + 6 * h)], x7 = buf[BIX(a + 7 * h)];
  float tx, ty;
  CMULV(tx, ty, c2, s2, x1);
  float2 y0 = make_float2(x0.x + tx, x0.y + ty), y1 = make_float2(x0.x - tx, x0.y - ty);
  CMULV(tx, ty, c2, s2, x3);
  float2 y2 = make_float2(x2.x + tx, x2.y + ty), y3 = make_float2(x2.x - tx, x2.y - ty);
  CMULV(tx, ty, c2, s2, x5);
  float2 y4 = make_float2(x4.x + tx, x4.y + ty), y5 = make_float2(x4.x - tx, x4.y - ty);
  CMULV(tx, ty, c2, s2, x7);
  float2 y6 = make_float2(x6.x + tx, x6.y + ty), y7 = make_float2(x6.x - tx, x6.y - ty);
  CMULV(tx, ty, c1, s1, y2);
  float2 z0 = make_float2(y0.x + tx, y0.y + ty), z2 = make_float2(y0.x - tx, y0.y - ty);
  CMULV(tx, ty, c1, s1, y3);    // -i*u = (u.y, -u.x)
  float2 z1 = make_float2(y1.x + ty, y1.y - tx), z3 = make_float2(y1.x - ty, y1.y + tx);
  CMULV(tx, ty, c1, s1, y6);
  float2 z4 = make_float2(y4.x + tx, y4.y + ty), z6 = make_float2(y4.x - tx, y4.y - ty);
  CMULV(tx, ty, c1, s1, y7);
  float2 z5 = make_float2(y5.x + ty, y5.y - tx), z7 = make_float2(y5.x - ty, y5.y + tx);
  float ca = R * (cv + sv), sa = R * (sv - cv);   // v*w8
  float cb = sv,            sb = -cv;             // -i*v
  float cc = R * (sv - cv), sc = -R * (cv + sv);  // v*w8^3
  CMULV(tx, ty, cv, sv, z4);
  buf[BIX(a)]         = make_float2(z0.x + tx, z0.y + ty);
  buf[BIX(a + 4 * h)] = make_float2(z0.x - tx, z0.y - ty);
  CMULV(tx, ty, ca, sa, z5);
  buf[BIX(a + h)]     = make_float2(z1.x + tx, z1.y + ty);
  buf[BIX(a + 5 * h)] = make_float2(z1.x - tx, z1.y - ty);
  CMULV(tx, ty, cb, sb, z6);
  buf[BIX(a + 2 * h)] = make_float2(z2.x + tx, z2.y + ty);
  buf[BIX(a + 6 * h)] = make_float2(z2.x - tx, z2.y - ty);
  CMULV(tx, ty, cc, sc, z7);
  buf[BIX(a + 3 * h)] = make_float2(z3.x + tx, z3.y + ty);
  buf[BIX(a + 7 * h)] = make_float2(z3.x - tx, z3.y - ty);
}

__device__ __forceinline__ void fft2048_stages(float2* buf, int tid) {
  octet_bfly(buf, tid << 3, 1, 1.f, 0.f);
  __syncthreads();
  {
    int j = tid & 7;
    int a = ((tid >> 3) << 6) + j;
    float sv, cv;
    __sincosf(-PI_F / 32.f * (float)j, &sv, &cv);
    octet_bfly(buf, a, 8, cv, sv);
  }
  __syncthreads();
  {
    int j = tid & 63;
    int a = ((tid >> 6) << 9) + j;
    float sv, cv;
    __sincosf(-PI_F / 256.f * (float)j, &sv, &cv);
    octet_bfly(buf, a, 64, cv, sv);
  }
  __syncthreads();
  for (int g = tid; g < 512; g += 256) {
    float sp, cp;
    __sincosf(-PI_F / 1024.f * (float)g, &sp, &cp);   // w' (stage 10)
    float c2 = cp * cp - sp * sp, s2 = 2.f * cp * sp; // ws = w'^2 (stage 9)
    quad_bfly(buf, g, 512, c2, s2, cp, sp);
  }
  __syncthreads();
}

// ---------------- fused FFT kernel: STFT pairs + resonance pairs + prep tail ----------------
__global__ __launch_bounds__(256) void k_fft(const float* __restrict__ audio,
                                             const float* __restrict__ resin,
                                             const float* __restrict__ Win,
                                             const float* __restrict__ Ws,
                                             const float* __restrict__ Wd,
                                             const float* __restrict__ bwIn,
                                             float* __restrict__ spec,
                                             float* __restrict__ frames,
                                             float* __restrict__ WT,
                                             float* __restrict__ WsT,
                                             float* __restrict__ WdT,
                                             short* __restrict__ Whg,
                                             short* __restrict__ Wlg) {
  __shared__ float2 buf[2176];        // 2048 + BIX padding
  int blk = blockIdx.x;

  if (blk >= 2560) {                  // ---- prep branch (no LDS use, no syncs) ----
    int i = (blk - 2560) * 256 + threadIdx.x;
    if (i < 8192)  { int o2 = i >> 5, m = i & 31;   WsT[m * 256 + o2] = Ws[i]; }
    if (i < 8192)  { int c = i >> 8, o2 = i & 255;  WdT[o2 * 32 + c] = Wd[i]; }
    if (i < 16384) {
      // i = ((s*32+o)*32+m)*2 + w
      int w = i & 1, m = (i >> 1) & 31, o = (i >> 6) & 31, s = i >> 11;
      float val = bwIn[i];
      unsigned bits = __float_as_uint(val);
      float rem = val - __uint_as_float(bits & 0xffff0000u);
      int row = (s * 2 + w) * 32 + o;
      Whg[row * 32 + m] = (short)(bits >> 16);
      Wlg[row * 32 + m] = (short)(__float_as_uint(rem) >> 16);
    }
    return;
  }

  if (blk < 2048) {
    int b  = blk >> 6;
    int f0 = (blk & 63) * 2;      // frames f0, f0+1
    for (int j = threadIdx.x; j < 2048; j += 256) {
      float h = 0.5f - 0.5f * __cosf(0.0030679615757712823f * (float)j); // 2pi/2048
      int i1 = f0 * 256 + j;
      int i2 = i1 + 256;
      float a1 = (i1 < 32768) ? audio[b * 32768 + i1] : 0.f;
      float a2 = (i2 < 32768) ? audio[b * 32768 + i2] : 0.f;
      buf[BIX(__brev((unsigned)j) >> 21)] = make_float2(a1 * h, a2 * h);
    }
    __syncthreads();
    fft2048_stages(buf, threadIdx.x);
    const float scale = 0.5f * 0.022097086912079608f;  // 0.5 / sqrt(2048)
    for (int k = threadIdx.x; k < 1024; k += 256) {
      float2 zk = buf[BIX(k)];
      float2 zn = buf[BIX((2048 - k) & 2047)];
      float f1r = zk.x + zn.x, f1i = zk.y - zn.y;
      float f2r = zk.y + zn.y, f2i = zk.x - zn.x;
      spec[(b * 128 + f0) * 1024 + k]     = sqrtf(f1r * f1r + f1i * f1i) * scale;
      spec[(b * 128 + f0 + 1) * 1024 + k] = sqrtf(f2r * f2r + f2i * f2i) * scale;
    }
  } else {
    int r = blk - 2048;           // 0..511
    int c = r >> 4;
    int g = r & 15;               // frames 2g (exp 2g+1), 2g+1 (exp 2g+2)
    float e1 = (float)(2 * g + 1);
    for (int k = threadIdx.x; k < 2048; k += 256) {
      int kk = (k <= 1024) ? k : 2048 - k;   // Hermitian (real) extension
      float cv = resin[c * 1025 + kk];
      cv = fminf(fmaxf(cv, 0.f), 0.9999f);
      float m1 = __powf(cv, e1);
      float m2 = m1 * cv;
      buf[BIX(__brev((unsigned)k) >> 21)] = make_float2(m1, m2);
    }
    __syncthreads();
    fft2048_stages(buf, threadIdx.x);
    for (int j = threadIdx.x; j < 2048; j += 256) {
      float h  = 0.5f - 0.5f * __cosf(0.0030679615757712823f * (float)j);
      float sc = h * (1.f / 2048.f);
      float2 z = buf[BIX(j)];
      frames[(c * 32 + 2 * g) * 2048 + j]     = z.x * sc;
      frames[(c * 32 + 2 * g + 1) * 2048 + j] = z.y * sc;
    }
  }
}

// ---------------- proj_in: h0[b,o,t] = sum_k Win[o][k]*spec[b,t,k] + bias ----------------
// v9 form (proven): float4 LDS reads (broadcast across half-wave), Win o-major.
__global__ __launch_bounds__(256) void k_proj_in(const float* __restrict__ spec,
                                                 const float* __restrict__ Win,
                                                 const float* __restrict__ bias,
                                                 float* __restrict__ h0) {
  __shared__ float specL[8][1024];
  __shared__ float red[32][8][8];   // [o][tt][p]
  int b  = blockIdx.x >> 4;
  int t0 = (blockIdx.x & 15) * 8;
  for (int i = threadIdx.x; i < 8192; i += 256) {
    int tt = i >> 10, k = i & 1023;
    specL[tt][k] = spec[(b * 128 + t0 + tt) * 1024 + k];
  }
  __syncthreads();
  int o = threadIdx.x & 31, p = threadIdx.x >> 5;
  float part[8] = {0.f,0.f,0.f,0.f,0.f,0.f,0.f,0.f};
  const float4* Wrow = (const float4*)(Win + o * 1024);   // Win is [o][k]
  for (int k4 = p * 32; k4 < p * 32 + 32; ++k4) {         // 128 k per thread
    float4 w4 = Wrow[k4];
    int k = k4 * 4;
#pragma unroll
    for (int tt = 0; tt < 8; ++tt) {
      float4 s4 = *(const float4*)&specL[tt][k];
      part[tt] += w4.x * s4.x + w4.y * s4.y + w4.z * s4.z + w4.w * s4.w;
    }
  }
#pragma unroll
  for (int tt = 0; tt < 8; ++tt) red[o][tt][p] = part[tt];
  __syncthreads();
  int oo = threadIdx.x >> 3, tt2 = threadIdx.x & 7;
  float s = bias[oo];
#pragma unroll
  for (int p2 = 0; p2 < 8; ++p2) s += red[oo][tt2][p2];
  h0[b * 4096 + oo * 128 + t0 + tt2] = s;
}

// ---------------- chain (blocks 0..31) + fused overlap-add/B-pack (blocks 32..159) ----------------
__global__ __launch_bounds__(1024) void k_chain(const float* __restrict__ h0,
                                                const short* __restrict__ Whg,
                                                const short* __restrict__ Wlg,
                                                const float* __restrict__ bb,
                                                float* __restrict__ accout,
                                                const float* __restrict__ frames,
                                                short* __restrict__ Bh,
                                                short* __restrict__ Bl) {
  __shared__ __align__(16) short Hh[192 * 40];   // rows stride 40 bf16 (80 B)
  __shared__ __align__(16) short Hl[192 * 40];
  __shared__ float Hf[128 * 33];                 // fp32 H for exact residual
  __shared__ float bL[256];
  __shared__ float red[16];
  int blk = blockIdx.x, tid = threadIdx.x;

  if (blk >= 32) {                  // ---- obpack branch (no LDS use, no syncs) ----
    int ubb = (blk - 32) * 4 + (tid >> 8);   // old obpack block id 0..511
    int r   = tid & 255;
    int c   = ubb >> 4, o = ubb & 15;
    bf16x8 hv, lv;
#pragma unroll
    for (int j = 0; j < 8; ++j) {
      int fo = 8 * o + j;
      int g  = fo >> 2;
      int j0 = ((fo & 3) << 8) + r;
      float val = frames[(c * 32 + g) * 2048 + j0];
      if (g > 0) val += frames[(c * 32 + g - 1) * 2048 + j0 + 1024];
      unsigned bits = __float_as_uint(val);
      float rem = val - __uint_as_float(bits & 0xffff0000u);
      hv[j] = (short)(bits >> 16);
      lv[j] = (short)(__float_as_uint(rem) >> 16);
    }
    int unit = (ubb * 16 + (r >> 4)) * 16 + (r & 15);
    ((bf16x8*)Bh)[unit] = hv;
    ((bf16x8*)Bl)[unit] = lv;
    return;
  }

  int b = blk;
  for (int i = tid; i < 4096; i += 1024) {
    int t = i & 127;                 // h0 layout [o][t]
    int o = i >> 7;
    float val = h0[b * 4096 + i];
    Hf[t * 33 + o] = val;
    unsigned bits = __float_as_uint(val);
    float rem = val - __uint_as_float(bits & 0xffff0000u);
    Hh[t * 40 + o] = (short)(bits >> 16);
    Hl[t * 40 + o] = (short)(__float_as_uint(rem) >> 16);
  }
  for (int i = tid; i < 64 * 40; i += 1024) {    // zero pad rows 128..191
    Hh[128 * 40 + i] = 0;
    Hl[128 * 40 + i] = 0;
  }
  if (tid < 256) bL[tid] = bb[tid];
  __syncthreads();

  int wave = tid >> 6, lane = tid & 63;
  int quad = lane >> 4, l15 = lane & 15;
  int t0 = (wave & 7) * 16, o0 = (wave >> 3) * 16;
  int tD = t0 + quad * 4;          // D rows tD..tD+3
  int oD = o0 + l15;               // D col

  const bf16x8* Hh8 = (const bf16x8*)Hh;   // unit = row*5 + quad (40 bf16 = 5 units)
  const bf16x8* Hl8 = (const bf16x8*)Hl;
  const bf16x8* Wh8 = (const bf16x8*)Whg;  // unit = row*4 + quad (32 bf16 = 4 units)
  const bf16x8* Wl8 = (const bf16x8*)Wlg;

  float accsum[4] = {0.f, 0.f, 0.f, 0.f};
  const int DIL[8] = {1, 2, 4, 8, 16, 32, 64, 1};

#pragma unroll
  for (int s = 0; s < 8; ++s) {
    int arow = t0 + l15;
    int frow = arow + DIL[s];        // <= 191, pad rows give zeros
    bf16x8 Ah = Hh8[arow * 5 + quad];
    bf16x8 Al = Hl8[arow * 5 + quad];
    bf16x8 Fh = Hh8[frow * 5 + quad];
    bf16x8 Fl = Hl8[frow * 5 + quad];
    int w0row = ((s * 2 + 0) * 32 + oD) * 4 + quad;
    int w1row = ((s * 2 + 1) * 32 + oD) * 4 + quad;
    bf16x8 B0h = Wh8[w0row], B0l = Wl8[w0row];
    bf16x8 B1h = Wh8[w1row], B1l = Wl8[w1row];
    float bias = bL[s * 32 + oD];
    f32x4 acc = {bias, bias, bias, bias};
    MFMA16(acc, Ah, B0h); MFMA16(acc, Ah, B0l); MFMA16(acc, Al, B0h);
    MFMA16(acc, Fh, B1h); MFMA16(acc, Fh, B1l); MFMA16(acc, Fl, B1h);
    float hnew[4], lmax = 0.f;
#pragma unroll
    for (int r = 0; r < 4; ++r) {
      float sv = acc[r];
      sv = (sv > 0.f) ? sv : 0.2f * sv;       // leaky_relu 0.2
      sv += Hf[(tD + r) * 33 + oD];           // residual (exact fp32)
      hnew[r] = sv;
      lmax = fmaxf(lmax, fabsf(sv));
    }
#pragma unroll
    for (int off = 32; off > 0; off >>= 1)
      lmax = fmaxf(lmax, __shfl_down(lmax, off, 64));
    if (lane == 0) red[wave] = lmax;
    __syncthreads();                 // red visible; all H reads of this step done
    float mx = red[0];
#pragma unroll
    for (int i = 1; i < 16; ++i) mx = fmaxf(mx, red[i]);
    float nm = 1.f / (mx + 1e-8f);
#pragma unroll
    for (int r = 0; r < 4; ++r) {
      float hv = hnew[r] * nm;
      accsum[r] += hv;
      int t = tD + r;
      Hf[t * 33 + oD] = hv;
      unsigned bits = __float_as_uint(hv);
      float rem = hv - __uint_as_float(bits & 0xffff0000u);
      Hh[t * 40 + oD] = (short)(bits >> 16);
      Hl[t * 40 + oD] = (short)(__float_as_uint(rem) >> 16);
    }
    __syncthreads();                 // new H visible for next step
  }
#pragma unroll
  for (int r = 0; r < 4; ++r)
    accout[b * 4096 + (tD + r) * 32 + oD] = accsum[r];
}

// ---------------- sparse + dense, 8 t per block ----------------
__global__ __launch_bounds__(256) void k_sparse_dense(const float* __restrict__ acc,
                                                      const float* __restrict__ WsT,
                                                      const float* __restrict__ bs,
                                                      const float* __restrict__ WdT,
                                                      const float* __restrict__ bd,
                                                      float* __restrict__ out_sparse,
                                                      float* __restrict__ v) {
  __shared__ float accL[8][32];
  __shared__ float sL[8][256];
  __shared__ float red[8][8][32];   // [p][tt][c]
  int b = blockIdx.x >> 4, tq = blockIdx.x & 15;
  int t0 = tq * 8;
  int tid = threadIdx.x;
  accL[tid >> 5][tid & 31] = acc[b * 4096 + (t0 + (tid >> 5)) * 32 + (tid & 31)];
  __syncthreads();
  float bsv = bs[tid];
  float s[8];
#pragma unroll
  for (int j = 0; j < 8; ++j) s[j] = bsv;
  for (int m = 0; m < 32; ++m) {
    float w = WsT[m * 256 + tid];
#pragma unroll
    for (int j = 0; j < 8; ++j) s[j] += w * accL[j][m];
  }
  float* os = out_sparse + b * 32768 + tid * 128 + t0;
#pragma unroll
  for (int j = 0; j < 8; ++j) {
    s[j] = fmaxf(s[j], 0.f);
    os[j] = s[j];
    sL[j][tid] = s[j];
  }
  __syncthreads();
  int c = tid & 31, p = tid >> 5;
  float pp[8] = {0.f,0.f,0.f,0.f,0.f,0.f,0.f,0.f};
  for (int jj = 0; jj < 32; ++jj) {
    int o2 = p * 32 + jj;
    float w = WdT[o2 * 32 + c];
#pragma unroll
    for (int j = 0; j < 8; ++j) pp[j] += w * sL[j][o2];
  }
#pragma unroll
  for (int j = 0; j < 8; ++j) red[p][j][c] = pp[j];
  __syncthreads();
  {
    int tt = tid >> 5, cc = tid & 31;
    float vv = bd[cc];
#pragma unroll
    for (int p2i = 0; p2i < 8; ++p2i) vv += red[p2i][tt][cc];
    v[b * 4096 + cc * 128 + t0 + tt] = vv;
  }
}

// ---------------- final conv as MFMA GEMM, v11: explicit B software-pipeline ----------------
// v4 structure (two-phase, 40 KB LDS, 4 blocks/CU cap) + 1-step-ahead B
// prefetch into registers across the FLATTENED 16-step K-loop (p unrolled).
// B loads are pure-global (no LDS hazard), so the prefetch for p1-ks0 issues
// during p0-ks7's MFMAs. Accumulation order c=0..31 unchanged -> bitwise-same.
// +16 VGPRs (~104); occupancy unaffected (LDS-bound).
// XCD-group swizzle: all 32 b-blocks of one (j,uc) share one XCD's L2 slice.
__global__ __launch_bounds__(512, 4) void k_conv(const float* __restrict__ v,
                                                 const short* __restrict__ Bh,
                                                 const short* __restrict__ Bl,
                                                 float* __restrict__ y) {
  __shared__ __align__(16) short AH[32 * 264];   // [row 32][K 256 + pad 8]
  __shared__ __align__(16) short AL[32 * 264];
  __shared__ float vwin[2][16][48];              // [c-half][c_local][ii]

  // --- XCD-group swizzle: group e (20 of them) -> XCD e%8; batches fill slots.
  int xcd  = blockIdx.x & 7;
  int slot = blockIdx.x >> 3;
  int e, b;
  if      (slot < 32) { e = xcd;      b = slot; }
  else if (slot < 64) { e = xcd + 8;  b = slot - 32; }
  else                { e = (xcd < 4) ? (xcd + 16) : (xcd + 12);
                        b = (xcd < 4) ? (slot - 64) : (slot - 48); }
  int j, uc;
  if      (e < 2)  { j = 0; uc = e; }
  else if (e < 6)  { j = 1; uc = e - 2; }
  else if (e < 12) { j = 2; uc = e - 6; }
  else             { j = 3; uc = e - 12; }
  int D0 = 32 * j - 16 * uc;       // d = D0 - 15 + ii, ii in [0,46]

  // stage compact v windows (both c-halves): 2*16*47 floats
  for (int i = threadIdx.x; i < 1504; i += 512) {
    int ii = i % 47;
    int r  = i / 47;               // 0..31
    int c  = r & 15, ph = r >> 4;
    int d  = D0 - 15 + ii;
    vwin[ph][c][ii] = (d >= 0 && d < 128)
        ? v[b * 4096 + (16 * ph + c) * 128 + d] : 0.f;
  }
  __syncthreads();

  int lane = threadIdx.x & 63, wave = threadIdx.x >> 6;
  int quad = lane >> 4, l15 = lane & 15;
  int cq   = quad >> 1;            // low bit of c
  int og   = 2 * uc + (quad & 1);  // global u-octet
  int nt0  = wave * 2;             // 8 waves x 2 nt = 16 nt

  f32x4 acc00 = (f32x4)0.f, acc01 = (f32x4)0.f;   // [qs][t]
  f32x4 acc10 = (f32x4)0.f, acc11 = (f32x4)0.f;

  const bf16x8* AH8 = (const bf16x8*)AH;
  const bf16x8* AL8 = (const bf16x8*)AL;
  const bf16x8* Bh8 = (const bf16x8*)Bh;
  const bf16x8* Bl8 = (const bf16x8*)Bl;
  short2* AH2 = (short2*)AH;
  short2* AL2 = (short2*)AL;

  int abase0 = (0 * 16 + l15) * 33 + quad;   // bf16x8 units, row stride 33
  int abase1 = (1 * 16 + l15) * 33 + quad;

  // prefetch B for step 0 (p=0, ks=0 -> c = cq)
  bf16x8 pbh0, pbl0, pbh1, pbl1;
  {
    int bb0 = (cq * 16 + og) * 256 + l15;
    pbh0 = Bh8[bb0 + nt0 * 16];       pbl0 = Bl8[bb0 + nt0 * 16];
    pbh1 = Bh8[bb0 + (nt0 + 1) * 16]; pbl1 = Bl8[bb0 + (nt0 + 1) * 16];
  }

#pragma unroll
  for (int p = 0; p < 2; ++p) {
    // expand Toeplitz A (hi/lo split) for this c-half: 32 rows x 128 kk-pairs
    for (int i = threadIdx.x; i < 4096; i += 512) {
      int kk2 = i & 127;           // kk = 2*kk2 (pair shares c_local)
      int row = i >> 7;            // 0..31
      int cl  = kk2 >> 3;
      int uu  = (kk2 & 7) * 2;
      int ii  = row - uu + 15;
      float v0 = vwin[p][cl][ii];
      float v1 = vwin[p][cl][ii - 1];
      unsigned w0 = __float_as_uint(v0), w1 = __float_as_uint(v1);
      float r0 = v0 - __uint_as_float(w0 & 0xffff0000u);
      float r1 = v1 - __uint_as_float(w1 & 0xffff0000u);
      int u2 = row * 132 + kk2;    // short2 units, row stride 132
      AH2[u2] = make_short2((short)(w0 >> 16), (short)(w1 >> 16));
      AL2[u2] = make_short2((short)(__float_as_uint(r0) >> 16),
                            (short)(__float_as_uint(r1) >> 16));
    }
    __syncthreads();

#pragma unroll
    for (int ks = 0; ks < 8; ++ks) {
      // consume prefetched B for this step
      bf16x8 bh0 = pbh0, bl0 = pbl0, bh1 = pbh1, bl1 = pbl1;
      // issue prefetch for next step (crosses the phase barrier for p0->p1)
      int step = p * 8 + ks + 1;
      if (step < 16) {
        int cn  = 16 * (step >> 3) + 2 * (step & 7) + cq;
        int bbn = (cn * 16 + og) * 256 + l15;
        pbh0 = Bh8[bbn + nt0 * 16];       pbl0 = Bl8[bbn + nt0 * 16];
        pbh1 = Bh8[bbn + (nt0 + 1) * 16]; pbl1 = Bl8[bbn + (nt0 + 1) * 16];
      }
      bf16x8 ah0 = AH8[abase0 + ks * 4];
      bf16x8 al0 = AL8[abase0 + ks * 4];
      bf16x8 ah1 = AH8[abase1 + ks * 4];
      bf16x8 al1 = AL8[abase1 + ks * 4];
      MFMA16(acc00, ah0, bh0); MFMA16(acc00, ah0, bl0); MFMA16(acc00, al0, bh0);
      MFMA16(acc10, ah1, bh0); MFMA16(acc10, ah1, bl0); MFMA16(acc10, al1, bh0);
      MFMA16(acc01, ah0, bh1); MFMA16(acc01, ah0, bl1); MFMA16(acc01, al0, bh1);
      MFMA16(acc11, ah1, bh1); MFMA16(acc11, ah1, bl1); MFMA16(acc11, al1, bh1);
    }
    __syncthreads();               // A consumed; safe to overwrite in next phase
  }

  {
    float* yb0 = y + b * 32768 + (32 * j + 0 * 16 + quad * 4) * 256 + l15;
    float* yb1 = y + b * 32768 + (32 * j + 1 * 16 + quad * 4) * 256 + l15;
#pragma unroll
    for (int reg = 0; reg < 4; ++reg) {
      atomicAdd(yb0 + reg * 256 + (nt0 + 0) * 16, acc00[reg]);
      atomicAdd(yb0 + reg * 256 + (nt0 + 1) * 16, acc01[reg]);
      atomicAdd(yb1 + reg * 256 + (nt0 + 0) * 16, acc10[reg]);
      atomicAdd(yb1 + reg * 256 + (nt0 + 1) * 16, acc11[reg]);
    }
  }
}

extern "C" void kernel_launch(void* const* d_in, const int* in_sizes, int n_in,
                              void* d_out, int out_size, void* d_ws, size_t ws_size,
                              hipStream_t stream) {
  const float* audio = (const float*)d_in[0];
  const float* Win   = (const float*)d_in[1];
  const float* bin   = (const float*)d_in[2];
  const float* bw    = (const float*)d_in[3];
  const float* bb    = (const float*)d_in[4];
  const float* Ws    = (const float*)d_in[5];
  const float* bs    = (const float*)d_in[6];
  const float* Wd    = (const float*)d_in[7];
  const float* bd    = (const float*)d_in[8];
  const float* reson = (const float*)d_in[9];

  float* out = (float*)d_out;           // [0,1048576) = y ; [1048576,2097152) = sparse
  float* ws  = (float*)d_ws;

  float* spec   = ws + WS_SPEC;
  float* h0     = ws + WS_H0;
  float* accb   = ws + WS_ACC;
  float* vbuf   = ws + WS_V;
  float* WT     = ws + WS_WTIN;
  float* WsT    = ws + WS_WST;
  float* WdT    = ws + WS_WDT;
  float* frames = ws + WS_FRAMES;
  // WS_RES region (dead after fusing overlap-add into chain launch) -> bf16 B packs
  short* Bh = (short*)(ws + WS_RES);               // 1,048,576 bf16 = 2 MB
  short* Bl = (short*)(ws + WS_RES + 524288u);     // 1,048,576 bf16 = 2 MB
  // chain-weight packs live in WS_V until k_sparse_dense overwrites it (after k_chain)
  short* Whg = (short*)(ws + WS_V);                // 16384 bf16 = 32 KB
  short* Wlg = (short*)(ws + WS_V + 8192u);        // 16384 bf16 = 32 KB

  // zero y region (atomicAdd target); d_out is poisoned before every launch
  hipMemsetAsync(d_out, 0, 1048576u * sizeof(float), stream);

  k_fft<<<2688, 256, 0, stream>>>(audio, reson, Win, Ws, Wd, bw,
                                  spec, frames, WT, WsT, WdT, Whg, Wlg);
  k_proj_in<<<512, 256, 0, stream>>>(spec, Win, bin, h0);
  k_chain<<<160, 1024, 0, stream>>>(h0, Whg, Wlg, bb, accb, frames, Bh, Bl);
  k_sparse_dense<<<512, 256, 0, stream>>>(accb, WsT, bs, WdT, bd, out + 1048576, vbuf);
  k_conv<<<640, 512, 0, stream>>>(vbuf, Bh, Bl, out);
}